// Round 1
// baseline (353.973 us; speedup 1.0000x reference)
//
#include <hip/hip_runtime.h>

#define DM   1024
#define DI   2048
#define DS   16
#define RK   64
#define NBAT 2
#define LL   1024
#define MR   (NBAT*LL)   // 2048 rows (B*L)
#define NCH  32          // scan chunks
#define LC   (LL/NCH)    // 32 steps per chunk

typedef short  bf16x8 __attribute__((ext_vector_type(8)));
typedef float  f32x4  __attribute__((ext_vector_type(4)));

__device__ __forceinline__ float bf2f(unsigned short u) {
  union { unsigned int i; float f; } v; v.i = ((unsigned int)u) << 16; return v.f;
}
__device__ __forceinline__ unsigned short f2bf(float f) {
  union { float f; unsigned int i; } v; v.f = f;
  return (unsigned short)((v.i + 0x7FFFu + ((v.i >> 16) & 1u)) >> 16);  // RNE
}

// ---------------- prep / convert kernels ----------------

__global__ void prep_x(const float* __restrict__ x, const float* __restrict__ mask,
                       unsigned short* __restrict__ xb) {
  int i = blockIdx.x * 256 + threadIdx.x;
  if (i < MR * DM) xb[i] = f2bf(x[i] * mask[i >> 10]);
}

// Wcat rows 0..4095 = in_proj_w; rows 4096..8191 = in_proj_w with feature(k) flipped
__global__ void prep_w(const float* __restrict__ W, unsigned short* __restrict__ Wcat) {
  int i = blockIdx.x * 256 + threadIdx.x;
  if (i < 8192 * 1024) {
    int nrow = i >> 10, k = i & 1023;
    float w = (nrow < 4096) ? W[i] : W[(size_t)(nrow - 4096) * 1024 + (1023 - k)];
    Wcat[i] = f2bf(w);
  }
}

__global__ void cvt_f2b(const float* __restrict__ src, unsigned short* __restrict__ dst, int n) {
  int i = blockIdx.x * 256 + threadIdx.x;
  if (i < n) dst[i] = f2bf(src[i]);
}

// A2[dir][d][s] = -exp(A_log)
__global__ void prep_A(const float* __restrict__ Af, const float* __restrict__ Ar,
                       float* __restrict__ A2) {
  int i = blockIdx.x * 256 + threadIdx.x;
  if (i < 2 * DI * DS) {
    float al = (i < DI * DS) ? Af[i] : Ar[i - DI * DS];
    A2[i] = -__expf(al);
  }
}

// dtb[dir][r][k] = bf16(x_dbl[dir][r][k]), k<64
__global__ void cvt_dtb(const float* __restrict__ xdbl, unsigned short* __restrict__ dtb) {
  int i = blockIdx.x * 256 + threadIdx.x;
  if (i < 2 * MR * RK) {
    int dir = i / (MR * RK);
    int j = i % (MR * RK);
    int r = j >> 6, k = j & 63;
    dtb[i] = f2bf(xdbl[(size_t)dir * (MR * 96) + (size_t)r * 96 + k]);
  }
}

// ---------------- bf16 MFMA GEMM, C = A(M,K) * B(N,K)^T, 128x128 tile ----------------

struct GArg { const unsigned short* A; const unsigned short* B; float* C; const float* bias; };

template<int EPI>  // 0 = plain f32 store, 1 = softplus(acc + bias[col])
__global__ __launch_bounds__(256)
void gemm_bt(GArg g0, GArg g1, int M, int N, int K, int lda, int ldb, int ldc)
{
  __shared__ __align__(16) unsigned short As[128 * 32];
  __shared__ __align__(16) unsigned short Bs[128 * 32];
  const GArg ga = blockIdx.z ? g1 : g0;
  const int tid  = threadIdx.x;
  const int wave = tid >> 6;
  const int lane = tid & 63;
  const int bm = blockIdx.y * 128;
  const int bn = blockIdx.x * 128;
  const int wr = wave >> 1, wc = wave & 1;   // wave owns 64x64 at (wr*64, wc*64)

  f32x4 acc[4][4];
#pragma unroll
  for (int m = 0; m < 4; ++m)
#pragma unroll
    for (int n = 0; n < 4; ++n) acc[m][n] = (f32x4){0.f, 0.f, 0.f, 0.f};

  const int rsel = lane & 15;
  const int ksel = (lane >> 4) * 8;

  for (int k0 = 0; k0 < K; k0 += 32) {
#pragma unroll
    for (int i = 0; i < 2; ++i) {
      const int chunk = wave * 2 + i;            // 0..7, wave-uniform
      const int flat  = chunk * 512 + lane * 8;  // bf16 idx in 128x32 tile (linear)
      const int row = flat >> 5, col = flat & 31;
      int gr = bm + row; if (gr > M - 1) gr = M - 1;
      const unsigned short* srcA = ga.A + (size_t)gr * lda + (k0 + col);
      __builtin_amdgcn_global_load_lds((const __attribute__((address_space(1))) void*)srcA,
                                       (__attribute__((address_space(3))) void*)(&As[chunk * 512]),
                                       16, 0, 0);
      int gc = bn + row; if (gc > N - 1) gc = N - 1;   // clamp for N=96 tail
      const unsigned short* srcB = ga.B + (size_t)gc * ldb + (k0 + col);
      __builtin_amdgcn_global_load_lds((const __attribute__((address_space(1))) void*)srcB,
                                       (__attribute__((address_space(3))) void*)(&Bs[chunk * 512]),
                                       16, 0, 0);
    }
    __syncthreads();   // compiler drains vmcnt before barrier
    bf16x8 af[4], bfv[4];
#pragma unroll
    for (int m = 0; m < 4; ++m)
      af[m] = *(const bf16x8*)&As[(wr * 64 + m * 16 + rsel) * 32 + ksel];
#pragma unroll
    for (int n = 0; n < 4; ++n)
      bfv[n] = *(const bf16x8*)&Bs[(wc * 64 + n * 16 + rsel) * 32 + ksel];
#pragma unroll
    for (int m = 0; m < 4; ++m)
#pragma unroll
      for (int n = 0; n < 4; ++n)
        acc[m][n] = __builtin_amdgcn_mfma_f32_16x16x32_bf16(af[m], bfv[n], acc[m][n], 0, 0, 0);
    __syncthreads();
  }

#pragma unroll
  for (int m = 0; m < 4; ++m) {
    const int row0 = bm + wr * 64 + m * 16 + (lane >> 4) * 4;
#pragma unroll
    for (int n = 0; n < 4; ++n) {
      const int col = bn + wc * 64 + n * 16 + rsel;
      if (col < N) {
#pragma unroll
        for (int r = 0; r < 4; ++r) {
          const int rr = row0 + r;
          if (rr < M) {
            float v = acc[m][n][r];
            if constexpr (EPI == 1) {
              v += ga.bias[col];
              v = (v > 15.f) ? v : log1pf(__expf(v));   // softplus
            }
            ga.C[(size_t)rr * ldc + col] = v;
          }
        }
      }
    }
  }
}

// ---------------- depthwise causal conv(4) + silu -> bf16 ----------------
// reads u region of xz (col offset dir*4096, row stride 8192), writes ub[dir] tight (MR x DI)
__global__ __launch_bounds__(256)
void conv_silu_k(const float* __restrict__ xz,
                 const float* __restrict__ cw_f, const float* __restrict__ cb_f,
                 const float* __restrict__ cw_r, const float* __restrict__ cb_r,
                 unsigned short* __restrict__ ub)
{
  const int tid = threadIdx.x;
  const int d   = blockIdx.x * 256 + tid;
  const int l0  = blockIdx.y * 128;
  const int dir = blockIdx.z >> 1, b = blockIdx.z & 1;
  const float* uin = xz + (size_t)dir * 4096 + d;
  const float* cw  = dir ? cw_r : cw_f;
  const float* cb  = dir ? cb_r : cb_f;
  const float w0 = cw[d * 4 + 0], w1 = cw[d * 4 + 1], w2 = cw[d * 4 + 2], w3 = cw[d * 4 + 3];
  const float bias = cb[d];
  unsigned short* uo = ub + (size_t)dir * ((size_t)MR * DI) + d;
  const size_t rbase = (size_t)b * LL;
  float x0 = (l0 >= 3) ? uin[(rbase + l0 - 3) * 8192] : 0.f;
  float x1 = (l0 >= 2) ? uin[(rbase + l0 - 2) * 8192] : 0.f;
  float x2 = (l0 >= 1) ? uin[(rbase + l0 - 1) * 8192] : 0.f;
  for (int l = l0; l < l0 + 128; ++l) {
    float x3 = uin[(rbase + l) * 8192];
    float o = w0 * x0 + w1 * x1 + w2 * x2 + w3 * x3 + bias;
    o = o / (1.f + __expf(-o));   // silu
    uo[(rbase + l) * DI] = f2bf(o);
    x0 = x1; x1 = x2; x2 = x3;
  }
}

// ---------------- chunked selective scan ----------------
// phase A: per (dir,b,chunk,d): prodA[16], h-from-zero[16]
__global__ __launch_bounds__(256)
void scanA(const float* __restrict__ xz, const unsigned short* __restrict__ ub,
           const float* __restrict__ xdbl, const float* __restrict__ A2,
           float* __restrict__ pAb, float* __restrict__ hb)
{
  const int tid = threadIdx.x;
  const int d = blockIdx.x * 256 + tid;
  const int c = blockIdx.y;
  const int dir = blockIdx.z >> 1, b = blockIdx.z & 1;
  __shared__ float sB[LC * DS];
  const float* xd = xdbl + (size_t)dir * (MR * 96);
  for (int i = tid; i < LC * DS; i += 256) {
    int t = i >> 4, s = i & 15;
    sB[i] = xd[(size_t)(b * LL + c * LC + t) * 96 + 64 + s];
  }
  __syncthreads();
  const float* dlt = xz + (size_t)dir * 4096 + d;
  const unsigned short* uu = ub + (size_t)dir * ((size_t)MR * DI) + d;
  float a2[DS];
#pragma unroll
  for (int s = 0; s < DS; ++s) a2[s] = A2[((size_t)dir * DI + d) * DS + s];
  float h[DS], pA[DS];
#pragma unroll
  for (int s = 0; s < DS; ++s) { h[s] = 0.f; pA[s] = 1.f; }
  for (int t = 0; t < LC; ++t) {
    size_t r = (size_t)b * LL + c * LC + t;
    float dl = dlt[r * 8192];
    float du = dl * bf2f(uu[r * DI]);
#pragma unroll
    for (int s = 0; s < DS; ++s) {
      float e = __expf(dl * a2[s]);
      pA[s] *= e;
      h[s] = e * h[s] + du * sB[t * DS + s];
    }
  }
  size_t base = ((((size_t)(dir * 2 + b)) * NCH + c) * DI + d) * DS;
#pragma unroll
  for (int s = 0; s < DS; ++s) { pAb[base + s] = pA[s]; hb[base + s] = h[s]; }
}

// phase B: sequential chunk combine; overwrites hb with h_init per chunk
__global__ __launch_bounds__(256)
void scanB(const float* __restrict__ pAb, float* __restrict__ hb)
{
  int i = blockIdx.x * 256 + threadIdx.x;   // 0..131071 = (dir*2+b)*32768 + d*16+s
  int db = i >> 15;
  int ds = i & 32767;
  float hrun = 0.f;
  for (int c = 0; c < NCH; ++c) {
    size_t off = (((size_t)db * NCH + c) << 15) + ds;
    float h0 = hb[off];
    float pa = pAb[off];
    hb[off] = hrun;
    hrun = pa * hrun + h0;
  }
}

// phase C: re-scan with h_init; y = sum_s h*C + D*u; gate with silu(z).
// DIR=0: write yg_f (f32) into xz z_f slot. DIR=1: read yg_f, add, write bf16 ygb.
template<int DIR>
__global__ __launch_bounds__(256)
void scanC(float* __restrict__ xz, const unsigned short* __restrict__ ub,
           const float* __restrict__ xdbl, const float* __restrict__ A2,
           const float* __restrict__ Dv, const float* __restrict__ hb,
           unsigned short* __restrict__ ygb)
{
  const int tid = threadIdx.x;
  const int d = blockIdx.x * 256 + tid;
  const int c = blockIdx.y;
  const int b = blockIdx.z;
  __shared__ float sB[LC * DS], sC[LC * DS];
  const float* xd = xdbl + (size_t)DIR * (MR * 96);
  for (int i = tid; i < LC * DS; i += 256) {
    int t = i >> 4, s = i & 15;
    size_t ro = (size_t)(b * LL + c * LC + t) * 96;
    sB[i] = xd[ro + 64 + s];
    sC[i] = xd[ro + 80 + s];
  }
  __syncthreads();
  const float* dlt = xz + (size_t)DIR * 4096 + d;
  const unsigned short* uu = ub + (size_t)DIR * ((size_t)MR * DI) + d;
  float a2[DS];
#pragma unroll
  for (int s = 0; s < DS; ++s) a2[s] = A2[((size_t)DIR * DI + d) * DS + s];
  float h[DS];
  size_t base = ((((size_t)(DIR * 2 + b)) * NCH + c) * DI + d) * DS;
#pragma unroll
  for (int s = 0; s < DS; ++s) h[s] = hb[base + s];
  const float Dd = Dv[d];
  for (int t = 0; t < LC; ++t) {
    size_t r = (size_t)b * LL + c * LC + t;
    float dl = dlt[r * 8192];
    float uf = bf2f(uu[r * DI]);
    float du = dl * uf;
    float y = 0.f;
#pragma unroll
    for (int s = 0; s < DS; ++s) {
      float e = __expf(dl * a2[s]);
      h[s] = e * h[s] + du * sB[t * DS + s];
      y += h[s] * sC[t * DS + s];
    }
    y += Dd * uf;
    float* accp = xz + r * 8192 + 2048 + d;             // yg accumulation slot (= z_f slot)
    float z = (DIR == 0) ? accp[0] : xz[r * 8192 + 6144 + d];
    float yg = y * (z / (1.f + __expf(-z)));
    if constexpr (DIR == 0) {
      accp[0] = yg;
    } else {
      ygb[r * DI + d] = f2bf(accp[0] + yg);
    }
  }
}

// ---------------- host launch ----------------

extern "C" void kernel_launch(void* const* d_in, const int* in_sizes, int n_in,
                              void* d_out, int out_size, void* d_ws, size_t ws_size,
                              hipStream_t stream)
{
  (void)in_sizes; (void)n_in; (void)out_size; (void)ws_size;
  const float* x      = (const float*)d_in[0];
  const float* mask   = (const float*)d_in[1];
  const float* inpw   = (const float*)d_in[2];
  const float* outpw  = (const float*)d_in[3];
  const float* cw_f   = (const float*)d_in[4];
  const float* cb_f   = (const float*)d_in[5];
  const float* xpw_f  = (const float*)d_in[6];
  const float* dtw_f  = (const float*)d_in[7];
  const float* dtbias_f = (const float*)d_in[8];
  const float* alog_f = (const float*)d_in[9];
  const float* Dv_f   = (const float*)d_in[10];
  const float* cw_r   = (const float*)d_in[11];
  const float* cb_r   = (const float*)d_in[12];
  const float* xpw_r  = (const float*)d_in[13];
  const float* dtw_r  = (const float*)d_in[14];
  const float* dtbias_r = (const float*)d_in[15];
  const float* alog_r = (const float*)d_in[16];
  const float* Dv_r   = (const float*)d_in[17];
  float* out = (float*)d_out;

  char* p = (char*)d_ws;
  auto carve = [&](size_t bytes) -> char* {
    char* q = p; p += (bytes + 255) & ~(size_t)255; return q;
  };
  unsigned short* xb   = (unsigned short*)carve((size_t)MR * DM * 2);
  unsigned short* Wcat = (unsigned short*)carve((size_t)8192 * 1024 * 2);
  unsigned short* xpb  = (unsigned short*)carve((size_t)2 * 96 * DI * 2);
  unsigned short* dtwb = (unsigned short*)carve((size_t)2 * DI * RK * 2);
  unsigned short* opb  = (unsigned short*)carve((size_t)DM * DI * 2);
  float*          A2   = (float*)carve((size_t)2 * DI * DS * 4);
  float*          xz   = (float*)carve((size_t)MR * 8192 * 4);
  unsigned short* ub   = (unsigned short*)carve((size_t)2 * MR * DI * 2);
  float*          xdbl = (float*)carve((size_t)2 * MR * 96 * 4);
  unsigned short* dtb  = (unsigned short*)carve((size_t)2 * MR * RK * 2);
  float*          pAb  = (float*)carve((size_t)4 * NCH * DI * DS * 4);
  float*          hb   = (float*)carve((size_t)4 * NCH * DI * DS * 4);
  unsigned short* ygb  = (unsigned short*)carve((size_t)MR * DI * 2);

  // prep/convert
  prep_x<<<(MR * DM + 255) / 256, 256, 0, stream>>>(x, mask, xb);
  prep_w<<<(8192 * 1024 + 255) / 256, 256, 0, stream>>>(inpw, Wcat);
  cvt_f2b<<<(96 * DI + 255) / 256, 256, 0, stream>>>(xpw_f, xpb, 96 * DI);
  cvt_f2b<<<(96 * DI + 255) / 256, 256, 0, stream>>>(xpw_r, xpb + 96 * DI, 96 * DI);
  cvt_f2b<<<(DI * RK + 255) / 256, 256, 0, stream>>>(dtw_f, dtwb, DI * RK);
  cvt_f2b<<<(DI * RK + 255) / 256, 256, 0, stream>>>(dtw_r, dtwb + DI * RK, DI * RK);
  cvt_f2b<<<(DM * DI + 255) / 256, 256, 0, stream>>>(outpw, opb, DM * DI);
  prep_A<<<(2 * DI * DS + 255) / 256, 256, 0, stream>>>(alog_f, alog_r, A2);

  // G1: xz(2048 x 8192) = xb(2048x1024) @ Wcat(8192x1024)^T
  {
    GArg g0{xb, Wcat, xz, nullptr};
    gemm_bt<0><<<dim3(64, 16, 1), 256, 0, stream>>>(g0, g0, MR, 8192, 1024, DM, DM, 8192);
  }
  // conv + silu -> ub (both dirs, both batches)
  conv_silu_k<<<dim3(8, 8, 4), 256, 0, stream>>>(xz, cw_f, cb_f, cw_r, cb_r, ub);
  // G2: x_dbl(2048 x 96) = ub @ x_proj^T, per dir via grid.z
  {
    GArg g0{ub, xpb, xdbl, nullptr};
    GArg g1{ub + (size_t)MR * DI, xpb + 96 * DI, xdbl + (size_t)MR * 96, nullptr};
    gemm_bt<0><<<dim3(1, 16, 2), 256, 0, stream>>>(g0, g1, MR, 96, DI, DI, DI, 96);
  }
  cvt_dtb<<<(2 * MR * RK + 255) / 256, 256, 0, stream>>>(xdbl, dtb);
  // G3: delta = softplus(dt @ dt_w^T + dt_b), written into xz u-regions (ldc 8192)
  {
    GArg g0{dtb, dtwb, xz, dtbias_f};
    GArg g1{dtb + (size_t)MR * RK, dtwb + DI * RK, xz + 4096, dtbias_r};
    gemm_bt<1><<<dim3(16, 16, 2), 256, 0, stream>>>(g0, g1, MR, DI, RK, RK, RK, 8192);
  }
  // scan
  scanA<<<dim3(8, NCH, 4), 256, 0, stream>>>(xz, ub, xdbl, A2, pAb, hb);
  scanB<<<dim3(512, 1, 1), 256, 0, stream>>>(pAb, hb);
  scanC<0><<<dim3(8, NCH, 2), 256, 0, stream>>>(xz, ub, xdbl, A2, Dv_f, hb, ygb);
  scanC<1><<<dim3(8, NCH, 2), 256, 0, stream>>>(xz, ub, xdbl, A2, Dv_r, hb, ygb);
  // G4: out(2048 x 1024) = ygb @ out_proj^T
  {
    GArg g0{ygb, opb, out, nullptr};
    gemm_bt<0><<<dim3(8, 16, 1), 256, 0, stream>>>(g0, g0, MR, DM, DI, DI, DI, DM);
  }
}

// Round 2
// 321.981 us; speedup vs baseline: 1.0994x; 1.0994x over previous
//
#include <hip/hip_runtime.h>

#define DM   1024
#define DI   2048
#define DS   16
#define RK   64
#define NBAT 2
#define LL   1024
#define MR   (NBAT*LL)   // 2048 rows (B*L)
#define NCH  32          // scan chunks
#define LC   (LL/NCH)    // 32 steps per chunk

typedef short  bf16x8 __attribute__((ext_vector_type(8)));
typedef float  f32x4  __attribute__((ext_vector_type(4)));

__device__ __forceinline__ float bf2f(unsigned short u) {
  union { unsigned int i; float f; } v; v.i = ((unsigned int)u) << 16; return v.f;
}
__device__ __forceinline__ unsigned short f2bf(float f) {
  union { float f; unsigned int i; } v; v.f = f;
  return (unsigned short)((v.i + 0x7FFFu + ((v.i >> 16) & 1u)) >> 16);  // RNE
}

// ---------------- fused prep / convert (one launch) ----------------
// regions: xb | Wcat(+flip) | xpb_f | xpb_r | dtwb_f | dtwb_r | opb | A2_f | A2_r
#define N_XB   (MR*DM)            // 2097152
#define N_WCAT (8192*1024)        // 8388608
#define N_XPB  (96*DI)            // 196608
#define N_DTWB (DI*RK)            // 131072
#define N_OPB  (DM*DI)            // 2097152
#define N_A2   (DI*DS)            // 32768
#define N_PREP (N_XB + N_WCAT + 2*N_XPB + 2*N_DTWB + N_OPB + 2*N_A2)

__global__ void prep_all(const float* __restrict__ x, const float* __restrict__ mask,
                         const float* __restrict__ W,
                         const float* __restrict__ xpw_f, const float* __restrict__ xpw_r,
                         const float* __restrict__ dtw_f, const float* __restrict__ dtw_r,
                         const float* __restrict__ outpw,
                         const float* __restrict__ Af, const float* __restrict__ Ar,
                         unsigned short* __restrict__ xb, unsigned short* __restrict__ Wcat,
                         unsigned short* __restrict__ xpb, unsigned short* __restrict__ dtwb,
                         unsigned short* __restrict__ opb, float* __restrict__ A2)
{
  int i = blockIdx.x * 256 + threadIdx.x;
  if (i < N_XB) { xb[i] = f2bf(x[i] * mask[i >> 10]); return; }
  i -= N_XB;
  if (i < N_WCAT) {
    int nrow = i >> 10, k = i & 1023;
    float w = (nrow < 4096) ? W[i] : W[(size_t)(nrow - 4096) * 1024 + (1023 - k)];
    Wcat[i] = f2bf(w); return;
  }
  i -= N_WCAT;
  if (i < N_XPB) { xpb[i] = f2bf(xpw_f[i]); return; }
  i -= N_XPB;
  if (i < N_XPB) { xpb[N_XPB + i] = f2bf(xpw_r[i]); return; }
  i -= N_XPB;
  if (i < N_DTWB) { dtwb[i] = f2bf(dtw_f[i]); return; }
  i -= N_DTWB;
  if (i < N_DTWB) { dtwb[N_DTWB + i] = f2bf(dtw_r[i]); return; }
  i -= N_DTWB;
  if (i < N_OPB) { opb[i] = f2bf(outpw[i]); return; }
  i -= N_OPB;
  if (i < N_A2) { A2[i] = -__expf(Af[i]); return; }
  i -= N_A2;
  if (i < N_A2) { A2[N_A2 + i] = -__expf(Ar[i]); return; }
}

// dtb[dir][r][k] = bf16(x_dbl[dir][r][k]), k<64
__global__ void cvt_dtb(const float* __restrict__ xdbl, unsigned short* __restrict__ dtb) {
  int i = blockIdx.x * 256 + threadIdx.x;
  if (i < 2 * MR * RK) {
    int dir = i / (MR * RK);
    int j = i % (MR * RK);
    int r = j >> 6, k = j & 63;
    dtb[i] = f2bf(xdbl[(size_t)dir * (MR * 96) + (size_t)r * 96 + k]);
  }
}

// ---------------- bf16 MFMA GEMM, C = A(M,K) * B(N,K)^T, 128x128 tile ----------------

struct GArg { const unsigned short* A; const unsigned short* B; void* C; const float* bias; };

// EPI: 0 none, 1 softplus(acc + bias[col]). OUT: 0 f32, 1 bf16. ATOMIC: f32 atomicAdd.
// SWZ: XCD-contiguous block swizzle (nwg%8==0 required). NDIR: 1 or 2 (dir = z&1).
template<int EPI, int OUT, int ATOMIC, int SWZ, int NDIR>
__global__ __launch_bounds__(256)
void gemm_bt(GArg g0, GArg g1, int M, int N, int K, int lda, int ldb, int ldc, int koff)
{
  __shared__ __align__(16) unsigned short As[128 * 32];
  __shared__ __align__(16) unsigned short Bs[128 * 32];
  const GArg ga = (NDIR == 2 && (blockIdx.z & 1)) ? g1 : g0;
  const int kc = (NDIR == 2) ? ((int)blockIdx.z >> 1) : (int)blockIdx.z;
  const unsigned short* Ap = ga.A + (size_t)kc * koff;
  const unsigned short* Bp = ga.B + (size_t)kc * koff;

  int bx = blockIdx.x, by = blockIdx.y;
  if constexpr (SWZ) {
    const int nwg = gridDim.x * gridDim.y;
    const int cpx = nwg >> 3;
    const int wg = by * gridDim.x + bx;
    const int sw = (wg & 7) * cpx + (wg >> 3);
    bx = sw % gridDim.x; by = sw / gridDim.x;
  }
  const int tid  = threadIdx.x;
  const int wave = tid >> 6;
  const int lane = tid & 63;
  const int bm = by * 128;
  const int bn = bx * 128;
  const int wr = wave >> 1, wc = wave & 1;   // wave owns 64x64 at (wr*64, wc*64)

  f32x4 acc[4][4];
#pragma unroll
  for (int m = 0; m < 4; ++m)
#pragma unroll
    for (int n = 0; n < 4; ++n) acc[m][n] = (f32x4){0.f, 0.f, 0.f, 0.f};

  const int rsel = lane & 15;
  const int ksel = (lane >> 4) * 8;

  for (int k0 = 0; k0 < K; k0 += 32) {
#pragma unroll
    for (int i = 0; i < 2; ++i) {
      const int chunk = wave * 2 + i;            // 0..7, wave-uniform
      const int flat  = chunk * 512 + lane * 8;  // bf16 idx in 128x32 tile (linear)
      const int row = flat >> 5, col = flat & 31;
      int gr = bm + row; if (gr > M - 1) gr = M - 1;
      const unsigned short* srcA = Ap + (size_t)gr * lda + (k0 + col);
      __builtin_amdgcn_global_load_lds((const __attribute__((address_space(1))) void*)srcA,
                                       (__attribute__((address_space(3))) void*)(&As[chunk * 512]),
                                       16, 0, 0);
      int gc = bn + row; if (gc > N - 1) gc = N - 1;   // clamp for N=96 tail
      const unsigned short* srcB = Bp + (size_t)gc * ldb + (k0 + col);
      __builtin_amdgcn_global_load_lds((const __attribute__((address_space(1))) void*)srcB,
                                       (__attribute__((address_space(3))) void*)(&Bs[chunk * 512]),
                                       16, 0, 0);
    }
    __syncthreads();   // compiler drains vmcnt before barrier
    bf16x8 af[4], bfv[4];
#pragma unroll
    for (int m = 0; m < 4; ++m)
      af[m] = *(const bf16x8*)&As[(wr * 64 + m * 16 + rsel) * 32 + ksel];
#pragma unroll
    for (int n = 0; n < 4; ++n)
      bfv[n] = *(const bf16x8*)&Bs[(wc * 64 + n * 16 + rsel) * 32 + ksel];
#pragma unroll
    for (int m = 0; m < 4; ++m)
#pragma unroll
      for (int n = 0; n < 4; ++n)
        acc[m][n] = __builtin_amdgcn_mfma_f32_16x16x32_bf16(af[m], bfv[n], acc[m][n], 0, 0, 0);
    __syncthreads();
  }

#pragma unroll
  for (int m = 0; m < 4; ++m) {
    const int row0 = bm + wr * 64 + m * 16 + (lane >> 4) * 4;
#pragma unroll
    for (int n = 0; n < 4; ++n) {
      const int col = bn + wc * 64 + n * 16 + rsel;
      if (col < N) {
#pragma unroll
        for (int r = 0; r < 4; ++r) {
          const int rr = row0 + r;
          if (rr < M) {
            float v = acc[m][n][r];
            if constexpr (EPI == 1) {
              v += ga.bias[col];
              v = (v > 15.f) ? v : log1pf(__expf(v));   // softplus
            }
            if constexpr (ATOMIC) {
              atomicAdd((float*)ga.C + (size_t)rr * ldc + col, v);
            } else if constexpr (OUT == 1) {
              ((unsigned short*)ga.C)[(size_t)rr * ldc + col] = f2bf(v);
            } else {
              ((float*)ga.C)[(size_t)rr * ldc + col] = v;
            }
          }
        }
      }
    }
  }
}

// ---------------- depthwise causal conv(4) + silu -> bf16 ----------------
// reads u region of xz (bf16, col offset dir*4096, row stride 8192), writes ub[dir] tight
__global__ __launch_bounds__(256)
void conv_silu_k(const unsigned short* __restrict__ xz,
                 const float* __restrict__ cw_f, const float* __restrict__ cb_f,
                 const float* __restrict__ cw_r, const float* __restrict__ cb_r,
                 unsigned short* __restrict__ ub)
{
  const int tid = threadIdx.x;
  const int d   = blockIdx.x * 256 + tid;
  const int l0  = blockIdx.y * 128;
  const int dir = blockIdx.z >> 1, b = blockIdx.z & 1;
  const unsigned short* uin = xz + (size_t)dir * 4096 + d;
  const float* cw  = dir ? cw_r : cw_f;
  const float* cb  = dir ? cb_r : cb_f;
  const float w0 = cw[d * 4 + 0], w1 = cw[d * 4 + 1], w2 = cw[d * 4 + 2], w3 = cw[d * 4 + 3];
  const float bias = cb[d];
  unsigned short* uo = ub + (size_t)dir * ((size_t)MR * DI) + d;
  const size_t rbase = (size_t)b * LL;
  float x0 = (l0 >= 3) ? bf2f(uin[(rbase + l0 - 3) * 8192]) : 0.f;
  float x1 = (l0 >= 2) ? bf2f(uin[(rbase + l0 - 2) * 8192]) : 0.f;
  float x2 = (l0 >= 1) ? bf2f(uin[(rbase + l0 - 1) * 8192]) : 0.f;
  for (int l = l0; l < l0 + 128; ++l) {
    float x3 = bf2f(uin[(rbase + l) * 8192]);
    float o = w0 * x0 + w1 * x1 + w2 * x2 + w3 * x3 + bias;
    o = o / (1.f + __expf(-o));   // silu
    uo[(rbase + l) * DI] = f2bf(o);
    x0 = x1; x1 = x2; x2 = x3;
  }
}

// ---------------- chunked selective scan ----------------
// phase A: per (dir,b,chunk,d): prodA[16], h-from-zero[16]
__global__ __launch_bounds__(256)
void scanA(const float* __restrict__ dlt, const unsigned short* __restrict__ ub,
           const float* __restrict__ xdbl, const float* __restrict__ A2,
           float* __restrict__ pAb, float* __restrict__ hb)
{
  const int tid = threadIdx.x;
  const int d = blockIdx.x * 256 + tid;
  const int c = blockIdx.y;
  const int dir = blockIdx.z >> 1, b = blockIdx.z & 1;
  __shared__ float sB[LC * DS];
  const float* xd = xdbl + (size_t)dir * (MR * 96);
  for (int i = tid; i < LC * DS; i += 256) {
    int t = i >> 4, s = i & 15;
    sB[i] = xd[(size_t)(b * LL + c * LC + t) * 96 + 64 + s];
  }
  __syncthreads();
  const float* dl_p = dlt + (size_t)dir * ((size_t)MR * DI) + d;
  const unsigned short* uu = ub + (size_t)dir * ((size_t)MR * DI) + d;
  float a2[DS];
#pragma unroll
  for (int s = 0; s < DS; ++s) a2[s] = A2[((size_t)dir * DI + d) * DS + s];
  float h[DS], pA[DS];
#pragma unroll
  for (int s = 0; s < DS; ++s) { h[s] = 0.f; pA[s] = 1.f; }
  for (int t = 0; t < LC; ++t) {
    size_t r = (size_t)b * LL + c * LC + t;
    float dl = dl_p[r * DI];
    float du = dl * bf2f(uu[r * DI]);
#pragma unroll
    for (int s = 0; s < DS; ++s) {
      float e = __expf(dl * a2[s]);
      pA[s] *= e;
      h[s] = e * h[s] + du * sB[t * DS + s];
    }
  }
  size_t base = ((((size_t)(dir * 2 + b)) * NCH + c) * DI + d) * DS;
#pragma unroll
  for (int s = 0; s < DS; ++s) { pAb[base + s] = pA[s]; hb[base + s] = h[s]; }
}

// phase B: sequential chunk combine; overwrites hb with h_init per chunk
__global__ __launch_bounds__(256)
void scanB(const float* __restrict__ pAb, float* __restrict__ hb)
{
  int i = blockIdx.x * 256 + threadIdx.x;   // 0..131071 = (dir*2+b)*32768 + d*16+s
  int db = i >> 15;
  int ds = i & 32767;
  float hrun = 0.f;
  for (int c = 0; c < NCH; ++c) {
    size_t off = (((size_t)db * NCH + c) << 15) + ds;
    float h0 = hb[off];
    float pa = pAb[off];
    hb[off] = hrun;
    hrun = pa * hrun + h0;
  }
}

// phase C (fused fwd+rev): re-scan with h_init; y = sum_s h*C + D*u; gate silu(z); add; bf16
__global__ __launch_bounds__(256)
void scanC_f(const unsigned short* __restrict__ xz, const unsigned short* __restrict__ ub,
             const float* __restrict__ dlt, const float* __restrict__ xdbl,
             const float* __restrict__ A2, const float* __restrict__ Dv_f,
             const float* __restrict__ Dv_r, const float* __restrict__ hb,
             unsigned short* __restrict__ ygb)
{
  const int tid = threadIdx.x;
  const int d = blockIdx.x * 256 + tid;
  const int c = blockIdx.y;
  const int b = blockIdx.z;
  __shared__ float sB[2][LC * DS], sC[2][LC * DS];
  for (int i = tid; i < LC * DS; i += 256) {
    int t = i >> 4, s = i & 15;
    size_t ro = (size_t)(b * LL + c * LC + t) * 96;
    sB[0][i] = xdbl[ro + 64 + s];
    sC[0][i] = xdbl[ro + 80 + s];
    sB[1][i] = xdbl[(size_t)MR * 96 + ro + 64 + s];
    sC[1][i] = xdbl[(size_t)MR * 96 + ro + 80 + s];
  }
  __syncthreads();
  float a2f[DS], a2r[DS], hf[DS], hr[DS];
  const size_t basef = ((((size_t)b) * NCH + c) * DI + d) * DS;
  const size_t baser = ((((size_t)(2 + b)) * NCH + c) * DI + d) * DS;
#pragma unroll
  for (int s = 0; s < DS; ++s) {
    a2f[s] = A2[(size_t)d * DS + s];
    a2r[s] = A2[((size_t)DI + d) * DS + s];
    hf[s] = hb[basef + s];
    hr[s] = hb[baser + s];
  }
  const float Df = Dv_f[d], Dr = Dv_r[d];
  for (int t = 0; t < LC; ++t) {
    size_t r = (size_t)b * LL + c * LC + t;
    float dlf = dlt[r * DI + d];
    float dlr = dlt[(size_t)MR * DI + r * DI + d];
    float uf = bf2f(ub[r * DI + d]);
    float ur = bf2f(ub[(size_t)MR * DI + r * DI + d]);
    float duf = dlf * uf, dur = dlr * ur;
    float yf = 0.f, yr = 0.f;
#pragma unroll
    for (int s = 0; s < DS; ++s) {
      float ef = __expf(dlf * a2f[s]);
      hf[s] = ef * hf[s] + duf * sB[0][t * DS + s];
      yf += hf[s] * sC[0][t * DS + s];
      float er = __expf(dlr * a2r[s]);
      hr[s] = er * hr[s] + dur * sB[1][t * DS + s];
      yr += hr[s] * sC[1][t * DS + s];
    }
    yf += Df * uf;
    yr += Dr * ur;
    float zf = bf2f(xz[r * 8192 + 2048 + d]);
    float zr = bf2f(xz[r * 8192 + 6144 + d]);
    float yg = yf * (zf / (1.f + __expf(-zf))) + yr * (zr / (1.f + __expf(-zr)));
    ygb[r * DI + d] = f2bf(yg);
  }
}

// ---------------- host launch ----------------

extern "C" void kernel_launch(void* const* d_in, const int* in_sizes, int n_in,
                              void* d_out, int out_size, void* d_ws, size_t ws_size,
                              hipStream_t stream)
{
  (void)in_sizes; (void)n_in; (void)out_size; (void)ws_size;
  const float* x      = (const float*)d_in[0];
  const float* mask   = (const float*)d_in[1];
  const float* inpw   = (const float*)d_in[2];
  const float* outpw  = (const float*)d_in[3];
  const float* cw_f   = (const float*)d_in[4];
  const float* cb_f   = (const float*)d_in[5];
  const float* xpw_f  = (const float*)d_in[6];
  const float* dtw_f  = (const float*)d_in[7];
  const float* dtbias_f = (const float*)d_in[8];
  const float* alog_f = (const float*)d_in[9];
  const float* Dv_f   = (const float*)d_in[10];
  const float* cw_r   = (const float*)d_in[11];
  const float* cb_r   = (const float*)d_in[12];
  const float* xpw_r  = (const float*)d_in[13];
  const float* dtw_r  = (const float*)d_in[14];
  const float* dtbias_r = (const float*)d_in[15];
  const float* alog_r = (const float*)d_in[16];
  const float* Dv_r   = (const float*)d_in[17];
  float* out = (float*)d_out;

  char* p = (char*)d_ws;
  auto carve = [&](size_t bytes) -> char* {
    char* q = p; p += (bytes + 255) & ~(size_t)255; return q;
  };
  unsigned short* xb   = (unsigned short*)carve((size_t)MR * DM * 2);
  unsigned short* Wcat = (unsigned short*)carve((size_t)8192 * 1024 * 2);
  unsigned short* xpb  = (unsigned short*)carve((size_t)2 * 96 * DI * 2);
  unsigned short* dtwb = (unsigned short*)carve((size_t)2 * DI * RK * 2);
  unsigned short* opb  = (unsigned short*)carve((size_t)DM * DI * 2);
  float*          A2   = (float*)carve((size_t)2 * DI * DS * 4);
  unsigned short* xz   = (unsigned short*)carve((size_t)MR * 8192 * 2);   // bf16 now
  float*          dlt  = (float*)carve((size_t)2 * MR * DI * 4);          // delta f32, tight
  unsigned short* ub   = (unsigned short*)carve((size_t)2 * MR * DI * 2);
  float*          xdbl = (float*)carve((size_t)2 * MR * 96 * 4);
  unsigned short* dtb  = (unsigned short*)carve((size_t)2 * MR * RK * 2);
  float*          pAb  = (float*)carve((size_t)4 * NCH * DI * DS * 4);
  float*          hb   = (float*)carve((size_t)4 * NCH * DI * DS * 4);
  unsigned short* ygb  = (unsigned short*)carve((size_t)MR * DI * 2);

  // zero-init atomic targets
  hipMemsetAsync(xdbl, 0, (size_t)2 * MR * 96 * 4, stream);
  hipMemsetAsync(out, 0, (size_t)MR * DM * 4, stream);

  // fused prep
  prep_all<<<(N_PREP + 255) / 256, 256, 0, stream>>>(
      x, mask, inpw, xpw_f, xpw_r, dtw_f, dtw_r, outpw, alog_f, alog_r,
      xb, Wcat, xpb, dtwb, opb, A2);

  // G1: xz(2048 x 8192, bf16) = xb(2048x1024) @ Wcat(8192x1024)^T   [SWZ, bf16 out]
  {
    GArg g0{xb, Wcat, xz, nullptr};
    gemm_bt<0, 1, 0, 1, 1><<<dim3(64, 16, 1), 256, 0, stream>>>(
        g0, g0, MR, 8192, 1024, DM, DM, 8192, 0);
  }
  // conv + silu -> ub (both dirs, both batches)
  conv_silu_k<<<dim3(8, 8, 4), 256, 0, stream>>>(xz, cw_f, cb_f, cw_r, cb_r, ub);
  // G2: x_dbl(2048 x 96) = ub @ x_proj^T, split-K=4, atomic accumulate
  {
    GArg g0{ub, xpb, xdbl, nullptr};
    GArg g1{ub + (size_t)MR * DI, xpb + 96 * DI, xdbl + (size_t)MR * 96, nullptr};
    gemm_bt<0, 0, 1, 0, 2><<<dim3(1, 16, 8), 256, 0, stream>>>(
        g0, g1, MR, 96, 512, DI, DI, 96, 512);
  }
  cvt_dtb<<<(2 * MR * RK + 255) / 256, 256, 0, stream>>>(xdbl, dtb);
  // G3: delta = softplus(dt @ dt_w^T + dt_b) -> dlt (tight f32, ldc=DI)
  {
    GArg g0{dtb, dtwb, dlt, dtbias_f};
    GArg g1{dtb + (size_t)MR * RK, dtwb + DI * RK, dlt + (size_t)MR * DI, dtbias_r};
    gemm_bt<1, 0, 0, 0, 2><<<dim3(16, 16, 2), 256, 0, stream>>>(
        g0, g1, MR, DI, 64, RK, RK, DI, 0);
  }
  // scan
  scanA<<<dim3(8, NCH, 4), 256, 0, stream>>>(dlt, ub, xdbl, A2, pAb, hb);
  scanB<<<dim3(512, 1, 1), 256, 0, stream>>>(pAb, hb);
  scanC_f<<<dim3(8, NCH, 2), 256, 0, stream>>>(xz, ub, dlt, xdbl, A2, Dv_f, Dv_r, hb, ygb);
  // G4: out(2048 x 1024) = ygb @ out_proj^T, split-K=2, atomic accumulate [SWZ]
  {
    GArg g0{ygb, opb, out, nullptr};
    gemm_bt<0, 0, 1, 1, 1><<<dim3(8, 16, 2), 256, 0, stream>>>(
        g0, g0, MR, DM, 1024, DI, DI, DM, 1024);
  }
}

// Round 3
// 297.950 us; speedup vs baseline: 1.1880x; 1.0807x over previous
//
#include <hip/hip_runtime.h>

#define DM   1024
#define DI   2048
#define DS   16
#define RK   64
#define NBAT 2
#define LL   1024
#define MR   (NBAT*LL)   // 2048 rows (B*L)
#define NCH  32          // scan chunks
#define LC   (LL/NCH)    // 32 steps per chunk

typedef short  bf16x8 __attribute__((ext_vector_type(8)));
typedef float  f32x4  __attribute__((ext_vector_type(4)));

__device__ __forceinline__ float bf2f(unsigned short u) {
  union { unsigned int i; float f; } v; v.i = ((unsigned int)u) << 16; return v.f;
}
__device__ __forceinline__ unsigned short f2bf(float f) {
  union { float f; unsigned int i; } v; v.f = f;
  return (unsigned short)((v.i + 0x7FFFu + ((v.i >> 16) & 1u)) >> 16);  // RNE
}

// ---------------- fused prep / convert (one launch) ----------------
#define N_XB   (MR*DM)
#define N_WCAT (8192*1024)
#define N_XPB  (96*DI)
#define N_DTWB (DI*RK)
#define N_OPB  (DM*DI)
#define N_A2   (DI*DS)
#define N_PREP (N_XB + N_WCAT + 2*N_XPB + 2*N_DTWB + N_OPB + 2*N_A2)

__global__ void prep_all(const float* __restrict__ x, const float* __restrict__ mask,
                         const float* __restrict__ W,
                         const float* __restrict__ xpw_f, const float* __restrict__ xpw_r,
                         const float* __restrict__ dtw_f, const float* __restrict__ dtw_r,
                         const float* __restrict__ outpw,
                         const float* __restrict__ Af, const float* __restrict__ Ar,
                         unsigned short* __restrict__ xb, unsigned short* __restrict__ Wcat,
                         unsigned short* __restrict__ xpb, unsigned short* __restrict__ dtwb,
                         unsigned short* __restrict__ opb, float* __restrict__ A2)
{
  int i = blockIdx.x * 256 + threadIdx.x;
  if (i < N_XB) { xb[i] = f2bf(x[i] * mask[i >> 10]); return; }
  i -= N_XB;
  if (i < N_WCAT) {
    int nrow = i >> 10, k = i & 1023;
    float w = (nrow < 4096) ? W[i] : W[(size_t)(nrow - 4096) * 1024 + (1023 - k)];
    Wcat[i] = f2bf(w); return;
  }
  i -= N_WCAT;
  if (i < N_XPB) { xpb[i] = f2bf(xpw_f[i]); return; }
  i -= N_XPB;
  if (i < N_XPB) { xpb[N_XPB + i] = f2bf(xpw_r[i]); return; }
  i -= N_XPB;
  if (i < N_DTWB) { dtwb[i] = f2bf(dtw_f[i]); return; }
  i -= N_DTWB;
  if (i < N_DTWB) { dtwb[N_DTWB + i] = f2bf(dtw_r[i]); return; }
  i -= N_DTWB;
  if (i < N_OPB) { opb[i] = f2bf(outpw[i]); return; }
  i -= N_OPB;
  if (i < N_A2) { A2[i] = -__expf(Af[i]); return; }
  i -= N_A2;
  if (i < N_A2) { A2[N_A2 + i] = -__expf(Ar[i]); return; }
}

__global__ void cvt_dtb(const float* __restrict__ xdbl, unsigned short* __restrict__ dtb) {
  int i = blockIdx.x * 256 + threadIdx.x;
  if (i < 2 * MR * RK) {
    int dir = i / (MR * RK);
    int j = i % (MR * RK);
    int r = j >> 6, k = j & 63;
    dtb[i] = f2bf(xdbl[(size_t)dir * (MR * 96) + (size_t)r * 96 + k]);
  }
}

// ---------------- bf16 MFMA GEMM, C = A(M,K) * B(N,K)^T, 128x128 tile ----------------
// 2-phase double-buffered pipeline: stage(next) issued before compute(cur),
// one __syncthreads (vmcnt drain) per K-step.

struct GArg { const unsigned short* A; const unsigned short* B; void* C; const float* bias; };

template<int EPI, int OUT, int ATOMIC, int NDIR>
__global__ __launch_bounds__(256)
void gemm_bt(GArg g0, GArg g1, int M, int N, int K, int lda, int ldb, int ldc, int koff)
{
  __shared__ __align__(16) unsigned short As[2][128 * 32];
  __shared__ __align__(16) unsigned short Bs[2][128 * 32];
  const GArg ga = (NDIR == 2 && (blockIdx.z & 1)) ? g1 : g0;
  const int kc = (NDIR == 2) ? ((int)blockIdx.z >> 1) : (int)blockIdx.z;
  const unsigned short* Ap = ga.A + (size_t)kc * koff;
  const unsigned short* Bp = ga.B + (size_t)kc * koff;

  const int tid  = threadIdx.x;
  const int wave = tid >> 6;
  const int lane = tid & 63;
  const int bm = blockIdx.y * 128;
  const int bn = blockIdx.x * 128;
  const int wr = wave >> 1, wc = wave & 1;

  f32x4 acc[4][4];
#pragma unroll
  for (int m = 0; m < 4; ++m)
#pragma unroll
    for (int n = 0; n < 4; ++n) acc[m][n] = (f32x4){0.f, 0.f, 0.f, 0.f};

  const int rsel = lane & 15;
  const int ksel = (lane >> 4) * 8;
  const int NT = K >> 5;

  // staging geometry (wave-uniform LDS dest, per-lane global src)
  const int chunk0 = wave * 2;
  const int flat0  = chunk0 * 512 + lane * 8;
  const int row0s  = flat0 >> 5, col0s = flat0 & 31;
  const int flat1  = (chunk0 + 1) * 512 + lane * 8;
  const int row1s  = flat1 >> 5, col1s = flat1 & 31;
  int grA0 = bm + row0s; if (grA0 > M - 1) grA0 = M - 1;
  int grA1 = bm + row1s; if (grA1 > M - 1) grA1 = M - 1;
  int gcB0 = bn + row0s; if (gcB0 > N - 1) gcB0 = N - 1;
  int gcB1 = bn + row1s; if (gcB1 > N - 1) gcB1 = N - 1;

#define STAGE(buf, kt)                                                                       \
  do {                                                                                       \
    const int k0_ = (kt) << 5;                                                               \
    __builtin_amdgcn_global_load_lds(                                                        \
        (const __attribute__((address_space(1))) void*)(Ap + (size_t)grA0 * lda + k0_ + col0s), \
        (__attribute__((address_space(3))) void*)(&As[buf][chunk0 * 512]), 16, 0, 0);        \
    __builtin_amdgcn_global_load_lds(                                                        \
        (const __attribute__((address_space(1))) void*)(Ap + (size_t)grA1 * lda + k0_ + col1s), \
        (__attribute__((address_space(3))) void*)(&As[buf][(chunk0 + 1) * 512]), 16, 0, 0);  \
    __builtin_amdgcn_global_load_lds(                                                        \
        (const __attribute__((address_space(1))) void*)(Bp + (size_t)gcB0 * ldb + k0_ + col0s), \
        (__attribute__((address_space(3))) void*)(&Bs[buf][chunk0 * 512]), 16, 0, 0);        \
    __builtin_amdgcn_global_load_lds(                                                        \
        (const __attribute__((address_space(1))) void*)(Bp + (size_t)gcB1 * ldb + k0_ + col1s), \
        (__attribute__((address_space(3))) void*)(&Bs[buf][(chunk0 + 1) * 512]), 16, 0, 0);  \
  } while (0)

  STAGE(0, 0);
  __syncthreads();          // drains vmcnt; tile 0 ready
  int cur = 0;
  for (int kt = 0; kt < NT; ++kt) {
    if (kt + 1 < NT) STAGE(cur ^ 1, kt + 1);   // prefetch overlaps compute below
    bf16x8 af[4], bfv[4];
#pragma unroll
    for (int m = 0; m < 4; ++m)
      af[m] = *(const bf16x8*)&As[cur][(wr * 64 + m * 16 + rsel) * 32 + ksel];
#pragma unroll
    for (int n = 0; n < 4; ++n)
      bfv[n] = *(const bf16x8*)&Bs[cur][(wc * 64 + n * 16 + rsel) * 32 + ksel];
#pragma unroll
    for (int m = 0; m < 4; ++m)
#pragma unroll
      for (int n = 0; n < 4; ++n)
        acc[m][n] = __builtin_amdgcn_mfma_f32_16x16x32_bf16(af[m], bfv[n], acc[m][n], 0, 0, 0);
    if (kt + 1 < NT) {
      __syncthreads();      // drains vmcnt: tile kt+1 landed; reads of buf cur done
      cur ^= 1;
    }
  }
#undef STAGE

#pragma unroll
  for (int m = 0; m < 4; ++m) {
    const int rowb = bm + wr * 64 + m * 16 + (lane >> 4) * 4;
#pragma unroll
    for (int n = 0; n < 4; ++n) {
      const int col = bn + wc * 64 + n * 16 + rsel;
      if (col < N) {
#pragma unroll
        for (int r = 0; r < 4; ++r) {
          const int rr = rowb + r;
          if (rr < M) {
            float v = acc[m][n][r];
            if constexpr (EPI == 1) {
              v += ga.bias[col];
              v = (v > 15.f) ? v : log1pf(__expf(v));   // softplus
            }
            if constexpr (ATOMIC) {
              atomicAdd((float*)ga.C + (size_t)rr * ldc + col, v);
            } else if constexpr (OUT == 1) {
              ((unsigned short*)ga.C)[(size_t)rr * ldc + col] = f2bf(v);
            } else {
              ((float*)ga.C)[(size_t)rr * ldc + col] = v;
            }
          }
        }
      }
    }
  }
}

// ---------------- depthwise causal conv(4) + silu -> bf16 ----------------
// 32 rows per thread, 1024 blocks
__global__ __launch_bounds__(256)
void conv_silu_k(const unsigned short* __restrict__ xz,
                 const float* __restrict__ cw_f, const float* __restrict__ cb_f,
                 const float* __restrict__ cw_r, const float* __restrict__ cb_r,
                 unsigned short* __restrict__ ub)
{
  const int tid = threadIdx.x;
  const int d   = blockIdx.x * 256 + tid;
  const int l0  = blockIdx.y * 32;
  const int dir = blockIdx.z >> 1, b = blockIdx.z & 1;
  const unsigned short* uin = xz + (size_t)dir * 4096 + d;
  const float* cw  = dir ? cw_r : cw_f;
  const float* cb  = dir ? cb_r : cb_f;
  const float w0 = cw[d * 4 + 0], w1 = cw[d * 4 + 1], w2 = cw[d * 4 + 2], w3 = cw[d * 4 + 3];
  const float bias = cb[d];
  unsigned short* uo = ub + (size_t)dir * ((size_t)MR * DI) + d;
  const size_t rbase = (size_t)b * LL;
  float x0 = (l0 >= 3) ? bf2f(uin[(rbase + l0 - 3) * 8192]) : 0.f;
  float x1 = (l0 >= 2) ? bf2f(uin[(rbase + l0 - 2) * 8192]) : 0.f;
  float x2 = (l0 >= 1) ? bf2f(uin[(rbase + l0 - 1) * 8192]) : 0.f;
  for (int l = l0; l < l0 + 32; ++l) {
    float x3 = bf2f(uin[(rbase + l) * 8192]);
    float o = w0 * x0 + w1 * x1 + w2 * x2 + w3 * x3 + bias;
    o = o / (1.f + __expf(-o));   // silu
    uo[(rbase + l) * DI] = f2bf(o);
    x0 = x1; x1 = x2; x2 = x3;
  }
}

// ---------------- chunked selective scan ----------------
__global__ __launch_bounds__(256)
void scanA(const float* __restrict__ dlt, const unsigned short* __restrict__ ub,
           const float* __restrict__ xdbl, const float* __restrict__ A2,
           float* __restrict__ pAb, float* __restrict__ hb)
{
  const int tid = threadIdx.x;
  const int d = blockIdx.x * 256 + tid;
  const int c = blockIdx.y;
  const int dir = blockIdx.z >> 1, b = blockIdx.z & 1;
  __shared__ float sB[LC * DS];
  const float* xd = xdbl + (size_t)dir * (MR * 96);
  for (int i = tid; i < LC * DS; i += 256) {
    int t = i >> 4, s = i & 15;
    sB[i] = xd[(size_t)(b * LL + c * LC + t) * 96 + 64 + s];
  }
  __syncthreads();
  const float* dl_p = dlt + (size_t)dir * ((size_t)MR * DI) + d;
  const unsigned short* uu = ub + (size_t)dir * ((size_t)MR * DI) + d;
  float a2[DS];
#pragma unroll
  for (int s = 0; s < DS; ++s) a2[s] = A2[((size_t)dir * DI + d) * DS + s];
  float h[DS], pA[DS];
#pragma unroll
  for (int s = 0; s < DS; ++s) { h[s] = 0.f; pA[s] = 1.f; }
  for (int t = 0; t < LC; ++t) {
    size_t r = (size_t)b * LL + c * LC + t;
    float dl = dl_p[r * DI];
    float du = dl * bf2f(uu[r * DI]);
#pragma unroll
    for (int s = 0; s < DS; ++s) {
      float e = __expf(dl * a2[s]);
      pA[s] *= e;
      h[s] = e * h[s] + du * sB[t * DS + s];
    }
  }
  size_t base = ((((size_t)(dir * 2 + b)) * NCH + c) * DI + d) * DS;
#pragma unroll
  for (int s = 0; s < DS; ++s) { pAb[base + s] = pA[s]; hb[base + s] = h[s]; }
}

__global__ __launch_bounds__(256)
void scanB(const float* __restrict__ pAb, float* __restrict__ hb)
{
  int i = blockIdx.x * 256 + threadIdx.x;
  int db = i >> 15;
  int ds = i & 32767;
  float hrun = 0.f;
  for (int c = 0; c < NCH; ++c) {
    size_t off = (((size_t)db * NCH + c) << 15) + ds;
    float h0 = hb[off];
    float pa = pAb[off];
    hb[off] = hrun;
    hrun = pa * hrun + h0;
  }
}

__global__ __launch_bounds__(256)
void scanC_f(const unsigned short* __restrict__ xz, const unsigned short* __restrict__ ub,
             const float* __restrict__ dlt, const float* __restrict__ xdbl,
             const float* __restrict__ A2, const float* __restrict__ Dv_f,
             const float* __restrict__ Dv_r, const float* __restrict__ hb,
             unsigned short* __restrict__ ygb)
{
  const int tid = threadIdx.x;
  const int d = blockIdx.x * 256 + tid;
  const int c = blockIdx.y;
  const int b = blockIdx.z;
  __shared__ float sB[2][LC * DS], sC[2][LC * DS];
  for (int i = tid; i < LC * DS; i += 256) {
    int t = i >> 4, s = i & 15;
    size_t ro = (size_t)(b * LL + c * LC + t) * 96;
    sB[0][i] = xdbl[ro + 64 + s];
    sC[0][i] = xdbl[ro + 80 + s];
    sB[1][i] = xdbl[(size_t)MR * 96 + ro + 64 + s];
    sC[1][i] = xdbl[(size_t)MR * 96 + ro + 80 + s];
  }
  __syncthreads();
  float a2f[DS], a2r[DS], hf[DS], hr[DS];
  const size_t basef = ((((size_t)b) * NCH + c) * DI + d) * DS;
  const size_t baser = ((((size_t)(2 + b)) * NCH + c) * DI + d) * DS;
#pragma unroll
  for (int s = 0; s < DS; ++s) {
    a2f[s] = A2[(size_t)d * DS + s];
    a2r[s] = A2[((size_t)DI + d) * DS + s];
    hf[s] = hb[basef + s];
    hr[s] = hb[baser + s];
  }
  const float Df = Dv_f[d], Dr = Dv_r[d];
  for (int t = 0; t < LC; ++t) {
    size_t r = (size_t)b * LL + c * LC + t;
    float dlf = dlt[r * DI + d];
    float dlr = dlt[(size_t)MR * DI + r * DI + d];
    float uf = bf2f(ub[r * DI + d]);
    float ur = bf2f(ub[(size_t)MR * DI + r * DI + d]);
    float duf = dlf * uf, dur = dlr * ur;
    float yf = 0.f, yr = 0.f;
#pragma unroll
    for (int s = 0; s < DS; ++s) {
      float ef = __expf(dlf * a2f[s]);
      hf[s] = ef * hf[s] + duf * sB[0][t * DS + s];
      yf += hf[s] * sC[0][t * DS + s];
      float er = __expf(dlr * a2r[s]);
      hr[s] = er * hr[s] + dur * sB[1][t * DS + s];
      yr += hr[s] * sC[1][t * DS + s];
    }
    yf += Df * uf;
    yr += Dr * ur;
    float zf = bf2f(xz[r * 8192 + 2048 + d]);
    float zr = bf2f(xz[r * 8192 + 6144 + d]);
    float yg = yf * (zf / (1.f + __expf(-zf))) + yr * (zr / (1.f + __expf(-zr)));
    ygb[r * DI + d] = f2bf(yg);
  }
}

// ---------------- host launch ----------------

extern "C" void kernel_launch(void* const* d_in, const int* in_sizes, int n_in,
                              void* d_out, int out_size, void* d_ws, size_t ws_size,
                              hipStream_t stream)
{
  (void)in_sizes; (void)n_in; (void)out_size; (void)ws_size;
  const float* x      = (const float*)d_in[0];
  const float* mask   = (const float*)d_in[1];
  const float* inpw   = (const float*)d_in[2];
  const float* outpw  = (const float*)d_in[3];
  const float* cw_f   = (const float*)d_in[4];
  const float* cb_f   = (const float*)d_in[5];
  const float* xpw_f  = (const float*)d_in[6];
  const float* dtw_f  = (const float*)d_in[7];
  const float* dtbias_f = (const float*)d_in[8];
  const float* alog_f = (const float*)d_in[9];
  const float* Dv_f   = (const float*)d_in[10];
  const float* cw_r   = (const float*)d_in[11];
  const float* cb_r   = (const float*)d_in[12];
  const float* xpw_r  = (const float*)d_in[13];
  const float* dtw_r  = (const float*)d_in[14];
  const float* dtbias_r = (const float*)d_in[15];
  const float* alog_r = (const float*)d_in[16];
  const float* Dv_r   = (const float*)d_in[17];
  float* out = (float*)d_out;

  char* p = (char*)d_ws;
  auto carve = [&](size_t bytes) -> char* {
    char* q = p; p += (bytes + 255) & ~(size_t)255; return q;
  };
  unsigned short* xb   = (unsigned short*)carve((size_t)MR * DM * 2);
  unsigned short* Wcat = (unsigned short*)carve((size_t)8192 * 1024 * 2);
  unsigned short* xpb  = (unsigned short*)carve((size_t)2 * 96 * DI * 2);
  unsigned short* dtwb = (unsigned short*)carve((size_t)2 * DI * RK * 2);
  unsigned short* opb  = (unsigned short*)carve((size_t)DM * DI * 2);
  float*          A2   = (float*)carve((size_t)2 * DI * DS * 4);
  unsigned short* xz   = (unsigned short*)carve((size_t)MR * 8192 * 2);
  float*          dlt  = (float*)carve((size_t)2 * MR * DI * 4);
  unsigned short* ub   = (unsigned short*)carve((size_t)2 * MR * DI * 2);
  float*          xdbl = (float*)carve((size_t)2 * MR * 96 * 4);
  unsigned short* dtb  = (unsigned short*)carve((size_t)2 * MR * RK * 2);
  float*          pAb  = (float*)carve((size_t)4 * NCH * DI * DS * 4);
  float*          hb   = (float*)carve((size_t)4 * NCH * DI * DS * 4);
  unsigned short* ygb  = (unsigned short*)carve((size_t)MR * DI * 2);

  hipMemsetAsync(xdbl, 0, (size_t)2 * MR * 96 * 4, stream);
  hipMemsetAsync(out, 0, (size_t)MR * DM * 4, stream);

  prep_all<<<(N_PREP + 255) / 256, 256, 0, stream>>>(
      x, mask, inpw, xpw_f, xpw_r, dtw_f, dtw_r, outpw, alog_f, alog_r,
      xb, Wcat, xpb, dtwb, opb, A2);

  // G1: xz(2048 x 8192, bf16) = xb @ Wcat^T   [no swizzle — natural order is L2-optimal]
  {
    GArg g0{xb, Wcat, xz, nullptr};
    gemm_bt<0, 1, 0, 1><<<dim3(64, 16, 1), 256, 0, stream>>>(
        g0, g0, MR, 8192, 1024, DM, DM, 8192, 0);
  }
  // conv + silu -> ub
  conv_silu_k<<<dim3(8, 32, 4), 256, 0, stream>>>(xz, cw_f, cb_f, cw_r, cb_r, ub);
  // G2: x_dbl = ub @ x_proj^T, split-K=8, atomic accumulate (256 blocks)
  {
    GArg g0{ub, xpb, xdbl, nullptr};
    GArg g1{ub + (size_t)MR * DI, xpb + 96 * DI, xdbl + (size_t)MR * 96, nullptr};
    gemm_bt<0, 0, 1, 2><<<dim3(1, 16, 16), 256, 0, stream>>>(
        g0, g1, MR, 96, 256, DI, DI, 96, 256);
  }
  cvt_dtb<<<(2 * MR * RK + 255) / 256, 256, 0, stream>>>(xdbl, dtb);
  // G3: delta = softplus(dt @ dt_w^T + dt_b) -> dlt (tight f32)
  {
    GArg g0{dtb, dtwb, dlt, dtbias_f};
    GArg g1{dtb + (size_t)MR * RK, dtwb + DI * RK, dlt + (size_t)MR * DI, dtbias_r};
    gemm_bt<1, 0, 0, 2><<<dim3(16, 16, 2), 256, 0, stream>>>(
        g0, g1, MR, DI, 64, RK, RK, DI, 0);
  }
  scanA<<<dim3(8, NCH, 4), 256, 0, stream>>>(dlt, ub, xdbl, A2, pAb, hb);
  scanB<<<dim3(512, 1, 1), 256, 0, stream>>>(pAb, hb);
  scanC_f<<<dim3(8, NCH, 2), 256, 0, stream>>>(xz, ub, dlt, xdbl, A2, Dv_f, Dv_r, hb, ygb);
  // G4: out = ygb @ out_proj^T, split-K=4, atomic accumulate (512 blocks)
  {
    GArg g0{ygb, opb, out, nullptr};
    gemm_bt<0, 0, 1, 1><<<dim3(8, 16, 4), 256, 0, stream>>>(
        g0, g0, MR, DM, 512, DI, DI, DM, 512);
  }
}

// Round 4
// 294.562 us; speedup vs baseline: 1.2017x; 1.0115x over previous
//
#include <hip/hip_runtime.h>

#define DM   1024
#define DI   2048
#define DS   16
#define RK   64
#define NBAT 2
#define LL   1024
#define MR   (NBAT*LL)   // 2048 rows (B*L)
#define NCH  64          // scan chunks
#define LC   (LL/NCH)    // 16 steps per chunk

typedef short  bf16x8 __attribute__((ext_vector_type(8)));
typedef float  f32x4  __attribute__((ext_vector_type(4)));

__device__ __forceinline__ float bf2f(unsigned short u) {
  union { unsigned int i; float f; } v; v.i = ((unsigned int)u) << 16; return v.f;
}
__device__ __forceinline__ unsigned short f2bf(float f) {
  union { float f; unsigned int i; } v; v.f = f;
  return (unsigned short)((v.i + 0x7FFFu + ((v.i >> 16) & 1u)) >> 16);  // RNE
}

// ---------------- fused prep / convert (one launch) ----------------
#define N_XB   (MR*DM)
#define N_WCAT (8192*1024)
#define N_XPB  (96*DI)
#define N_DTWB (DI*RK)
#define N_OPB  (DM*DI)
#define N_A2   (DI*DS)
#define N_PREP (N_XB + N_WCAT + 2*N_XPB + 2*N_DTWB + N_OPB + 2*N_A2)

__global__ void prep_all(const float* __restrict__ x, const float* __restrict__ mask,
                         const float* __restrict__ W,
                         const float* __restrict__ xpw_f, const float* __restrict__ xpw_r,
                         const float* __restrict__ dtw_f, const float* __restrict__ dtw_r,
                         const float* __restrict__ outpw,
                         const float* __restrict__ Af, const float* __restrict__ Ar,
                         unsigned short* __restrict__ xb, unsigned short* __restrict__ Wcat,
                         unsigned short* __restrict__ xpb, unsigned short* __restrict__ dtwb,
                         unsigned short* __restrict__ opb, float* __restrict__ A2)
{
  int i = blockIdx.x * 256 + threadIdx.x;
  if (i < N_XB) { xb[i] = f2bf(x[i] * mask[i >> 10]); return; }
  i -= N_XB;
  if (i < N_WCAT) {
    int nrow = i >> 10, k = i & 1023;
    float w = (nrow < 4096) ? W[i] : W[(size_t)(nrow - 4096) * 1024 + (1023 - k)];
    Wcat[i] = f2bf(w); return;
  }
  i -= N_WCAT;
  if (i < N_XPB) { xpb[i] = f2bf(xpw_f[i]); return; }
  i -= N_XPB;
  if (i < N_XPB) { xpb[N_XPB + i] = f2bf(xpw_r[i]); return; }
  i -= N_XPB;
  if (i < N_DTWB) { dtwb[i] = f2bf(dtw_f[i]); return; }
  i -= N_DTWB;
  if (i < N_DTWB) { dtwb[N_DTWB + i] = f2bf(dtw_r[i]); return; }
  i -= N_DTWB;
  if (i < N_OPB) { opb[i] = f2bf(outpw[i]); return; }
  i -= N_OPB;
  if (i < N_A2) { A2[i] = -__expf(Af[i]); return; }
  i -= N_A2;
  if (i < N_A2) { A2[N_A2 + i] = -__expf(Ar[i]); return; }
}

__global__ void cvt_dtb(const float* __restrict__ xdbl, unsigned short* __restrict__ dtb) {
  int i = blockIdx.x * 256 + threadIdx.x;
  if (i < 2 * MR * RK) {
    int dir = i / (MR * RK);
    int j = i % (MR * RK);
    int r = j >> 6, k = j & 63;
    dtb[i] = f2bf(xdbl[(size_t)dir * (MR * 96) + (size_t)r * 96 + k]);
  }
}

// ---------------- bf16 MFMA GEMM, C = A(M,K) * B(N,K)^T, 128x128 tile ----------------
// 2-phase double-buffered pipeline: stage(next) issued before compute(cur),
// one __syncthreads (vmcnt drain) per K-step.

struct GArg { const unsigned short* A; const unsigned short* B; void* C; const float* bias; };

template<int EPI, int OUT, int ATOMIC, int NDIR>
__global__ __launch_bounds__(256)
void gemm_bt(GArg g0, GArg g1, int M, int N, int K, int lda, int ldb, int ldc, int koff)
{
  __shared__ __align__(16) unsigned short As[2][128 * 32];
  __shared__ __align__(16) unsigned short Bs[2][128 * 32];
  const GArg ga = (NDIR == 2 && (blockIdx.z & 1)) ? g1 : g0;
  const int kc = (NDIR == 2) ? ((int)blockIdx.z >> 1) : (int)blockIdx.z;
  const unsigned short* Ap = ga.A + (size_t)kc * koff;
  const unsigned short* Bp = ga.B + (size_t)kc * koff;

  const int tid  = threadIdx.x;
  const int wave = tid >> 6;
  const int lane = tid & 63;
  const int bm = blockIdx.y * 128;
  const int bn = blockIdx.x * 128;
  const int wr = wave >> 1, wc = wave & 1;

  f32x4 acc[4][4];
#pragma unroll
  for (int m = 0; m < 4; ++m)
#pragma unroll
    for (int n = 0; n < 4; ++n) acc[m][n] = (f32x4){0.f, 0.f, 0.f, 0.f};

  const int rsel = lane & 15;
  const int ksel = (lane >> 4) * 8;
  const int NT = K >> 5;

  const int chunk0 = wave * 2;
  const int flat0  = chunk0 * 512 + lane * 8;
  const int row0s  = flat0 >> 5, col0s = flat0 & 31;
  const int flat1  = (chunk0 + 1) * 512 + lane * 8;
  const int row1s  = flat1 >> 5, col1s = flat1 & 31;
  int grA0 = bm + row0s; if (grA0 > M - 1) grA0 = M - 1;
  int grA1 = bm + row1s; if (grA1 > M - 1) grA1 = M - 1;
  int gcB0 = bn + row0s; if (gcB0 > N - 1) gcB0 = N - 1;
  int gcB1 = bn + row1s; if (gcB1 > N - 1) gcB1 = N - 1;

#define STAGE(buf, kt)                                                                       \
  do {                                                                                       \
    const int k0_ = (kt) << 5;                                                               \
    __builtin_amdgcn_global_load_lds(                                                        \
        (const __attribute__((address_space(1))) void*)(Ap + (size_t)grA0 * lda + k0_ + col0s), \
        (__attribute__((address_space(3))) void*)(&As[buf][chunk0 * 512]), 16, 0, 0);        \
    __builtin_amdgcn_global_load_lds(                                                        \
        (const __attribute__((address_space(1))) void*)(Ap + (size_t)grA1 * lda + k0_ + col1s), \
        (__attribute__((address_space(3))) void*)(&As[buf][(chunk0 + 1) * 512]), 16, 0, 0);  \
    __builtin_amdgcn_global_load_lds(                                                        \
        (const __attribute__((address_space(1))) void*)(Bp + (size_t)gcB0 * ldb + k0_ + col0s), \
        (__attribute__((address_space(3))) void*)(&Bs[buf][chunk0 * 512]), 16, 0, 0);        \
    __builtin_amdgcn_global_load_lds(                                                        \
        (const __attribute__((address_space(1))) void*)(Bp + (size_t)gcB1 * ldb + k0_ + col1s), \
        (__attribute__((address_space(3))) void*)(&Bs[buf][(chunk0 + 1) * 512]), 16, 0, 0);  \
  } while (0)

  STAGE(0, 0);
  __syncthreads();
  int cur = 0;
  for (int kt = 0; kt < NT; ++kt) {
    if (kt + 1 < NT) STAGE(cur ^ 1, kt + 1);
    bf16x8 af[4], bfv[4];
#pragma unroll
    for (int m = 0; m < 4; ++m)
      af[m] = *(const bf16x8*)&As[cur][(wr * 64 + m * 16 + rsel) * 32 + ksel];
#pragma unroll
    for (int n = 0; n < 4; ++n)
      bfv[n] = *(const bf16x8*)&Bs[cur][(wc * 64 + n * 16 + rsel) * 32 + ksel];
#pragma unroll
    for (int m = 0; m < 4; ++m)
#pragma unroll
      for (int n = 0; n < 4; ++n)
        acc[m][n] = __builtin_amdgcn_mfma_f32_16x16x32_bf16(af[m], bfv[n], acc[m][n], 0, 0, 0);
    if (kt + 1 < NT) {
      __syncthreads();
      cur ^= 1;
    }
  }
#undef STAGE

#pragma unroll
  for (int m = 0; m < 4; ++m) {
    const int rowb = bm + wr * 64 + m * 16 + (lane >> 4) * 4;
#pragma unroll
    for (int n = 0; n < 4; ++n) {
      const int col = bn + wc * 64 + n * 16 + rsel;
      if (col < N) {
#pragma unroll
        for (int r = 0; r < 4; ++r) {
          const int rr = rowb + r;
          if (rr < M) {
            float v = acc[m][n][r];
            if constexpr (EPI == 1) {
              v += ga.bias[col];
              v = (v > 15.f) ? v : log1pf(__expf(v));   // softplus
            }
            if constexpr (ATOMIC) {
              atomicAdd((float*)ga.C + (size_t)rr * ldc + col, v);
            } else if constexpr (OUT == 1) {
              ((unsigned short*)ga.C)[(size_t)rr * ldc + col] = f2bf(v);
            } else {
              ((float*)ga.C)[(size_t)rr * ldc + col] = v;
            }
          }
        }
      }
    }
  }
}

// ---------------- depthwise causal conv(4) + silu -> bf16 ----------------
__global__ __launch_bounds__(256)
void conv_silu_k(const unsigned short* __restrict__ xz,
                 const float* __restrict__ cw_f, const float* __restrict__ cb_f,
                 const float* __restrict__ cw_r, const float* __restrict__ cb_r,
                 unsigned short* __restrict__ ub)
{
  const int tid = threadIdx.x;
  const int d   = blockIdx.x * 256 + tid;
  const int l0  = blockIdx.y * 32;
  const int dir = blockIdx.z >> 1, b = blockIdx.z & 1;
  const unsigned short* uin = xz + (size_t)dir * 4096 + d;
  const float* cw  = dir ? cw_r : cw_f;
  const float* cb  = dir ? cb_r : cb_f;
  const float w0 = cw[d * 4 + 0], w1 = cw[d * 4 + 1], w2 = cw[d * 4 + 2], w3 = cw[d * 4 + 3];
  const float bias = cb[d];
  unsigned short* uo = ub + (size_t)dir * ((size_t)MR * DI) + d;
  const size_t rbase = (size_t)b * LL;
  float x0 = (l0 >= 3) ? bf2f(uin[(rbase + l0 - 3) * 8192]) : 0.f;
  float x1 = (l0 >= 2) ? bf2f(uin[(rbase + l0 - 2) * 8192]) : 0.f;
  float x2 = (l0 >= 1) ? bf2f(uin[(rbase + l0 - 1) * 8192]) : 0.f;
  for (int l = l0; l < l0 + 32; ++l) {
    float x3 = bf2f(uin[(rbase + l) * 8192]);
    float o = w0 * x0 + w1 * x1 + w2 * x2 + w3 * x3 + bias;
    o = o / (1.f + __expf(-o));   // silu
    uo[(rbase + l) * DI] = f2bf(o);
    x0 = x1; x1 = x2; x2 = x3;
  }
}

// ---------------- chunked selective scan ----------------
// phase A: per (dir,b,chunk,d): prodA[16], h-from-zero[16]
__global__ __launch_bounds__(256)
void scanA(const float* __restrict__ dlt, const unsigned short* __restrict__ ub,
           const float* __restrict__ xdbl, const float* __restrict__ A2,
           float* __restrict__ pAb, float* __restrict__ hb)
{
  const int tid = threadIdx.x;
  const int d = blockIdx.x * 256 + tid;
  const int c = blockIdx.y;
  const int dir = blockIdx.z >> 1, b = blockIdx.z & 1;
  __shared__ float sB[LC * DS];
  const float* xd = xdbl + (size_t)dir * (MR * 96);
  for (int i = tid; i < LC * DS; i += 256) {
    int t = i >> 4, s = i & 15;
    sB[i] = xd[(size_t)(b * LL + c * LC + t) * 96 + 64 + s];
  }
  __syncthreads();
  const float* dl_p = dlt + (size_t)dir * ((size_t)MR * DI) + d;
  const unsigned short* uu = ub + (size_t)dir * ((size_t)MR * DI) + d;
  float a2[DS];
#pragma unroll
  for (int s = 0; s < DS; ++s) a2[s] = A2[((size_t)dir * DI + d) * DS + s];
  float h[DS], pA[DS];
#pragma unroll
  for (int s = 0; s < DS; ++s) { h[s] = 0.f; pA[s] = 1.f; }
  for (int t = 0; t < LC; ++t) {
    size_t r = (size_t)b * LL + c * LC + t;
    float dl = dl_p[r * DI];
    float du = dl * bf2f(uu[r * DI]);
#pragma unroll
    for (int s = 0; s < DS; ++s) {
      float e = __expf(dl * a2[s]);
      pA[s] *= e;
      h[s] = e * h[s] + du * sB[t * DS + s];
    }
  }
  size_t base = ((((size_t)(dir * 2 + b)) * NCH + c) * DI + d) * DS;
#pragma unroll
  for (int s = 0; s < DS; ++s) { pAb[base + s] = pA[s]; hb[base + s] = h[s]; }
}

// phase B: sequential chunk combine; overwrites hb with h_init per chunk
__global__ __launch_bounds__(256)
void scanB(const float* __restrict__ pAb, float* __restrict__ hb)
{
  int i = blockIdx.x * 256 + threadIdx.x;   // (dir*2+b)*32768 + d*16+s
  int db = i >> 15;
  int ds = i & 32767;
  float hrun = 0.f;
  for (int c = 0; c < NCH; ++c) {
    size_t off = (((size_t)db * NCH + c) << 15) + ds;
    float h0 = hb[off];
    float pa = pAb[off];
    hb[off] = hrun;
    hrun = pa * hrun + h0;
  }
}

// phase C (per-dir): re-scan with h_init; y = sum_s h*C + D*u; gate silu(z);
// write bf16 partial ygp[dir]
__global__ __launch_bounds__(256)
void scanC_d(const unsigned short* __restrict__ xz, const unsigned short* __restrict__ ub,
             const float* __restrict__ dlt, const float* __restrict__ xdbl,
             const float* __restrict__ A2, const float* __restrict__ Dv_f,
             const float* __restrict__ Dv_r, const float* __restrict__ hb,
             unsigned short* __restrict__ ygp)
{
  const int tid = threadIdx.x;
  const int d = blockIdx.x * 256 + tid;
  const int c = blockIdx.y;
  const int dir = blockIdx.z >> 1, b = blockIdx.z & 1;
  __shared__ float sB[LC * DS], sC[LC * DS];
  const float* xd = xdbl + (size_t)dir * (MR * 96);
  for (int i = tid; i < LC * DS; i += 256) {
    int t = i >> 4, s = i & 15;
    size_t ro = (size_t)(b * LL + c * LC + t) * 96;
    sB[i] = xd[ro + 64 + s];
    sC[i] = xd[ro + 80 + s];
  }
  __syncthreads();
  const float* dl_p = dlt + (size_t)dir * ((size_t)MR * DI) + d;
  const unsigned short* uu = ub + (size_t)dir * ((size_t)MR * DI) + d;
  float a2[DS], h[DS];
  const size_t base = ((((size_t)(dir * 2 + b)) * NCH + c) * DI + d) * DS;
#pragma unroll
  for (int s = 0; s < DS; ++s) {
    a2[s] = A2[((size_t)dir * DI + d) * DS + s];
    h[s] = hb[base + s];
  }
  const float Dd = dir ? Dv_r[d] : Dv_f[d];
  unsigned short* yo = ygp + (size_t)dir * ((size_t)MR * DI) + d;
  for (int t = 0; t < LC; ++t) {
    size_t r = (size_t)b * LL + c * LC + t;
    float dl = dl_p[r * DI];
    float uf = bf2f(uu[r * DI]);
    float du = dl * uf;
    float y = 0.f;
#pragma unroll
    for (int s = 0; s < DS; ++s) {
      float e = __expf(dl * a2[s]);
      h[s] = e * h[s] + du * sB[t * DS + s];
      y += h[s] * sC[t * DS + s];
    }
    y += Dd * uf;
    float z = bf2f(xz[r * 8192 + 2048 + dir * 4096 + d]);
    float yg = y * (z / (1.f + __expf(-z)));
    yo[r * DI] = f2bf(yg);
  }
}

// combine: ygb = bf16(ygf + ygr), 4 elems/thread
__global__ void add_bf(const unsigned short* __restrict__ ygp, unsigned short* __restrict__ ygb)
{
  int i = blockIdx.x * 256 + threadIdx.x;
  if (i < MR * DI / 4) {
    const ushort4 a = ((const ushort4*)ygp)[i];
    const ushort4 b = ((const ushort4*)(ygp + (size_t)MR * DI))[i];
    ushort4 o;
    o.x = f2bf(bf2f(a.x) + bf2f(b.x));
    o.y = f2bf(bf2f(a.y) + bf2f(b.y));
    o.z = f2bf(bf2f(a.z) + bf2f(b.z));
    o.w = f2bf(bf2f(a.w) + bf2f(b.w));
    ((ushort4*)ygb)[i] = o;
  }
}

// ---------------- host launch ----------------

extern "C" void kernel_launch(void* const* d_in, const int* in_sizes, int n_in,
                              void* d_out, int out_size, void* d_ws, size_t ws_size,
                              hipStream_t stream)
{
  (void)in_sizes; (void)n_in; (void)out_size; (void)ws_size;
  const float* x      = (const float*)d_in[0];
  const float* mask   = (const float*)d_in[1];
  const float* inpw   = (const float*)d_in[2];
  const float* outpw  = (const float*)d_in[3];
  const float* cw_f   = (const float*)d_in[4];
  const float* cb_f   = (const float*)d_in[5];
  const float* xpw_f  = (const float*)d_in[6];
  const float* dtw_f  = (const float*)d_in[7];
  const float* dtbias_f = (const float*)d_in[8];
  const float* alog_f = (const float*)d_in[9];
  const float* Dv_f   = (const float*)d_in[10];
  const float* cw_r   = (const float*)d_in[11];
  const float* cb_r   = (const float*)d_in[12];
  const float* xpw_r  = (const float*)d_in[13];
  const float* dtw_r  = (const float*)d_in[14];
  const float* dtbias_r = (const float*)d_in[15];
  const float* alog_r = (const float*)d_in[16];
  const float* Dv_r   = (const float*)d_in[17];
  float* out = (float*)d_out;

  char* p = (char*)d_ws;
  auto carve = [&](size_t bytes) -> char* {
    char* q = p; p += (bytes + 255) & ~(size_t)255; return q;
  };
  unsigned short* xb   = (unsigned short*)carve((size_t)MR * DM * 2);
  unsigned short* Wcat = (unsigned short*)carve((size_t)8192 * 1024 * 2);
  unsigned short* xpb  = (unsigned short*)carve((size_t)2 * 96 * DI * 2);
  unsigned short* dtwb = (unsigned short*)carve((size_t)2 * DI * RK * 2);
  unsigned short* opb  = (unsigned short*)carve((size_t)DM * DI * 2);
  float*          A2   = (float*)carve((size_t)2 * DI * DS * 4);
  unsigned short* xz   = (unsigned short*)carve((size_t)MR * 8192 * 2);
  float*          dlt  = (float*)carve((size_t)2 * MR * DI * 4);
  unsigned short* ub   = (unsigned short*)carve((size_t)2 * MR * DI * 2);
  float*          xdbl = (float*)carve((size_t)2 * MR * 96 * 4);
  unsigned short* dtb  = (unsigned short*)carve((size_t)2 * MR * RK * 2);
  float*          pAb  = (float*)carve((size_t)4 * NCH * DI * DS * 4);
  float*          hb   = (float*)carve((size_t)4 * NCH * DI * DS * 4);
  unsigned short* ygb  = (unsigned short*)carve((size_t)MR * DI * 2);
  // per-dir yg partials alias Wcat (dead after G1; 2*MR*DI == N_WCAT exactly)
  unsigned short* ygp  = Wcat;

  hipMemsetAsync(xdbl, 0, (size_t)2 * MR * 96 * 4, stream);
  hipMemsetAsync(out, 0, (size_t)MR * DM * 4, stream);

  prep_all<<<(N_PREP + 255) / 256, 256, 0, stream>>>(
      x, mask, inpw, xpw_f, xpw_r, dtw_f, dtw_r, outpw, alog_f, alog_r,
      xb, Wcat, xpb, dtwb, opb, A2);

  // G1: xz(2048 x 8192, bf16) = xb @ Wcat^T
  {
    GArg g0{xb, Wcat, xz, nullptr};
    gemm_bt<0, 1, 0, 1><<<dim3(64, 16, 1), 256, 0, stream>>>(
        g0, g0, MR, 8192, 1024, DM, DM, 8192, 0);
  }
  // conv + silu -> ub
  conv_silu_k<<<dim3(8, 32, 4), 256, 0, stream>>>(xz, cw_f, cb_f, cw_r, cb_r, ub);
  // G2: x_dbl = ub @ x_proj^T, split-K=8, atomic accumulate
  {
    GArg g0{ub, xpb, xdbl, nullptr};
    GArg g1{ub + (size_t)MR * DI, xpb + 96 * DI, xdbl + (size_t)MR * 96, nullptr};
    gemm_bt<0, 0, 1, 2><<<dim3(1, 16, 16), 256, 0, stream>>>(
        g0, g1, MR, 96, 256, DI, DI, 96, 256);
  }
  cvt_dtb<<<(2 * MR * RK + 255) / 256, 256, 0, stream>>>(xdbl, dtb);
  // G3: delta = softplus(dt @ dt_w^T + dt_b) -> dlt (tight f32)
  {
    GArg g0{dtb, dtwb, dlt, dtbias_f};
    GArg g1{dtb + (size_t)MR * RK, dtwb + DI * RK, dlt + (size_t)MR * DI, dtbias_r};
    gemm_bt<1, 0, 0, 2><<<dim3(16, 16, 2), 256, 0, stream>>>(
        g0, g1, MR, DI, 64, RK, RK, DI, 0);
  }
  scanA<<<dim3(8, NCH, 4), 256, 0, stream>>>(dlt, ub, xdbl, A2, pAb, hb);
  scanB<<<dim3(512, 1, 1), 256, 0, stream>>>(pAb, hb);
  scanC_d<<<dim3(8, NCH, 4), 256, 0, stream>>>(xz, ub, dlt, xdbl, A2, Dv_f, Dv_r, hb, ygp);
  add_bf<<<(MR * DI / 4 + 255) / 256, 256, 0, stream>>>(ygp, ygb);
  // G4: out = ygb @ out_proj^T, split-K=4, atomic accumulate
  {
    GArg g0{ygb, opb, out, nullptr};
    gemm_bt<0, 0, 1, 1><<<dim3(8, 16, 4), 256, 0, stream>>>(
        g0, g0, MR, DM, 512, DI, DI, DM, 512);
  }
}

// Round 5
// 272.401 us; speedup vs baseline: 1.2995x; 1.0814x over previous
//
#include <hip/hip_runtime.h>

#define DM   1024
#define DI   2048
#define DS   16
#define RK   64
#define NBAT 2
#define LL   1024
#define MR   (NBAT*LL)   // 2048 rows (B*L)
#define NCH  64          // scan chunks
#define LC   (LL/NCH)    // 16 steps per chunk

typedef short  bf16x8 __attribute__((ext_vector_type(8)));
typedef float  f32x4  __attribute__((ext_vector_type(4)));

__device__ __forceinline__ float bf2f(unsigned short u) {
  union { unsigned int i; float f; } v; v.i = ((unsigned int)u) << 16; return v.f;
}
__device__ __forceinline__ unsigned short f2bf(float f) {
  union { float f; unsigned int i; } v; v.f = f;
  return (unsigned short)((v.i + 0x7FFFu + ((v.i >> 16) & 1u)) >> 16);  // RNE
}

// ---------------- fused prep / convert / zero-init (one launch) ----------------
#define N_XB    (MR*DM)
#define N_WCAT  (8192*1024)
#define N_XPB   (96*DI)
#define N_DTWB  (DI*RK)
#define N_OPB   (DM*DI)
#define N_A2    (DI*DS)
#define N_ZXD   (2*MR*96)
#define N_ZOUT  (MR*DM)
#define N_PREP  (N_XB + N_WCAT + 2*N_XPB + 2*N_DTWB + N_OPB + 2*N_A2 + N_ZXD + N_ZOUT)

__global__ void prep_all(const float* __restrict__ x, const float* __restrict__ mask,
                         const float* __restrict__ W,
                         const float* __restrict__ xpw_f, const float* __restrict__ xpw_r,
                         const float* __restrict__ dtw_f, const float* __restrict__ dtw_r,
                         const float* __restrict__ outpw,
                         const float* __restrict__ Af, const float* __restrict__ Ar,
                         unsigned short* __restrict__ xb, unsigned short* __restrict__ Wcat,
                         unsigned short* __restrict__ xpb, unsigned short* __restrict__ dtwb,
                         unsigned short* __restrict__ opb, float* __restrict__ A2,
                         float* __restrict__ xdbl_z, float* __restrict__ out_z)
{
  int i = blockIdx.x * 256 + threadIdx.x;
  if (i < N_XB) { xb[i] = f2bf(x[i] * mask[i >> 10]); return; }
  i -= N_XB;
  if (i < N_WCAT) {
    int nrow = i >> 10, k = i & 1023;
    float w = (nrow < 4096) ? W[i] : W[(size_t)(nrow - 4096) * 1024 + (1023 - k)];
    Wcat[i] = f2bf(w); return;
  }
  i -= N_WCAT;
  if (i < N_XPB) { xpb[i] = f2bf(xpw_f[i]); return; }
  i -= N_XPB;
  if (i < N_XPB) { xpb[N_XPB + i] = f2bf(xpw_r[i]); return; }
  i -= N_XPB;
  if (i < N_DTWB) { dtwb[i] = f2bf(dtw_f[i]); return; }
  i -= N_DTWB;
  if (i < N_DTWB) { dtwb[N_DTWB + i] = f2bf(dtw_r[i]); return; }
  i -= N_DTWB;
  if (i < N_OPB) { opb[i] = f2bf(outpw[i]); return; }
  i -= N_OPB;
  if (i < N_A2) { A2[i] = -__expf(Af[i]); return; }
  i -= N_A2;
  if (i < N_A2) { A2[N_A2 + i] = -__expf(Ar[i]); return; }
  i -= N_A2;
  if (i < N_ZXD) { xdbl_z[i] = 0.f; return; }
  i -= N_ZXD;
  if (i < N_ZOUT) { out_z[i] = 0.f; return; }
}

__global__ void cvt_dtb(const float* __restrict__ xdbl, unsigned short* __restrict__ dtb) {
  int i = blockIdx.x * 256 + threadIdx.x;
  if (i < 2 * MR * RK) {
    int dir = i / (MR * RK);
    int j = i % (MR * RK);
    int r = j >> 6, k = j & 63;
    dtb[i] = f2bf(xdbl[(size_t)dir * (MR * 96) + (size_t)r * 96 + k]);
  }
}

// ---------------- bf16 MFMA GEMM, C = A(M,K) * B(N,K)^T, 128x128 tile ----------------
// 2-phase double-buffered pipeline.

struct GArg { const unsigned short* A; const unsigned short* B; void* C; const float* bias; };

template<int EPI, int OUT, int ATOMIC, int NDIR>
__global__ __launch_bounds__(256)
void gemm_bt(GArg g0, GArg g1, int M, int N, int K, int lda, int ldb, int ldc, int koff)
{
  __shared__ __align__(16) unsigned short As[2][128 * 32];
  __shared__ __align__(16) unsigned short Bs[2][128 * 32];
  const GArg ga = (NDIR == 2 && (blockIdx.z & 1)) ? g1 : g0;
  const int kc = (NDIR == 2) ? ((int)blockIdx.z >> 1) : (int)blockIdx.z;
  const unsigned short* Ap = ga.A + (size_t)kc * koff;
  const unsigned short* Bp = ga.B + (size_t)kc * koff;

  const int tid  = threadIdx.x;
  const int wave = tid >> 6;
  const int lane = tid & 63;
  const int bm = blockIdx.y * 128;
  const int bn = blockIdx.x * 128;
  const int wr = wave >> 1, wc = wave & 1;

  f32x4 acc[4][4];
#pragma unroll
  for (int m = 0; m < 4; ++m)
#pragma unroll
    for (int n = 0; n < 4; ++n) acc[m][n] = (f32x4){0.f, 0.f, 0.f, 0.f};

  const int rsel = lane & 15;
  const int ksel = (lane >> 4) * 8;
  const int NT = K >> 5;

  const int chunk0 = wave * 2;
  const int flat0  = chunk0 * 512 + lane * 8;
  const int row0s  = flat0 >> 5, col0s = flat0 & 31;
  const int flat1  = (chunk0 + 1) * 512 + lane * 8;
  const int row1s  = flat1 >> 5, col1s = flat1 & 31;
  int grA0 = bm + row0s; if (grA0 > M - 1) grA0 = M - 1;
  int grA1 = bm + row1s; if (grA1 > M - 1) grA1 = M - 1;
  int gcB0 = bn + row0s; if (gcB0 > N - 1) gcB0 = N - 1;
  int gcB1 = bn + row1s; if (gcB1 > N - 1) gcB1 = N - 1;

#define STAGE(buf, kt)                                                                       \
  do {                                                                                       \
    const int k0_ = (kt) << 5;                                                               \
    __builtin_amdgcn_global_load_lds(                                                        \
        (const __attribute__((address_space(1))) void*)(Ap + (size_t)grA0 * lda + k0_ + col0s), \
        (__attribute__((address_space(3))) void*)(&As[buf][chunk0 * 512]), 16, 0, 0);        \
    __builtin_amdgcn_global_load_lds(                                                        \
        (const __attribute__((address_space(1))) void*)(Ap + (size_t)grA1 * lda + k0_ + col1s), \
        (__attribute__((address_space(3))) void*)(&As[buf][(chunk0 + 1) * 512]), 16, 0, 0);  \
    __builtin_amdgcn_global_load_lds(                                                        \
        (const __attribute__((address_space(1))) void*)(Bp + (size_t)gcB0 * ldb + k0_ + col0s), \
        (__attribute__((address_space(3))) void*)(&Bs[buf][chunk0 * 512]), 16, 0, 0);        \
    __builtin_amdgcn_global_load_lds(                                                        \
        (const __attribute__((address_space(1))) void*)(Bp + (size_t)gcB1 * ldb + k0_ + col1s), \
        (__attribute__((address_space(3))) void*)(&Bs[buf][(chunk0 + 1) * 512]), 16, 0, 0);  \
  } while (0)

  STAGE(0, 0);
  __syncthreads();
  int cur = 0;
  for (int kt = 0; kt < NT; ++kt) {
    if (kt + 1 < NT) STAGE(cur ^ 1, kt + 1);
    bf16x8 af[4], bfv[4];
#pragma unroll
    for (int m = 0; m < 4; ++m)
      af[m] = *(const bf16x8*)&As[cur][(wr * 64 + m * 16 + rsel) * 32 + ksel];
#pragma unroll
    for (int n = 0; n < 4; ++n)
      bfv[n] = *(const bf16x8*)&Bs[cur][(wc * 64 + n * 16 + rsel) * 32 + ksel];
#pragma unroll
    for (int m = 0; m < 4; ++m)
#pragma unroll
      for (int n = 0; n < 4; ++n)
        acc[m][n] = __builtin_amdgcn_mfma_f32_16x16x32_bf16(af[m], bfv[n], acc[m][n], 0, 0, 0);
    if (kt + 1 < NT) {
      __syncthreads();
      cur ^= 1;
    }
  }
#undef STAGE

#pragma unroll
  for (int m = 0; m < 4; ++m) {
    const int rowb = bm + wr * 64 + m * 16 + (lane >> 4) * 4;
#pragma unroll
    for (int n = 0; n < 4; ++n) {
      const int col = bn + wc * 64 + n * 16 + rsel;
      if (col < N) {
#pragma unroll
        for (int r = 0; r < 4; ++r) {
          const int rr = rowb + r;
          if (rr < M) {
            float v = acc[m][n][r];
            if constexpr (EPI == 1) {
              v += ga.bias[col];
              v = (v > 15.f) ? v : log1pf(__expf(v));   // softplus
            }
            if constexpr (ATOMIC) {
              atomicAdd((float*)ga.C + (size_t)rr * ldc + col, v);
            } else if constexpr (OUT == 1) {
              ((unsigned short*)ga.C)[(size_t)rr * ldc + col] = f2bf(v);
            } else {
              ((float*)ga.C)[(size_t)rr * ldc + col] = v;
            }
          }
        }
      }
    }
  }
}

// ---------------- depthwise causal conv(4) + silu -> bf16 ----------------
__global__ __launch_bounds__(256)
void conv_silu_k(const unsigned short* __restrict__ xz,
                 const float* __restrict__ cw_f, const float* __restrict__ cb_f,
                 const float* __restrict__ cw_r, const float* __restrict__ cb_r,
                 unsigned short* __restrict__ ub)
{
  const int tid = threadIdx.x;
  const int d   = blockIdx.x * 256 + tid;
  const int l0  = blockIdx.y * 32;
  const int dir = blockIdx.z >> 1, b = blockIdx.z & 1;
  const unsigned short* uin = xz + (size_t)dir * 4096 + d;
  const float* cw  = dir ? cw_r : cw_f;
  const float* cb  = dir ? cb_r : cb_f;
  const float w0 = cw[d * 4 + 0], w1 = cw[d * 4 + 1], w2 = cw[d * 4 + 2], w3 = cw[d * 4 + 3];
  const float bias = cb[d];
  unsigned short* uo = ub + (size_t)dir * ((size_t)MR * DI) + d;
  const size_t rbase = (size_t)b * LL;
  float x0 = (l0 >= 3) ? bf2f(uin[(rbase + l0 - 3) * 8192]) : 0.f;
  float x1 = (l0 >= 2) ? bf2f(uin[(rbase + l0 - 2) * 8192]) : 0.f;
  float x2 = (l0 >= 1) ? bf2f(uin[(rbase + l0 - 1) * 8192]) : 0.f;
  for (int l = l0; l < l0 + 32; ++l) {
    float x3 = bf2f(uin[(rbase + l) * 8192]);
    float o = w0 * x0 + w1 * x1 + w2 * x2 + w3 * x3 + bias;
    o = o / (1.f + __expf(-o));   // silu
    uo[(rbase + l) * DI] = f2bf(o);
    x0 = x1; x1 = x2; x2 = x3;
  }
}

// ---------------- chunked selective scan (bf16 delta + bf16 state) ----------------
// phase A: per (dir,b,chunk,d): prodA[16], h-from-zero[16] -> bf16
__global__ __launch_bounds__(256)
void scanA(const unsigned short* __restrict__ dlt, const unsigned short* __restrict__ ub,
           const float* __restrict__ xdbl, const float* __restrict__ A2,
           unsigned short* __restrict__ pAb, unsigned short* __restrict__ hb)
{
  const int tid = threadIdx.x;
  const int d = blockIdx.x * 256 + tid;
  const int c = blockIdx.y;
  const int dir = blockIdx.z >> 1, b = blockIdx.z & 1;
  __shared__ float sB[LC * DS];
  const float* xd = xdbl + (size_t)dir * (MR * 96);
  for (int i = tid; i < LC * DS; i += 256) {
    int t = i >> 4, s = i & 15;
    sB[i] = xd[(size_t)(b * LL + c * LC + t) * 96 + 64 + s];
  }
  __syncthreads();
  const unsigned short* dl_p = dlt + (size_t)dir * ((size_t)MR * DI) + d;
  const unsigned short* uu = ub + (size_t)dir * ((size_t)MR * DI) + d;
  float a2[DS];
#pragma unroll
  for (int s = 0; s < DS; ++s) a2[s] = A2[((size_t)dir * DI + d) * DS + s];
  float h[DS], pA[DS];
#pragma unroll
  for (int s = 0; s < DS; ++s) { h[s] = 0.f; pA[s] = 1.f; }
  for (int t = 0; t < LC; ++t) {
    size_t r = (size_t)b * LL + c * LC + t;
    float dl = bf2f(dl_p[r * DI]);
    float du = dl * bf2f(uu[r * DI]);
#pragma unroll
    for (int s = 0; s < DS; ++s) {
      float e = __expf(dl * a2[s]);
      pA[s] *= e;
      h[s] = e * h[s] + du * sB[t * DS + s];
    }
  }
  size_t base = ((((size_t)(dir * 2 + b)) * NCH + c) * DI + d) * DS;
#pragma unroll
  for (int s = 0; s < DS; ++s) { pAb[base + s] = f2bf(pA[s]); hb[base + s] = f2bf(h[s]); }
}

// phase B: sequential chunk combine; overwrites hb with h_init per chunk (bf16 io, f32 carry)
__global__ __launch_bounds__(256)
void scanB(const unsigned short* __restrict__ pAb, unsigned short* __restrict__ hb)
{
  int i = blockIdx.x * 256 + threadIdx.x;   // (dir*2+b)*32768 + d*16+s
  int db = i >> 15;
  int ds = i & 32767;
  float hrun = 0.f;
  for (int c = 0; c < NCH; ++c) {
    size_t off = (((size_t)db * NCH + c) << 15) + ds;
    float h0 = bf2f(hb[off]);
    float pa = bf2f(pAb[off]);
    hb[off] = f2bf(hrun);
    hrun = pa * hrun + h0;
  }
}

// phase C (fused fwd+rev): re-scan with h_init; y = sum_s h*C + D*u; gate silu(z); add; bf16
__global__ __launch_bounds__(256)
void scanC_f(const unsigned short* __restrict__ xz, const unsigned short* __restrict__ ub,
             const unsigned short* __restrict__ dlt, const float* __restrict__ xdbl,
             const float* __restrict__ A2, const float* __restrict__ Dv_f,
             const float* __restrict__ Dv_r, const unsigned short* __restrict__ hb,
             unsigned short* __restrict__ ygb)
{
  const int tid = threadIdx.x;
  const int d = blockIdx.x * 256 + tid;
  const int c = blockIdx.y;
  const int b = blockIdx.z;
  __shared__ float sB[2][LC * DS], sC[2][LC * DS];
  for (int i = tid; i < LC * DS; i += 256) {
    int t = i >> 4, s = i & 15;
    size_t ro = (size_t)(b * LL + c * LC + t) * 96;
    sB[0][i] = xdbl[ro + 64 + s];
    sC[0][i] = xdbl[ro + 80 + s];
    sB[1][i] = xdbl[(size_t)MR * 96 + ro + 64 + s];
    sC[1][i] = xdbl[(size_t)MR * 96 + ro + 80 + s];
  }
  __syncthreads();
  float a2f[DS], a2r[DS], hf[DS], hr[DS];
  const size_t basef = ((((size_t)b) * NCH + c) * DI + d) * DS;
  const size_t baser = ((((size_t)(2 + b)) * NCH + c) * DI + d) * DS;
#pragma unroll
  for (int s = 0; s < DS; ++s) {
    a2f[s] = A2[(size_t)d * DS + s];
    a2r[s] = A2[((size_t)DI + d) * DS + s];
    hf[s] = bf2f(hb[basef + s]);
    hr[s] = bf2f(hb[baser + s]);
  }
  const float Df = Dv_f[d], Dr = Dv_r[d];
  for (int t = 0; t < LC; ++t) {
    size_t r = (size_t)b * LL + c * LC + t;
    float dlf = bf2f(dlt[r * DI + d]);
    float dlr = bf2f(dlt[(size_t)MR * DI + r * DI + d]);
    float uf = bf2f(ub[r * DI + d]);
    float ur = bf2f(ub[(size_t)MR * DI + r * DI + d]);
    float duf = dlf * uf, dur = dlr * ur;
    float yf = 0.f, yr = 0.f;
#pragma unroll
    for (int s = 0; s < DS; ++s) {
      float ef = __expf(dlf * a2f[s]);
      hf[s] = ef * hf[s] + duf * sB[0][t * DS + s];
      yf += hf[s] * sC[0][t * DS + s];
      float er = __expf(dlr * a2r[s]);
      hr[s] = er * hr[s] + dur * sB[1][t * DS + s];
      yr += hr[s] * sC[1][t * DS + s];
    }
    yf += Df * uf;
    yr += Dr * ur;
    float zf = bf2f(xz[r * 8192 + 2048 + d]);
    float zr = bf2f(xz[r * 8192 + 6144 + d]);
    float yg = yf * (zf / (1.f + __expf(-zf))) + yr * (zr / (1.f + __expf(-zr)));
    ygb[r * DI + d] = f2bf(yg);
  }
}

// ---------------- host launch ----------------

extern "C" void kernel_launch(void* const* d_in, const int* in_sizes, int n_in,
                              void* d_out, int out_size, void* d_ws, size_t ws_size,
                              hipStream_t stream)
{
  (void)in_sizes; (void)n_in; (void)out_size; (void)ws_size;
  const float* x      = (const float*)d_in[0];
  const float* mask   = (const float*)d_in[1];
  const float* inpw   = (const float*)d_in[2];
  const float* outpw  = (const float*)d_in[3];
  const float* cw_f   = (const float*)d_in[4];
  const float* cb_f   = (const float*)d_in[5];
  const float* xpw_f  = (const float*)d_in[6];
  const float* dtw_f  = (const float*)d_in[7];
  const float* dtbias_f = (const float*)d_in[8];
  const float* alog_f = (const float*)d_in[9];
  const float* Dv_f   = (const float*)d_in[10];
  const float* cw_r   = (const float*)d_in[11];
  const float* cb_r   = (const float*)d_in[12];
  const float* xpw_r  = (const float*)d_in[13];
  const float* dtw_r  = (const float*)d_in[14];
  const float* dtbias_r = (const float*)d_in[15];
  const float* alog_r = (const float*)d_in[16];
  const float* Dv_r   = (const float*)d_in[17];
  float* out = (float*)d_out;

  char* p = (char*)d_ws;
  auto carve = [&](size_t bytes) -> char* {
    char* q = p; p += (bytes + 255) & ~(size_t)255; return q;
  };
  unsigned short* xb   = (unsigned short*)carve((size_t)MR * DM * 2);
  unsigned short* Wcat = (unsigned short*)carve((size_t)8192 * 1024 * 2);
  unsigned short* xpb  = (unsigned short*)carve((size_t)2 * 96 * DI * 2);
  unsigned short* dtwb = (unsigned short*)carve((size_t)2 * DI * RK * 2);
  unsigned short* opb  = (unsigned short*)carve((size_t)DM * DI * 2);
  float*          A2   = (float*)carve((size_t)2 * DI * DS * 4);
  unsigned short* xz   = (unsigned short*)carve((size_t)MR * 8192 * 2);
  unsigned short* dlt  = (unsigned short*)carve((size_t)2 * MR * DI * 2);   // delta bf16
  unsigned short* ub   = (unsigned short*)carve((size_t)2 * MR * DI * 2);
  float*          xdbl = (float*)carve((size_t)2 * MR * 96 * 4);
  unsigned short* dtb  = (unsigned short*)carve((size_t)2 * MR * RK * 2);
  unsigned short* pAb  = (unsigned short*)carve((size_t)4 * NCH * DI * DS * 2);  // bf16 state
  unsigned short* hb   = (unsigned short*)carve((size_t)4 * NCH * DI * DS * 2);  // bf16 state
  unsigned short* ygb  = (unsigned short*)carve((size_t)MR * DI * 2);

  // fused prep (+ zero-init of atomic targets xdbl/out)
  prep_all<<<(N_PREP + 255) / 256, 256, 0, stream>>>(
      x, mask, inpw, xpw_f, xpw_r, dtw_f, dtw_r, outpw, alog_f, alog_r,
      xb, Wcat, xpb, dtwb, opb, A2, xdbl, out);

  // G1: xz(2048 x 8192, bf16) = xb @ Wcat^T
  {
    GArg g0{xb, Wcat, xz, nullptr};
    gemm_bt<0, 1, 0, 1><<<dim3(64, 16, 1), 256, 0, stream>>>(
        g0, g0, MR, 8192, 1024, DM, DM, 8192, 0);
  }
  // conv + silu -> ub
  conv_silu_k<<<dim3(8, 32, 4), 256, 0, stream>>>(xz, cw_f, cb_f, cw_r, cb_r, ub);
  // G2: x_dbl = ub @ x_proj^T, split-K=8, atomic accumulate
  {
    GArg g0{ub, xpb, xdbl, nullptr};
    GArg g1{ub + (size_t)MR * DI, xpb + 96 * DI, xdbl + (size_t)MR * 96, nullptr};
    gemm_bt<0, 0, 1, 2><<<dim3(1, 16, 16), 256, 0, stream>>>(
        g0, g1, MR, 96, 256, DI, DI, 96, 256);
  }
  cvt_dtb<<<(2 * MR * RK + 255) / 256, 256, 0, stream>>>(xdbl, dtb);
  // G3: delta = softplus(dt @ dt_w^T + dt_b) -> dlt (bf16, ldc=DI)
  {
    GArg g0{dtb, dtwb, dlt, dtbias_f};
    GArg g1{dtb + (size_t)MR * RK, dtwb + DI * RK, dlt + (size_t)MR * DI, dtbias_r};
    gemm_bt<1, 1, 0, 2><<<dim3(16, 16, 2), 256, 0, stream>>>(
        g0, g1, MR, DI, 64, RK, RK, DI, 0);
  }
  scanA<<<dim3(8, NCH, 4), 256, 0, stream>>>(dlt, ub, xdbl, A2, pAb, hb);
  scanB<<<dim3(512, 1, 1), 256, 0, stream>>>(pAb, hb);
  scanC_f<<<dim3(8, NCH, 2), 256, 0, stream>>>(xz, ub, dlt, xdbl, A2, Dv_f, Dv_r, hb, ygb);
  // G4: out = ygb @ out_proj^T, split-K=4, atomic accumulate
  {
    GArg g0{ygb, opb, out, nullptr};
    gemm_bt<0, 0, 1, 1><<<dim3(8, 16, 4), 256, 0, stream>>>(
        g0, g0, MR, DM, 512, DI, DI, DM, 512);
  }
}

// Round 6
// 263.636 us; speedup vs baseline: 1.3427x; 1.0332x over previous
//
#include <hip/hip_runtime.h>

#define DM   1024
#define DI   2048
#define DS   16
#define RK   64
#define NBAT 2
#define LL   1024
#define MR   (NBAT*LL)   // 2048 rows (B*L)
#define NCH  64          // scan chunks
#define LC   (LL/NCH)    // 16 steps per chunk

typedef short  bf16x8 __attribute__((ext_vector_type(8)));
typedef short  short8v __attribute__((ext_vector_type(8)));
typedef float  f32x4  __attribute__((ext_vector_type(4)));

__device__ __forceinline__ float bf2f(unsigned short u) {
  union { unsigned int i; float f; } v; v.i = ((unsigned int)u) << 16; return v.f;
}
__device__ __forceinline__ unsigned short f2bf(float f) {
  union { float f; unsigned int i; } v; v.f = f;
  return (unsigned short)((v.i + 0x7FFFu + ((v.i >> 16) & 1u)) >> 16);  // RNE
}

// ---------------- fused prep / convert / zero-init (one launch, x4 vectorized) --------
#define N_XB    (MR*DM)
#define N_WCAT  (8192*1024)
#define N_XPB   (96*DI)
#define N_DTWB  (DI*RK)
#define N_OPB   (DM*DI)
#define N_A2    (DI*DS)
#define N_ZXD   (2*MR*96)
#define N_ZOUT  (MR*DM)
#define N_PREP  (N_XB + N_WCAT + 2*N_XPB + 2*N_DTWB + N_OPB + 2*N_A2 + N_ZXD + N_ZOUT)

__device__ __forceinline__ void cvt4(const float* src, unsigned short* dst) {
  const float4 v = *(const float4*)src;
  ushort4 o; o.x = f2bf(v.x); o.y = f2bf(v.y); o.z = f2bf(v.z); o.w = f2bf(v.w);
  *(ushort4*)dst = o;
}

__global__ void prep_all(const float* __restrict__ x, const float* __restrict__ mask,
                         const float* __restrict__ W,
                         const float* __restrict__ xpw_f, const float* __restrict__ xpw_r,
                         const float* __restrict__ dtw_f, const float* __restrict__ dtw_r,
                         const float* __restrict__ outpw,
                         const float* __restrict__ Af, const float* __restrict__ Ar,
                         unsigned short* __restrict__ xb, unsigned short* __restrict__ Wcat,
                         unsigned short* __restrict__ xpb, unsigned short* __restrict__ dtwb,
                         unsigned short* __restrict__ opb, float* __restrict__ A2,
                         float* __restrict__ xdbl_z, float* __restrict__ out_z)
{
  int i = (blockIdx.x * 256 + threadIdx.x) * 4;
  if (i < N_XB) {
    const float4 v = *(const float4*)&x[i];
    const float m = mask[i >> 10];
    ushort4 o; o.x = f2bf(v.x * m); o.y = f2bf(v.y * m); o.z = f2bf(v.z * m); o.w = f2bf(v.w * m);
    *(ushort4*)&xb[i] = o; return;
  }
  i -= N_XB;
  if (i < N_WCAT) {
    const int nrow = i >> 10, k = i & 1023;
    float4 v;
    if (nrow < 4096) {
      v = *(const float4*)&W[i];
    } else {
      const float4 t = *(const float4*)&W[(size_t)(nrow - 4096) * 1024 + (1020 - k)];
      v.x = t.w; v.y = t.z; v.z = t.y; v.w = t.x;
    }
    ushort4 o; o.x = f2bf(v.x); o.y = f2bf(v.y); o.z = f2bf(v.z); o.w = f2bf(v.w);
    *(ushort4*)&Wcat[i] = o; return;
  }
  i -= N_WCAT;
  if (i < N_XPB) { cvt4(&xpw_f[i], &xpb[i]); return; }
  i -= N_XPB;
  if (i < N_XPB) { cvt4(&xpw_r[i], &xpb[N_XPB + i]); return; }
  i -= N_XPB;
  if (i < N_DTWB) { cvt4(&dtw_f[i], &dtwb[i]); return; }
  i -= N_DTWB;
  if (i < N_DTWB) { cvt4(&dtw_r[i], &dtwb[N_DTWB + i]); return; }
  i -= N_DTWB;
  if (i < N_OPB) { cvt4(&outpw[i], &opb[i]); return; }
  i -= N_OPB;
  if (i < N_A2) {
    const float4 v = *(const float4*)&Af[i];
    float4 o; o.x = -__expf(v.x); o.y = -__expf(v.y); o.z = -__expf(v.z); o.w = -__expf(v.w);
    *(float4*)&A2[i] = o; return;
  }
  i -= N_A2;
  if (i < N_A2) {
    const float4 v = *(const float4*)&Ar[i];
    float4 o; o.x = -__expf(v.x); o.y = -__expf(v.y); o.z = -__expf(v.z); o.w = -__expf(v.w);
    *(float4*)&A2[N_A2 + i] = o; return;
  }
  i -= N_A2;
  if (i < N_ZXD) { *(float4*)&xdbl_z[i] = (float4){0.f, 0.f, 0.f, 0.f}; return; }
  i -= N_ZXD;
  if (i < N_ZOUT) { *(float4*)&out_z[i] = (float4){0.f, 0.f, 0.f, 0.f}; return; }
}

__global__ void cvt_dtb(const float* __restrict__ xdbl, unsigned short* __restrict__ dtb) {
  int i = (blockIdx.x * 256 + threadIdx.x) * 4;
  if (i < 2 * MR * RK) {
    const int dir = i / (MR * RK);
    const int j = i % (MR * RK);
    const int r = j >> 6, k = j & 63;
    cvt4(&xdbl[(size_t)dir * (MR * 96) + (size_t)r * 96 + k], &dtb[i]);
  }
}

// ---------------- bf16 MFMA GEMM, C = A(M,K) * B(N,K)^T, 128x128 tile ----------------
// 2-phase double-buffered pipeline (unchanged — proven baseline).

struct GArg { const unsigned short* A; const unsigned short* B; void* C; const float* bias; };

template<int EPI, int OUT, int ATOMIC, int NDIR>
__global__ __launch_bounds__(256)
void gemm_bt(GArg g0, GArg g1, int M, int N, int K, int lda, int ldb, int ldc, int koff)
{
  __shared__ __align__(16) unsigned short As[2][128 * 32];
  __shared__ __align__(16) unsigned short Bs[2][128 * 32];
  const GArg ga = (NDIR == 2 && (blockIdx.z & 1)) ? g1 : g0;
  const int kc = (NDIR == 2) ? ((int)blockIdx.z >> 1) : (int)blockIdx.z;
  const unsigned short* Ap = ga.A + (size_t)kc * koff;
  const unsigned short* Bp = ga.B + (size_t)kc * koff;

  const int tid  = threadIdx.x;
  const int wave = tid >> 6;
  const int lane = tid & 63;
  const int bm = blockIdx.y * 128;
  const int bn = blockIdx.x * 128;
  const int wr = wave >> 1, wc = wave & 1;

  f32x4 acc[4][4];
#pragma unroll
  for (int m = 0; m < 4; ++m)
#pragma unroll
    for (int n = 0; n < 4; ++n) acc[m][n] = (f32x4){0.f, 0.f, 0.f, 0.f};

  const int rsel = lane & 15;
  const int ksel = (lane >> 4) * 8;
  const int NT = K >> 5;

  const int chunk0 = wave * 2;
  const int flat0  = chunk0 * 512 + lane * 8;
  const int row0s  = flat0 >> 5, col0s = flat0 & 31;
  const int flat1  = (chunk0 + 1) * 512 + lane * 8;
  const int row1s  = flat1 >> 5, col1s = flat1 & 31;
  int grA0 = bm + row0s; if (grA0 > M - 1) grA0 = M - 1;
  int grA1 = bm + row1s; if (grA1 > M - 1) grA1 = M - 1;
  int gcB0 = bn + row0s; if (gcB0 > N - 1) gcB0 = N - 1;
  int gcB1 = bn + row1s; if (gcB1 > N - 1) gcB1 = N - 1;

#define STAGE(buf, kt)                                                                       \
  do {                                                                                       \
    const int k0_ = (kt) << 5;                                                               \
    __builtin_amdgcn_global_load_lds(                                                        \
        (const __attribute__((address_space(1))) void*)(Ap + (size_t)grA0 * lda + k0_ + col0s), \
        (__attribute__((address_space(3))) void*)(&As[buf][chunk0 * 512]), 16, 0, 0);        \
    __builtin_amdgcn_global_load_lds(                                                        \
        (const __attribute__((address_space(1))) void*)(Ap + (size_t)grA1 * lda + k0_ + col1s), \
        (__attribute__((address_space(3))) void*)(&As[buf][(chunk0 + 1) * 512]), 16, 0, 0);  \
    __builtin_amdgcn_global_load_lds(                                                        \
        (const __attribute__((address_space(1))) void*)(Bp + (size_t)gcB0 * ldb + k0_ + col0s), \
        (__attribute__((address_space(3))) void*)(&Bs[buf][chunk0 * 512]), 16, 0, 0);        \
    __builtin_amdgcn_global_load_lds(                                                        \
        (const __attribute__((address_space(1))) void*)(Bp + (size_t)gcB1 * ldb + k0_ + col1s), \
        (__attribute__((address_space(3))) void*)(&Bs[buf][(chunk0 + 1) * 512]), 16, 0, 0);  \
  } while (0)

  STAGE(0, 0);
  __syncthreads();
  int cur = 0;
  for (int kt = 0; kt < NT; ++kt) {
    if (kt + 1 < NT) STAGE(cur ^ 1, kt + 1);
    bf16x8 af[4], bfv[4];
#pragma unroll
    for (int m = 0; m < 4; ++m)
      af[m] = *(const bf16x8*)&As[cur][(wr * 64 + m * 16 + rsel) * 32 + ksel];
#pragma unroll
    for (int n = 0; n < 4; ++n)
      bfv[n] = *(const bf16x8*)&Bs[cur][(wc * 64 + n * 16 + rsel) * 32 + ksel];
#pragma unroll
    for (int m = 0; m < 4; ++m)
#pragma unroll
      for (int n = 0; n < 4; ++n)
        acc[m][n] = __builtin_amdgcn_mfma_f32_16x16x32_bf16(af[m], bfv[n], acc[m][n], 0, 0, 0);
    if (kt + 1 < NT) {
      __syncthreads();
      cur ^= 1;
    }
  }
#undef STAGE

#pragma unroll
  for (int m = 0; m < 4; ++m) {
    const int rowb = bm + wr * 64 + m * 16 + (lane >> 4) * 4;
#pragma unroll
    for (int n = 0; n < 4; ++n) {
      const int col = bn + wc * 64 + n * 16 + rsel;
      if (col < N) {
#pragma unroll
        for (int r = 0; r < 4; ++r) {
          const int rr = rowb + r;
          if (rr < M) {
            float v = acc[m][n][r];
            if constexpr (EPI == 1) {
              v += ga.bias[col];
              v = (v > 15.f) ? v : log1pf(__expf(v));   // softplus
            }
            if constexpr (ATOMIC) {
              atomicAdd((float*)ga.C + (size_t)rr * ldc + col, v);
            } else if constexpr (OUT == 1) {
              ((unsigned short*)ga.C)[(size_t)rr * ldc + col] = f2bf(v);
            } else {
              ((float*)ga.C)[(size_t)rr * ldc + col] = v;
            }
          }
        }
      }
    }
  }
}

// ---------------- depthwise causal conv(4) + silu -> bf16 (x8 d-vectorized) -----------
// thread owns 8 consecutive d; block covers all DI; grid (l-chunks, dir*2+b)
__global__ __launch_bounds__(256)
void conv_silu_k(const unsigned short* __restrict__ xz,
                 const float* __restrict__ cw_f, const float* __restrict__ cb_f,
                 const float* __restrict__ cw_r, const float* __restrict__ cb_r,
                 unsigned short* __restrict__ ub)
{
  const int tid = threadIdx.x;
  const int d0  = tid * 8;
  const int l0  = blockIdx.x * 16;
  const int dir = blockIdx.y >> 1, b = blockIdx.y & 1;
  const float* cw = dir ? cw_r : cw_f;
  const float* cb = dir ? cb_r : cb_f;
  float w0[8], w1[8], w2[8], w3[8], bs[8];
#pragma unroll
  for (int j = 0; j < 8; ++j) {
    const float4 wv = *(const float4*)&cw[(d0 + j) * 4];
    w0[j] = wv.x; w1[j] = wv.y; w2[j] = wv.z; w3[j] = wv.w;
    bs[j] = cb[d0 + j];
  }
  const unsigned short* uin = xz + (size_t)dir * 4096 + d0;          // row stride 8192
  unsigned short* uo = ub + (size_t)dir * ((size_t)MR * DI) + d0;    // row stride DI
  const size_t rbase = (size_t)b * LL;
  float xa[8], xbv[8], xc[8];
#pragma unroll
  for (int j = 0; j < 8; ++j) { xa[j] = 0.f; xbv[j] = 0.f; xc[j] = 0.f; }
  if (l0 >= 3) { const short8v v = *(const short8v*)&uin[(rbase + l0 - 3) * 8192];
#pragma unroll
    for (int j = 0; j < 8; ++j) xa[j] = bf2f((unsigned short)v[j]); }
  if (l0 >= 2) { const short8v v = *(const short8v*)&uin[(rbase + l0 - 2) * 8192];
#pragma unroll
    for (int j = 0; j < 8; ++j) xbv[j] = bf2f((unsigned short)v[j]); }
  if (l0 >= 1) { const short8v v = *(const short8v*)&uin[(rbase + l0 - 1) * 8192];
#pragma unroll
    for (int j = 0; j < 8; ++j) xc[j] = bf2f((unsigned short)v[j]); }
  for (int l = l0; l < l0 + 16; ++l) {
    const short8v v = *(const short8v*)&uin[(rbase + l) * 8192];
    short8v ov;
#pragma unroll
    for (int j = 0; j < 8; ++j) {
      const float x3 = bf2f((unsigned short)v[j]);
      float o = w0[j] * xa[j] + w1[j] * xbv[j] + w2[j] * xc[j] + w3[j] * x3 + bs[j];
      o = o / (1.f + __expf(-o));   // silu
      ov[j] = (short)f2bf(o);
      xa[j] = xbv[j]; xbv[j] = xc[j]; xc[j] = x3;
    }
    *(short8v*)&uo[(rbase + l) * DI] = ov;
  }
}

// ---------------- chunked selective scan (bf16 delta/state, f32 sumdl) ----------------
// phase A: per (dir,b,chunk,d): sumdl (f32), h-from-zero[16] (bf16)
// pA[s] = prod_t exp(dl_t*a2[s]) == exp(a2[s] * sum_t dl_t)  -> store only sum dl
__global__ __launch_bounds__(256)
void scanA(const unsigned short* __restrict__ dlt, const unsigned short* __restrict__ ub,
           const float* __restrict__ xdbl, const float* __restrict__ A2,
           float* __restrict__ sdl, unsigned short* __restrict__ hb)
{
  const int tid = threadIdx.x;
  const int d = blockIdx.x * 256 + tid;
  const int c = blockIdx.y;
  const int dir = blockIdx.z >> 1, b = blockIdx.z & 1;
  __shared__ float sB[LC * DS];
  const float* xd = xdbl + (size_t)dir * (MR * 96);
  for (int i = tid; i < LC * DS; i += 256) {
    int t = i >> 4, s = i & 15;
    sB[i] = xd[(size_t)(b * LL + c * LC + t) * 96 + 64 + s];
  }
  __syncthreads();
  const unsigned short* dl_p = dlt + (size_t)dir * ((size_t)MR * DI) + d;
  const unsigned short* uu = ub + (size_t)dir * ((size_t)MR * DI) + d;
  float a2[DS];
#pragma unroll
  for (int s = 0; s < DS; ++s) a2[s] = A2[((size_t)dir * DI + d) * DS + s];
  float h[DS];
#pragma unroll
  for (int s = 0; s < DS; ++s) h[s] = 0.f;
  float sumdl = 0.f;
  for (int t = 0; t < LC; ++t) {
    size_t r = (size_t)b * LL + c * LC + t;
    float dl = bf2f(dl_p[r * DI]);
    float du = dl * bf2f(uu[r * DI]);
    sumdl += dl;
#pragma unroll
    for (int s = 0; s < DS; ++s) {
      float e = __expf(dl * a2[s]);
      h[s] = e * h[s] + du * sB[t * DS + s];
    }
  }
  const size_t base = ((((size_t)(dir * 2 + b)) * NCH + c) * DI + d) * DS;
#pragma unroll
  for (int s = 0; s < DS; ++s) hb[base + s] = f2bf(h[s]);
  sdl[(((size_t)(dir * 2 + b)) * NCH + c) * DI + d] = sumdl;
}

// phase B: sequential chunk combine; pa recomputed from sumdl (f32, more accurate)
__global__ __launch_bounds__(256)
void scanB(const float* __restrict__ sdl, const float* __restrict__ A2,
           unsigned short* __restrict__ hb)
{
  const int i = blockIdx.x * 256 + threadIdx.x;   // (dir*2+b)*32768 + d*16+s
  const int db = i >> 15;
  const int ds_ = i & 32767;
  const int d = ds_ >> 4, s = i & 15;
  const int dir = db >> 1;
  const float a2 = A2[((size_t)dir * DI + d) * DS + s];
  float hrun = 0.f;
  for (int c = 0; c < NCH; ++c) {
    const size_t off = (((size_t)db * NCH + c) << 15) + ds_;
    const float h0 = bf2f(hb[off]);
    const float pa = __expf(a2 * sdl[((size_t)db * NCH + c) * DI + d]);
    hb[off] = f2bf(hrun);
    hrun = pa * hrun + h0;
  }
}

// phase C (fused fwd+rev): re-scan with h_init; y = sum_s h*C + D*u; gate silu(z); add; bf16
__global__ __launch_bounds__(256)
void scanC_f(const unsigned short* __restrict__ xz, const unsigned short* __restrict__ ub,
             const unsigned short* __restrict__ dlt, const float* __restrict__ xdbl,
             const float* __restrict__ A2, const float* __restrict__ Dv_f,
             const float* __restrict__ Dv_r, const unsigned short* __restrict__ hb,
             unsigned short* __restrict__ ygb)
{
  const int tid = threadIdx.x;
  const int d = blockIdx.x * 256 + tid;
  const int c = blockIdx.y;
  const int b = blockIdx.z;
  __shared__ float sB[2][LC * DS], sC[2][LC * DS];
  for (int i = tid; i < LC * DS; i += 256) {
    int t = i >> 4, s = i & 15;
    size_t ro = (size_t)(b * LL + c * LC + t) * 96;
    sB[0][i] = xdbl[ro + 64 + s];
    sC[0][i] = xdbl[ro + 80 + s];
    sB[1][i] = xdbl[(size_t)MR * 96 + ro + 64 + s];
    sC[1][i] = xdbl[(size_t)MR * 96 + ro + 80 + s];
  }
  __syncthreads();
  float a2f[DS], a2r[DS], hf[DS], hr[DS];
  const size_t basef = ((((size_t)b) * NCH + c) * DI + d) * DS;
  const size_t baser = ((((size_t)(2 + b)) * NCH + c) * DI + d) * DS;
#pragma unroll
  for (int s = 0; s < DS; ++s) {
    a2f[s] = A2[(size_t)d * DS + s];
    a2r[s] = A2[((size_t)DI + d) * DS + s];
    hf[s] = bf2f(hb[basef + s]);
    hr[s] = bf2f(hb[baser + s]);
  }
  const float Df = Dv_f[d], Dr = Dv_r[d];
  for (int t = 0; t < LC; ++t) {
    size_t r = (size_t)b * LL + c * LC + t;
    float dlf = bf2f(dlt[r * DI + d]);
    float dlr = bf2f(dlt[(size_t)MR * DI + r * DI + d]);
    float uf = bf2f(ub[r * DI + d]);
    float ur = bf2f(ub[(size_t)MR * DI + r * DI + d]);
    float duf = dlf * uf, dur = dlr * ur;
    float yf = 0.f, yr = 0.f;
#pragma unroll
    for (int s = 0; s < DS; ++s) {
      float ef = __expf(dlf * a2f[s]);
      hf[s] = ef * hf[s] + duf * sB[0][t * DS + s];
      yf += hf[s] * sC[0][t * DS + s];
      float er = __expf(dlr * a2r[s]);
      hr[s] = er * hr[s] + dur * sB[1][t * DS + s];
      yr += hr[s] * sC[1][t * DS + s];
    }
    yf += Df * uf;
    yr += Dr * ur;
    float zf = bf2f(xz[r * 8192 + 2048 + d]);
    float zr = bf2f(xz[r * 8192 + 6144 + d]);
    float yg = yf * (zf / (1.f + __expf(-zf))) + yr * (zr / (1.f + __expf(-zr)));
    ygb[r * DI + d] = f2bf(yg);
  }
}

// ---------------- host launch ----------------

extern "C" void kernel_launch(void* const* d_in, const int* in_sizes, int n_in,
                              void* d_out, int out_size, void* d_ws, size_t ws_size,
                              hipStream_t stream)
{
  (void)in_sizes; (void)n_in; (void)out_size; (void)ws_size;
  const float* x      = (const float*)d_in[0];
  const float* mask   = (const float*)d_in[1];
  const float* inpw   = (const float*)d_in[2];
  const float* outpw  = (const float*)d_in[3];
  const float* cw_f   = (const float*)d_in[4];
  const float* cb_f   = (const float*)d_in[5];
  const float* xpw_f  = (const float*)d_in[6];
  const float* dtw_f  = (const float*)d_in[7];
  const float* dtbias_f = (const float*)d_in[8];
  const float* alog_f = (const float*)d_in[9];
  const float* Dv_f   = (const float*)d_in[10];
  const float* cw_r   = (const float*)d_in[11];
  const float* cb_r   = (const float*)d_in[12];
  const float* xpw_r  = (const float*)d_in[13];
  const float* dtw_r  = (const float*)d_in[14];
  const float* dtbias_r = (const float*)d_in[15];
  const float* alog_r = (const float*)d_in[16];
  const float* Dv_r   = (const float*)d_in[17];
  float* out = (float*)d_out;

  char* p = (char*)d_ws;
  auto carve = [&](size_t bytes) -> char* {
    char* q = p; p += (bytes + 255) & ~(size_t)255; return q;
  };
  unsigned short* xb   = (unsigned short*)carve((size_t)MR * DM * 2);
  unsigned short* Wcat = (unsigned short*)carve((size_t)8192 * 1024 * 2);
  unsigned short* xpb  = (unsigned short*)carve((size_t)2 * 96 * DI * 2);
  unsigned short* dtwb = (unsigned short*)carve((size_t)2 * DI * RK * 2);
  unsigned short* opb  = (unsigned short*)carve((size_t)DM * DI * 2);
  float*          A2   = (float*)carve((size_t)2 * DI * DS * 4);
  unsigned short* xz   = (unsigned short*)carve((size_t)MR * 8192 * 2);
  unsigned short* dlt  = (unsigned short*)carve((size_t)2 * MR * DI * 2);
  unsigned short* ub   = (unsigned short*)carve((size_t)2 * MR * DI * 2);
  float*          xdbl = (float*)carve((size_t)2 * MR * 96 * 4);
  unsigned short* dtb  = (unsigned short*)carve((size_t)2 * MR * RK * 2);
  float*          sdl  = (float*)carve((size_t)4 * NCH * DI * 4);            // f32 sum(dl)
  unsigned short* hb   = (unsigned short*)carve((size_t)4 * NCH * DI * DS * 2);
  unsigned short* ygb  = (unsigned short*)carve((size_t)MR * DI * 2);

  // fused prep (+ zero-init of atomic targets xdbl/out)
  prep_all<<<(N_PREP / 4 + 255) / 256, 256, 0, stream>>>(
      x, mask, inpw, xpw_f, xpw_r, dtw_f, dtw_r, outpw, alog_f, alog_r,
      xb, Wcat, xpb, dtwb, opb, A2, xdbl, out);

  // G1: xz(2048 x 8192, bf16) = xb @ Wcat^T
  {
    GArg g0{xb, Wcat, xz, nullptr};
    gemm_bt<0, 1, 0, 1><<<dim3(64, 16, 1), 256, 0, stream>>>(
        g0, g0, MR, 8192, 1024, DM, DM, 8192, 0);
  }
  // conv + silu -> ub
  conv_silu_k<<<dim3(64, 4, 1), 256, 0, stream>>>(xz, cw_f, cb_f, cw_r, cb_r, ub);
  // G2: x_dbl = ub @ x_proj^T, split-K=8, atomic accumulate
  {
    GArg g0{ub, xpb, xdbl, nullptr};
    GArg g1{ub + (size_t)MR * DI, xpb + 96 * DI, xdbl + (size_t)MR * 96, nullptr};
    gemm_bt<0, 0, 1, 2><<<dim3(1, 16, 16), 256, 0, stream>>>(
        g0, g1, MR, 96, 256, DI, DI, 96, 256);
  }
  cvt_dtb<<<(2 * MR * RK / 4 + 255) / 256, 256, 0, stream>>>(xdbl, dtb);
  // G3: delta = softplus(dt @ dt_w^T + dt_b) -> dlt (bf16, ldc=DI)
  {
    GArg g0{dtb, dtwb, dlt, dtbias_f};
    GArg g1{dtb + (size_t)MR * RK, dtwb + DI * RK, dlt + (size_t)MR * DI, dtbias_r};
    gemm_bt<1, 1, 0, 2><<<dim3(16, 16, 2), 256, 0, stream>>>(
        g0, g1, MR, DI, 64, RK, RK, DI, 0);
  }
  scanA<<<dim3(8, NCH, 4), 256, 0, stream>>>(dlt, ub, xdbl, A2, sdl, hb);
  scanB<<<dim3(512, 1, 1), 256, 0, stream>>>(sdl, A2, hb);
  scanC_f<<<dim3(8, NCH, 2), 256, 0, stream>>>(xz, ub, dlt, xdbl, A2, Dv_f, Dv_r, hb, ygb);
  // G4: out = ygb @ out_proj^T, split-K=4, atomic accumulate
  {
    GArg g0{ygb, opb, out, nullptr};
    gemm_bt<0, 0, 1, 1><<<dim3(8, 16, 4), 256, 0, stream>>>(
        g0, g0, MR, DM, 512, DI, DI, DM, 512);
  }
}

// Round 7
// 242.394 us; speedup vs baseline: 1.4603x; 1.0876x over previous
//
#include <hip/hip_runtime.h>

#define DM   1024
#define DI   2048
#define DS   16
#define RK   64
#define NBAT 2
#define LL   1024
#define MR   (NBAT*LL)   // 2048 rows (B*L)
#define NCH  64          // scan chunks
#define LC   (LL/NCH)    // 16 steps per chunk

typedef short  bf16x8 __attribute__((ext_vector_type(8)));
typedef short  short8v __attribute__((ext_vector_type(8)));
typedef float  f32x4  __attribute__((ext_vector_type(4)));

__device__ __forceinline__ float bf2f(unsigned short u) {
  union { unsigned int i; float f; } v; v.i = ((unsigned int)u) << 16; return v.f;
}
__device__ __forceinline__ unsigned short f2bf(float f) {
  union { float f; unsigned int i; } v; v.f = f;
  return (unsigned short)((v.i + 0x7FFFu + ((v.i >> 16) & 1u)) >> 16);  // RNE
}

// ---------------- fused prep / convert / zero-init (one launch, x4 vectorized) --------
// W is read ONCE; both normal and feature-flipped Wcat halves written from it.
#define N_XB    (MR*DM)
#define N_WH    (4096*1024)       // half of Wcat (source W elements)
#define N_XPB   (96*DI)
#define N_DTWB  (DI*RK)
#define N_OPB   (DM*DI)
#define N_A2    (DI*DS)
#define N_ZXD   (2*MR*96)
#define N_ZOUT  (MR*DM)
#define N_PREP  (N_XB + N_WH + 2*N_XPB + 2*N_DTWB + N_OPB + 2*N_A2 + N_ZXD + N_ZOUT)

__device__ __forceinline__ void cvt4(const float* src, unsigned short* dst) {
  const float4 v = *(const float4*)src;
  ushort4 o; o.x = f2bf(v.x); o.y = f2bf(v.y); o.z = f2bf(v.z); o.w = f2bf(v.w);
  *(ushort4*)dst = o;
}

__global__ void prep_all(const float* __restrict__ x, const float* __restrict__ mask,
                         const float* __restrict__ W,
                         const float* __restrict__ xpw_f, const float* __restrict__ xpw_r,
                         const float* __restrict__ dtw_f, const float* __restrict__ dtw_r,
                         const float* __restrict__ outpw,
                         const float* __restrict__ Af, const float* __restrict__ Ar,
                         unsigned short* __restrict__ xb, unsigned short* __restrict__ Wcat,
                         unsigned short* __restrict__ xpb, unsigned short* __restrict__ dtwb,
                         unsigned short* __restrict__ opb, float* __restrict__ A2,
                         float* __restrict__ xdbl_z, float* __restrict__ out_z)
{
  int i = (blockIdx.x * 256 + threadIdx.x) * 4;
  if (i < N_XB) {
    const float4 v = *(const float4*)&x[i];
    const float m = mask[i >> 10];
    ushort4 o; o.x = f2bf(v.x * m); o.y = f2bf(v.y * m); o.z = f2bf(v.z * m); o.w = f2bf(v.w * m);
    *(ushort4*)&xb[i] = o; return;
  }
  i -= N_XB;
  if (i < N_WH) {
    const int nrow = i >> 10, k = i & 1023;
    const float4 v = *(const float4*)&W[i];
    ushort4 o; o.x = f2bf(v.x); o.y = f2bf(v.y); o.z = f2bf(v.z); o.w = f2bf(v.w);
    *(ushort4*)&Wcat[i] = o;
    ushort4 rr; rr.x = f2bf(v.w); rr.y = f2bf(v.z); rr.z = f2bf(v.y); rr.w = f2bf(v.x);
    *(ushort4*)&Wcat[(size_t)(4096 + nrow) * 1024 + (1020 - k)] = rr;
    return;
  }
  i -= N_WH;
  if (i < N_XPB) { cvt4(&xpw_f[i], &xpb[i]); return; }
  i -= N_XPB;
  if (i < N_XPB) { cvt4(&xpw_r[i], &xpb[N_XPB + i]); return; }
  i -= N_XPB;
  if (i < N_DTWB) { cvt4(&dtw_f[i], &dtwb[i]); return; }
  i -= N_DTWB;
  if (i < N_DTWB) { cvt4(&dtw_r[i], &dtwb[N_DTWB + i]); return; }
  i -= N_DTWB;
  if (i < N_OPB) { cvt4(&outpw[i], &opb[i]); return; }
  i -= N_OPB;
  if (i < N_A2) {
    const float4 v = *(const float4*)&Af[i];
    float4 o; o.x = -__expf(v.x); o.y = -__expf(v.y); o.z = -__expf(v.z); o.w = -__expf(v.w);
    *(float4*)&A2[i] = o; return;
  }
  i -= N_A2;
  if (i < N_A2) {
    const float4 v = *(const float4*)&Ar[i];
    float4 o; o.x = -__expf(v.x); o.y = -__expf(v.y); o.z = -__expf(v.z); o.w = -__expf(v.w);
    *(float4*)&A2[N_A2 + i] = o; return;
  }
  i -= N_A2;
  if (i < N_ZXD) { *(float4*)&xdbl_z[i] = (float4){0.f, 0.f, 0.f, 0.f}; return; }
  i -= N_ZXD;
  if (i < N_ZOUT) { *(float4*)&out_z[i] = (float4){0.f, 0.f, 0.f, 0.f}; return; }
}

__global__ void cvt_dtb(const float* __restrict__ xdbl, unsigned short* __restrict__ dtb) {
  int i = (blockIdx.x * 256 + threadIdx.x) * 4;
  if (i < 2 * MR * RK) {
    const int dir = i / (MR * RK);
    const int j = i % (MR * RK);
    const int r = j >> 6, k = j & 63;
    cvt4(&xdbl[(size_t)dir * (MR * 96) + (size_t)r * 96 + k], &dtb[i]);
  }
}

// ---------------- G1: 256x256 tile, BK=64, swizzled-LDS bf16 MFMA GEMM ----------------
// C(2048x8192, bf16) = A(2048x1024) @ B(8192x1024)^T. 8 waves (2Mx4N), 128KB LDS.
// 2-phase discipline: all 8 stage-loads issued at half start; one __syncthreads per
// K-tile (vmcnt(0)+barrier) separates every LDS write window from its read window.
// LDS swizzle (rule #21, both-sides): linear gload_lds dest + pre-swizzled GLOBAL
// source col (col ^ ((row>>1)&7)<<3) + the same XOR on the ds_read address.
__global__ __launch_bounds__(512)
void gemm256(const unsigned short* __restrict__ A, const unsigned short* __restrict__ B,
             unsigned short* __restrict__ C)
{
  __shared__ __align__(16) unsigned short As[2][16384];   // 2 x 256x64
  __shared__ __align__(16) unsigned short Bs[2][16384];   // 2 x 256x64
  const int tid = threadIdx.x;
  const int wid = tid >> 6, lane = tid & 63;
  const int bm = blockIdx.y * 256;
  const int bn = blockIdx.x * 256;
  const int wm = wid >> 2, wn = wid & 3;      // wave owns rows wm*128..+128, cols wn*64..+64
  const bool isA = wid < 4;
  const int cw = isA ? wid : wid - 4;

  // staging: waves 0-3 stage A, 4-7 stage B; 8 x 16B per thread per K-tile
  const unsigned short* sp[8];
#pragma unroll
  for (int l = 0; l < 8; ++l) {
    const int row = cw * 64 + l * 8 + (lane >> 3);                 // 0..255
    const int col = ((lane & 7) * 8) ^ (((row >> 1) & 7) << 3);    // pre-swizzled source
    sp[l] = (isA ? A + (size_t)(bm + row) * 1024
                 : B + (size_t)(bn + row) * 1024) + col;
  }
  const int dbase = cw * 4096 + lane * 8;     // linear LDS element offset (dest)

  f32x4 acc[8][4];
#pragma unroll
  for (int rf = 0; rf < 8; ++rf)
#pragma unroll
    for (int cf = 0; cf < 4; ++cf) acc[rf][cf] = (f32x4){0.f, 0.f, 0.f, 0.f};

#define STG256(b, kt)                                                                  \
  do {                                                                                 \
    unsigned short* dst = (isA ? &As[b][0] : &Bs[b][0]) + dbase;                       \
    const int kk = (kt) * 64;                                                          \
    _Pragma("unroll")                                                                  \
    for (int l = 0; l < 8; ++l)                                                        \
      __builtin_amdgcn_global_load_lds(                                                \
          (const __attribute__((address_space(1))) void*)(sp[l] + kk),                 \
          (__attribute__((address_space(3))) void*)(dst + l * 512), 16, 0, 0);         \
  } while (0)

  const int rsel = lane & 15;
  const int ko = (lane >> 4) * 8;
  const int swzl = ((rsel >> 1) & 7) << 3;    // row-derived XOR, same as staging side

  STG256(0, 0);
  __syncthreads();                             // tile 0 landed
  for (int t = 0; t < 16; ++t) {
    const int buf = t & 1;
    if (t < 15) STG256(buf ^ 1, t + 1);        // issue all 8 loads up front
    const unsigned short* pa = &As[buf][0];
    const unsigned short* pb = &Bs[buf][0];
#pragma unroll
    for (int ks = 0; ks < 2; ++ks) {
      const int kl = (ks * 32 + ko) ^ swzl;
      bf16x8 bfv[4];
#pragma unroll
      for (int cf = 0; cf < 4; ++cf)
        bfv[cf] = *(const bf16x8*)&pb[(wn * 64 + cf * 16 + rsel) * 64 + kl];
#pragma unroll
      for (int rf = 0; rf < 8; ++rf) {
        const bf16x8 af = *(const bf16x8*)&pa[(wm * 128 + rf * 16 + rsel) * 64 + kl];
#pragma unroll
        for (int cf = 0; cf < 4; ++cf)
          acc[rf][cf] = __builtin_amdgcn_mfma_f32_16x16x32_bf16(af, bfv[cf], acc[rf][cf], 0, 0, 0);
      }
    }
    __syncthreads();                           // vmcnt(0) drain + barrier: next tile ready
  }
#undef STG256

#pragma unroll
  for (int rf = 0; rf < 8; ++rf) {
    const int row0 = bm + wm * 128 + rf * 16 + (lane >> 4) * 4;
#pragma unroll
    for (int cf = 0; cf < 4; ++cf) {
      const int col = bn + wn * 64 + cf * 16 + rsel;
#pragma unroll
      for (int j = 0; j < 4; ++j)
        C[(size_t)(row0 + j) * 8192 + col] = f2bf(acc[rf][cf][j]);
    }
  }
}

// ---------------- bf16 MFMA GEMM, C = A(M,K) * B(N,K)^T, 128x128 tile ----------------
// 2-phase double-buffered pipeline (G2/G3/G4).

struct GArg { const unsigned short* A; const unsigned short* B; void* C; const float* bias; };

template<int EPI, int OUT, int ATOMIC, int NDIR>
__global__ __launch_bounds__(256)
void gemm_bt(GArg g0, GArg g1, int M, int N, int K, int lda, int ldb, int ldc, int koff)
{
  __shared__ __align__(16) unsigned short As[2][128 * 32];
  __shared__ __align__(16) unsigned short Bs[2][128 * 32];
  const GArg ga = (NDIR == 2 && (blockIdx.z & 1)) ? g1 : g0;
  const int kc = (NDIR == 2) ? ((int)blockIdx.z >> 1) : (int)blockIdx.z;
  const unsigned short* Ap = ga.A + (size_t)kc * koff;
  const unsigned short* Bp = ga.B + (size_t)kc * koff;

  const int tid  = threadIdx.x;
  const int wave = tid >> 6;
  const int lane = tid & 63;
  const int bm = blockIdx.y * 128;
  const int bn = blockIdx.x * 128;
  const int wr = wave >> 1, wc = wave & 1;

  f32x4 acc[4][4];
#pragma unroll
  for (int m = 0; m < 4; ++m)
#pragma unroll
    for (int n = 0; n < 4; ++n) acc[m][n] = (f32x4){0.f, 0.f, 0.f, 0.f};

  const int rsel = lane & 15;
  const int ksel = (lane >> 4) * 8;
  const int NT = K >> 5;

  const int chunk0 = wave * 2;
  const int flat0  = chunk0 * 512 + lane * 8;
  const int row0s  = flat0 >> 5, col0s = flat0 & 31;
  const int flat1  = (chunk0 + 1) * 512 + lane * 8;
  const int row1s  = flat1 >> 5, col1s = flat1 & 31;
  int grA0 = bm + row0s; if (grA0 > M - 1) grA0 = M - 1;
  int grA1 = bm + row1s; if (grA1 > M - 1) grA1 = M - 1;
  int gcB0 = bn + row0s; if (gcB0 > N - 1) gcB0 = N - 1;
  int gcB1 = bn + row1s; if (gcB1 > N - 1) gcB1 = N - 1;

#define STAGE(buf, kt)                                                                       \
  do {                                                                                       \
    const int k0_ = (kt) << 5;                                                               \
    __builtin_amdgcn_global_load_lds(                                                        \
        (const __attribute__((address_space(1))) void*)(Ap + (size_t)grA0 * lda + k0_ + col0s), \
        (__attribute__((address_space(3))) void*)(&As[buf][chunk0 * 512]), 16, 0, 0);        \
    __builtin_amdgcn_global_load_lds(                                                        \
        (const __attribute__((address_space(1))) void*)(Ap + (size_t)grA1 * lda + k0_ + col1s), \
        (__attribute__((address_space(3))) void*)(&As[buf][(chunk0 + 1) * 512]), 16, 0, 0);  \
    __builtin_amdgcn_global_load_lds(                                                        \
        (const __attribute__((address_space(1))) void*)(Bp + (size_t)gcB0 * ldb + k0_ + col0s), \
        (__attribute__((address_space(3))) void*)(&Bs[buf][chunk0 * 512]), 16, 0, 0);        \
    __builtin_amdgcn_global_load_lds(                                                        \
        (const __attribute__((address_space(1))) void*)(Bp + (size_t)gcB1 * ldb + k0_ + col1s), \
        (__attribute__((address_space(3))) void*)(&Bs[buf][(chunk0 + 1) * 512]), 16, 0, 0);  \
  } while (0)

  STAGE(0, 0);
  __syncthreads();
  int cur = 0;
  for (int kt = 0; kt < NT; ++kt) {
    if (kt + 1 < NT) STAGE(cur ^ 1, kt + 1);
    bf16x8 af[4], bfv[4];
#pragma unroll
    for (int m = 0; m < 4; ++m)
      af[m] = *(const bf16x8*)&As[cur][(wr * 64 + m * 16 + rsel) * 32 + ksel];
#pragma unroll
    for (int n = 0; n < 4; ++n)
      bfv[n] = *(const bf16x8*)&Bs[cur][(wc * 64 + n * 16 + rsel) * 32 + ksel];
#pragma unroll
    for (int m = 0; m < 4; ++m)
#pragma unroll
      for (int n = 0; n < 4; ++n)
        acc[m][n] = __builtin_amdgcn_mfma_f32_16x16x32_bf16(af[m], bfv[n], acc[m][n], 0, 0, 0);
    if (kt + 1 < NT) {
      __syncthreads();
      cur ^= 1;
    }
  }
#undef STAGE

#pragma unroll
  for (int m = 0; m < 4; ++m) {
    const int rowb = bm + wr * 64 + m * 16 + (lane >> 4) * 4;
#pragma unroll
    for (int n = 0; n < 4; ++n) {
      const int col = bn + wc * 64 + n * 16 + rsel;
      if (col < N) {
#pragma unroll
        for (int r = 0; r < 4; ++r) {
          const int rr = rowb + r;
          if (rr < M) {
            float v = acc[m][n][r];
            if constexpr (EPI == 1) {
              v += ga.bias[col];
              v = (v > 15.f) ? v : log1pf(__expf(v));   // softplus
            }
            if constexpr (ATOMIC) {
              atomicAdd((float*)ga.C + (size_t)rr * ldc + col, v);
            } else if constexpr (OUT == 1) {
              ((unsigned short*)ga.C)[(size_t)rr * ldc + col] = f2bf(v);
            } else {
              ((float*)ga.C)[(size_t)rr * ldc + col] = v;
            }
          }
        }
      }
    }
  }
}

// ---------------- depthwise causal conv(4) + silu -> bf16 (x8 d-vectorized) -----------
__global__ __launch_bounds__(256)
void conv_silu_k(const unsigned short* __restrict__ xz,
                 const float* __restrict__ cw_f, const float* __restrict__ cb_f,
                 const float* __restrict__ cw_r, const float* __restrict__ cb_r,
                 unsigned short* __restrict__ ub)
{
  const int tid = threadIdx.x;
  const int d0  = tid * 8;
  const int l0  = blockIdx.x * 16;
  const int dir = blockIdx.y >> 1, b = blockIdx.y & 1;
  const float* cw = dir ? cw_r : cw_f;
  const float* cb = dir ? cb_r : cb_f;
  float w0[8], w1[8], w2[8], w3[8], bs[8];
#pragma unroll
  for (int j = 0; j < 8; ++j) {
    const float4 wv = *(const float4*)&cw[(d0 + j) * 4];
    w0[j] = wv.x; w1[j] = wv.y; w2[j] = wv.z; w3[j] = wv.w;
    bs[j] = cb[d0 + j];
  }
  const unsigned short* uin = xz + (size_t)dir * 4096 + d0;
  unsigned short* uo = ub + (size_t)dir * ((size_t)MR * DI) + d0;
  const size_t rbase = (size_t)b * LL;
  float xa[8], xbv[8], xc[8];
#pragma unroll
  for (int j = 0; j < 8; ++j) { xa[j] = 0.f; xbv[j] = 0.f; xc[j] = 0.f; }
  if (l0 >= 3) { const short8v v = *(const short8v*)&uin[(rbase + l0 - 3) * 8192];
#pragma unroll
    for (int j = 0; j < 8; ++j) xa[j] = bf2f((unsigned short)v[j]); }
  if (l0 >= 2) { const short8v v = *(const short8v*)&uin[(rbase + l0 - 2) * 8192];
#pragma unroll
    for (int j = 0; j < 8; ++j) xbv[j] = bf2f((unsigned short)v[j]); }
  if (l0 >= 1) { const short8v v = *(const short8v*)&uin[(rbase + l0 - 1) * 8192];
#pragma unroll
    for (int j = 0; j < 8; ++j) xc[j] = bf2f((unsigned short)v[j]); }
  for (int l = l0; l < l0 + 16; ++l) {
    const short8v v = *(const short8v*)&uin[(rbase + l) * 8192];
    short8v ov;
#pragma unroll
    for (int j = 0; j < 8; ++j) {
      const float x3 = bf2f((unsigned short)v[j]);
      float o = w0[j] * xa[j] + w1[j] * xbv[j] + w2[j] * xc[j] + w3[j] * x3 + bs[j];
      o = o / (1.f + __expf(-o));   // silu
      ov[j] = (short)f2bf(o);
      xa[j] = xbv[j]; xbv[j] = xc[j]; xc[j] = x3;
    }
    *(short8v*)&uo[(rbase + l) * DI] = ov;
  }
}

// ---------------- chunked selective scan (bf16 delta/state, f32 sumdl) ----------------
__global__ __launch_bounds__(256)
void scanA(const unsigned short* __restrict__ dlt, const unsigned short* __restrict__ ub,
           const float* __restrict__ xdbl, const float* __restrict__ A2,
           float* __restrict__ sdl, unsigned short* __restrict__ hb)
{
  const int tid = threadIdx.x;
  const int d = blockIdx.x * 256 + tid;
  const int c = blockIdx.y;
  const int dir = blockIdx.z >> 1, b = blockIdx.z & 1;
  __shared__ float sB[LC * DS];
  const float* xd = xdbl + (size_t)dir * (MR * 96);
  for (int i = tid; i < LC * DS; i += 256) {
    int t = i >> 4, s = i & 15;
    sB[i] = xd[(size_t)(b * LL + c * LC + t) * 96 + 64 + s];
  }
  __syncthreads();
  const unsigned short* dl_p = dlt + (size_t)dir * ((size_t)MR * DI) + d;
  const unsigned short* uu = ub + (size_t)dir * ((size_t)MR * DI) + d;
  float a2[DS];
#pragma unroll
  for (int s = 0; s < DS; ++s) a2[s] = A2[((size_t)dir * DI + d) * DS + s];
  float h[DS];
#pragma unroll
  for (int s = 0; s < DS; ++s) h[s] = 0.f;
  float sumdl = 0.f;
  for (int t = 0; t < LC; ++t) {
    size_t r = (size_t)b * LL + c * LC + t;
    float dl = bf2f(dl_p[r * DI]);
    float du = dl * bf2f(uu[r * DI]);
    sumdl += dl;
#pragma unroll
    for (int s = 0; s < DS; ++s) {
      float e = __expf(dl * a2[s]);
      h[s] = e * h[s] + du * sB[t * DS + s];
    }
  }
  const size_t base = ((((size_t)(dir * 2 + b)) * NCH + c) * DI + d) * DS;
#pragma unroll
  for (int s = 0; s < DS; ++s) hb[base + s] = f2bf(h[s]);
  sdl[(((size_t)(dir * 2 + b)) * NCH + c) * DI + d] = sumdl;
}

__global__ __launch_bounds__(256)
void scanB(const float* __restrict__ sdl, const float* __restrict__ A2,
           unsigned short* __restrict__ hb)
{
  const int i = blockIdx.x * 256 + threadIdx.x;
  const int db = i >> 15;
  const int ds_ = i & 32767;
  const int d = ds_ >> 4, s = i & 15;
  const int dir = db >> 1;
  const float a2 = A2[((size_t)dir * DI + d) * DS + s];
  float hrun = 0.f;
  for (int c = 0; c < NCH; ++c) {
    const size_t off = (((size_t)db * NCH + c) << 15) + ds_;
    const float h0 = bf2f(hb[off]);
    const float pa = __expf(a2 * sdl[((size_t)db * NCH + c) * DI + d]);
    hb[off] = f2bf(hrun);
    hrun = pa * hrun + h0;
  }
}

__global__ __launch_bounds__(256)
void scanC_f(const unsigned short* __restrict__ xz, const unsigned short* __restrict__ ub,
             const unsigned short* __restrict__ dlt, const float* __restrict__ xdbl,
             const float* __restrict__ A2, const float* __restrict__ Dv_f,
             const float* __restrict__ Dv_r, const unsigned short* __restrict__ hb,
             unsigned short* __restrict__ ygb)
{
  const int tid = threadIdx.x;
  const int d = blockIdx.x * 256 + tid;
  const int c = blockIdx.y;
  const int b = blockIdx.z;
  __shared__ float sB[2][LC * DS], sC[2][LC * DS];
  for (int i = tid; i < LC * DS; i += 256) {
    int t = i >> 4, s = i & 15;
    size_t ro = (size_t)(b * LL + c * LC + t) * 96;
    sB[0][i] = xdbl[ro + 64 + s];
    sC[0][i] = xdbl[ro + 80 + s];
    sB[1][i] = xdbl[(size_t)MR * 96 + ro + 64 + s];
    sC[1][i] = xdbl[(size_t)MR * 96 + ro + 80 + s];
  }
  __syncthreads();
  float a2f[DS], a2r[DS], hf[DS], hr[DS];
  const size_t basef = ((((size_t)b) * NCH + c) * DI + d) * DS;
  const size_t baser = ((((size_t)(2 + b)) * NCH + c) * DI + d) * DS;
#pragma unroll
  for (int s = 0; s < DS; ++s) {
    a2f[s] = A2[(size_t)d * DS + s];
    a2r[s] = A2[((size_t)DI + d) * DS + s];
    hf[s] = bf2f(hb[basef + s]);
    hr[s] = bf2f(hb[baser + s]);
  }
  const float Df = Dv_f[d], Dr = Dv_r[d];
  for (int t = 0; t < LC; ++t) {
    size_t r = (size_t)b * LL + c * LC + t;
    float dlf = bf2f(dlt[r * DI + d]);
    float dlr = bf2f(dlt[(size_t)MR * DI + r * DI + d]);
    float uf = bf2f(ub[r * DI + d]);
    float ur = bf2f(ub[(size_t)MR * DI + r * DI + d]);
    float duf = dlf * uf, dur = dlr * ur;
    float yf = 0.f, yr = 0.f;
#pragma unroll
    for (int s = 0; s < DS; ++s) {
      float ef = __expf(dlf * a2f[s]);
      hf[s] = ef * hf[s] + duf * sB[0][t * DS + s];
      yf += hf[s] * sC[0][t * DS + s];
      float er = __expf(dlr * a2r[s]);
      hr[s] = er * hr[s] + dur * sB[1][t * DS + s];
      yr += hr[s] * sC[1][t * DS + s];
    }
    yf += Df * uf;
    yr += Dr * ur;
    float zf = bf2f(xz[r * 8192 + 2048 + d]);
    float zr = bf2f(xz[r * 8192 + 6144 + d]);
    float yg = yf * (zf / (1.f + __expf(-zf))) + yr * (zr / (1.f + __expf(-zr)));
    ygb[r * DI + d] = f2bf(yg);
  }
}

// ---------------- host launch ----------------

extern "C" void kernel_launch(void* const* d_in, const int* in_sizes, int n_in,
                              void* d_out, int out_size, void* d_ws, size_t ws_size,
                              hipStream_t stream)
{
  (void)in_sizes; (void)n_in; (void)out_size; (void)ws_size;
  const float* x      = (const float*)d_in[0];
  const float* mask   = (const float*)d_in[1];
  const float* inpw   = (const float*)d_in[2];
  const float* outpw  = (const float*)d_in[3];
  const float* cw_f   = (const float*)d_in[4];
  const float* cb_f   = (const float*)d_in[5];
  const float* xpw_f  = (const float*)d_in[6];
  const float* dtw_f  = (const float*)d_in[7];
  const float* dtbias_f = (const float*)d_in[8];
  const float* alog_f = (const float*)d_in[9];
  const float* Dv_f   = (const float*)d_in[10];
  const float* cw_r   = (const float*)d_in[11];
  const float* cb_r   = (const float*)d_in[12];
  const float* xpw_r  = (const float*)d_in[13];
  const float* dtw_r  = (const float*)d_in[14];
  const float* dtbias_r = (const float*)d_in[15];
  const float* alog_r = (const float*)d_in[16];
  const float* Dv_r   = (const float*)d_in[17];
  float* out = (float*)d_out;

  char* p = (char*)d_ws;
  auto carve = [&](size_t bytes) -> char* {
    char* q = p; p += (bytes + 255) & ~(size_t)255; return q;
  };
  unsigned short* xb   = (unsigned short*)carve((size_t)MR * DM * 2);
  unsigned short* Wcat = (unsigned short*)carve((size_t)8192 * 1024 * 2);
  unsigned short* xpb  = (unsigned short*)carve((size_t)2 * 96 * DI * 2);
  unsigned short* dtwb = (unsigned short*)carve((size_t)2 * DI * RK * 2);
  unsigned short* opb  = (unsigned short*)carve((size_t)DM * DI * 2);
  float*          A2   = (float*)carve((size_t)2 * DI * DS * 4);
  unsigned short* xz   = (unsigned short*)carve((size_t)MR * 8192 * 2);
  unsigned short* dlt  = (unsigned short*)carve((size_t)2 * MR * DI * 2);
  unsigned short* ub   = (unsigned short*)carve((size_t)2 * MR * DI * 2);
  float*          xdbl = (float*)carve((size_t)2 * MR * 96 * 4);
  unsigned short* dtb  = (unsigned short*)carve((size_t)2 * MR * RK * 2);
  float*          sdl  = (float*)carve((size_t)4 * NCH * DI * 4);
  unsigned short* hb   = (unsigned short*)carve((size_t)4 * NCH * DI * DS * 2);
  unsigned short* ygb  = (unsigned short*)carve((size_t)MR * DI * 2);

  // fused prep (+ zero-init of atomic targets xdbl/out)
  prep_all<<<(N_PREP / 4 + 255) / 256, 256, 0, stream>>>(
      x, mask, inpw, xpw_f, xpw_r, dtw_f, dtw_r, outpw, alog_f, alog_r,
      xb, Wcat, xpb, dtwb, opb, A2, xdbl, out);

  // G1: xz(2048 x 8192, bf16) = xb @ Wcat^T — 256^2 swizzled kernel
  gemm256<<<dim3(32, 8, 1), 512, 0, stream>>>(xb, Wcat, xz);

  // conv + silu -> ub
  conv_silu_k<<<dim3(64, 4, 1), 256, 0, stream>>>(xz, cw_f, cb_f, cw_r, cb_r, ub);
  // G2: x_dbl = ub @ x_proj^T, split-K=8, atomic accumulate
  {
    GArg g0{ub, xpb, xdbl, nullptr};
    GArg g1{ub + (size_t)MR * DI, xpb + 96 * DI, xdbl + (size_t)MR * 96, nullptr};
    gemm_bt<0, 0, 1, 2><<<dim3(1, 16, 16), 256, 0, stream>>>(
        g0, g1, MR, 96, 256, DI, DI, 96, 256);
  }
  cvt_dtb<<<(2 * MR * RK / 4 + 255) / 256, 256, 0, stream>>>(xdbl, dtb);
  // G3: delta = softplus(dt @ dt_w^T + dt_b) -> dlt (bf16, ldc=DI)
  {
    GArg g0{dtb, dtwb, dlt, dtbias_f};
    GArg g1{dtb + (size_t)MR * RK, dtwb + DI * RK, dlt + (size_t)MR * DI, dtbias_r};
    gemm_bt<1, 1, 0, 2><<<dim3(16, 16, 2), 256, 0, stream>>>(
        g0, g1, MR, DI, 64, RK, RK, DI, 0);
  }
  scanA<<<dim3(8, NCH, 4), 256, 0, stream>>>(dlt, ub, xdbl, A2, sdl, hb);
  scanB<<<dim3(512, 1, 1), 256, 0, stream>>>(sdl, A2, hb);
  scanC_f<<<dim3(8, NCH, 2), 256, 0, stream>>>(xz, ub, dlt, xdbl, A2, Dv_f, Dv_r, hb, ygb);
  // G4: out = ygb @ out_proj^T, split-K=4, atomic accumulate
  {
    GArg g0{ygb, opb, out, nullptr};
    gemm_bt<0, 0, 1, 1><<<dim3(8, 16, 4), 256, 0, stream>>>(
        g0, g0, MR, DM, 512, DI, DI, DM, 512);
  }
}

// Round 8
// 239.256 us; speedup vs baseline: 1.4795x; 1.0131x over previous
//
#include <hip/hip_runtime.h>

#define DM   1024
#define DI   2048
#define DS   16
#define RK   64
#define NBAT 2
#define LL   1024
#define MR   (NBAT*LL)   // 2048 rows (B*L)
#define NCH  128         // scan chunks
#define LC   (LL/NCH)    // 8 steps per chunk

typedef short  bf16x8 __attribute__((ext_vector_type(8)));
typedef short  short8v __attribute__((ext_vector_type(8)));
typedef float  f32x4  __attribute__((ext_vector_type(4)));

__device__ __forceinline__ float bf2f(unsigned short u) {
  union { unsigned int i; float f; } v; v.i = ((unsigned int)u) << 16; return v.f;
}
__device__ __forceinline__ unsigned short f2bf(float f) {
  union { float f; unsigned int i; } v; v.f = f;
  return (unsigned short)((v.i + 0x7FFFu + ((v.i >> 16) & 1u)) >> 16);  // RNE
}
__device__ __forceinline__ float fsilu(float z) {
  return z * __builtin_amdgcn_rcpf(1.f + __expf(-z));   // v_rcp_f32, ~1e-5 rel
}

// ---------------- fused prep / convert / zero-init (one launch, x4 vectorized) --------
#define N_XB    (MR*DM)
#define N_WH    (4096*1024)       // half of Wcat (source W elements)
#define N_XPB   (96*DI)
#define N_DTWB  (DI*RK)
#define N_OPB   (DM*DI)
#define N_A2    (DI*DS)
#define N_ZXD   (2*MR*96)
#define N_ZOUT  (MR*DM)
#define N_PREP  (N_XB + N_WH + 2*N_XPB + 2*N_DTWB + N_OPB + 2*N_A2 + N_ZXD + N_ZOUT)

__device__ __forceinline__ void cvt4(const float* src, unsigned short* dst) {
  const float4 v = *(const float4*)src;
  ushort4 o; o.x = f2bf(v.x); o.y = f2bf(v.y); o.z = f2bf(v.z); o.w = f2bf(v.w);
  *(ushort4*)dst = o;
}

__global__ void prep_all(const float* __restrict__ x, const float* __restrict__ mask,
                         const float* __restrict__ W,
                         const float* __restrict__ xpw_f, const float* __restrict__ xpw_r,
                         const float* __restrict__ dtw_f, const float* __restrict__ dtw_r,
                         const float* __restrict__ outpw,
                         const float* __restrict__ Af, const float* __restrict__ Ar,
                         unsigned short* __restrict__ xb, unsigned short* __restrict__ Wcat,
                         unsigned short* __restrict__ xpb, unsigned short* __restrict__ dtwb,
                         unsigned short* __restrict__ opb, float* __restrict__ A2,
                         float* __restrict__ xdbl_z, float* __restrict__ out_z)
{
  int i = (blockIdx.x * 256 + threadIdx.x) * 4;
  if (i < N_XB) {
    const float4 v = *(const float4*)&x[i];
    const float m = mask[i >> 10];
    ushort4 o; o.x = f2bf(v.x * m); o.y = f2bf(v.y * m); o.z = f2bf(v.z * m); o.w = f2bf(v.w * m);
    *(ushort4*)&xb[i] = o; return;
  }
  i -= N_XB;
  if (i < N_WH) {
    const int nrow = i >> 10, k = i & 1023;
    const float4 v = *(const float4*)&W[i];
    ushort4 o; o.x = f2bf(v.x); o.y = f2bf(v.y); o.z = f2bf(v.z); o.w = f2bf(v.w);
    *(ushort4*)&Wcat[i] = o;
    ushort4 rr; rr.x = f2bf(v.w); rr.y = f2bf(v.z); rr.z = f2bf(v.y); rr.w = f2bf(v.x);
    *(ushort4*)&Wcat[(size_t)(4096 + nrow) * 1024 + (1020 - k)] = rr;
    return;
  }
  i -= N_WH;
  if (i < N_XPB) { cvt4(&xpw_f[i], &xpb[i]); return; }
  i -= N_XPB;
  if (i < N_XPB) { cvt4(&xpw_r[i], &xpb[N_XPB + i]); return; }
  i -= N_XPB;
  if (i < N_DTWB) { cvt4(&dtw_f[i], &dtwb[i]); return; }
  i -= N_DTWB;
  if (i < N_DTWB) { cvt4(&dtw_r[i], &dtwb[N_DTWB + i]); return; }
  i -= N_DTWB;
  if (i < N_OPB) { cvt4(&outpw[i], &opb[i]); return; }
  i -= N_OPB;
  if (i < N_A2) {
    const float4 v = *(const float4*)&Af[i];
    float4 o; o.x = -__expf(v.x); o.y = -__expf(v.y); o.z = -__expf(v.z); o.w = -__expf(v.w);
    *(float4*)&A2[i] = o; return;
  }
  i -= N_A2;
  if (i < N_A2) {
    const float4 v = *(const float4*)&Ar[i];
    float4 o; o.x = -__expf(v.x); o.y = -__expf(v.y); o.z = -__expf(v.z); o.w = -__expf(v.w);
    *(float4*)&A2[N_A2 + i] = o; return;
  }
  i -= N_A2;
  if (i < N_ZXD) { *(float4*)&xdbl_z[i] = (float4){0.f, 0.f, 0.f, 0.f}; return; }
  i -= N_ZXD;
  if (i < N_ZOUT) { *(float4*)&out_z[i] = (float4){0.f, 0.f, 0.f, 0.f}; return; }
}

__global__ void cvt_dtb(const float* __restrict__ xdbl, unsigned short* __restrict__ dtb) {
  int i = (blockIdx.x * 256 + threadIdx.x) * 4;
  if (i < 2 * MR * RK) {
    const int dir = i / (MR * RK);
    const int j = i % (MR * RK);
    const int r = j >> 6, k = j & 63;
    cvt4(&xdbl[(size_t)dir * (MR * 96) + (size_t)r * 96 + k], &dtb[i]);
  }
}

// ---------------- G1: 256x256 tile, BK=64, swizzled-LDS bf16 MFMA GEMM ----------------
__global__ __launch_bounds__(512)
void gemm256(const unsigned short* __restrict__ A, const unsigned short* __restrict__ B,
             unsigned short* __restrict__ C)
{
  __shared__ __align__(16) unsigned short As[2][16384];   // 2 x 256x64
  __shared__ __align__(16) unsigned short Bs[2][16384];   // 2 x 256x64
  const int tid = threadIdx.x;
  const int wid = tid >> 6, lane = tid & 63;
  const int bm = blockIdx.y * 256;
  const int bn = blockIdx.x * 256;
  const int wm = wid >> 2, wn = wid & 3;
  const bool isA = wid < 4;
  const int cw = isA ? wid : wid - 4;

  const unsigned short* sp[8];
#pragma unroll
  for (int l = 0; l < 8; ++l) {
    const int row = cw * 64 + l * 8 + (lane >> 3);
    const int col = ((lane & 7) * 8) ^ (((row >> 1) & 7) << 3);    // pre-swizzled source
    sp[l] = (isA ? A + (size_t)(bm + row) * 1024
                 : B + (size_t)(bn + row) * 1024) + col;
  }
  const int dbase = cw * 4096 + lane * 8;

  f32x4 acc[8][4];
#pragma unroll
  for (int rf = 0; rf < 8; ++rf)
#pragma unroll
    for (int cf = 0; cf < 4; ++cf) acc[rf][cf] = (f32x4){0.f, 0.f, 0.f, 0.f};

#define STG256(b, kt)                                                                  \
  do {                                                                                 \
    unsigned short* dst = (isA ? &As[b][0] : &Bs[b][0]) + dbase;                       \
    const int kk = (kt) * 64;                                                          \
    _Pragma("unroll")                                                                  \
    for (int l = 0; l < 8; ++l)                                                        \
      __builtin_amdgcn_global_load_lds(                                                \
          (const __attribute__((address_space(1))) void*)(sp[l] + kk),                 \
          (__attribute__((address_space(3))) void*)(dst + l * 512), 16, 0, 0);         \
  } while (0)

  const int rsel = lane & 15;
  const int ko = (lane >> 4) * 8;
  const int swzl = ((rsel >> 1) & 7) << 3;

  STG256(0, 0);
  __syncthreads();
  for (int t = 0; t < 16; ++t) {
    const int buf = t & 1;
    if (t < 15) STG256(buf ^ 1, t + 1);
    const unsigned short* pa = &As[buf][0];
    const unsigned short* pb = &Bs[buf][0];
#pragma unroll
    for (int ks = 0; ks < 2; ++ks) {
      const int kl = (ks * 32 + ko) ^ swzl;
      bf16x8 bfv[4];
#pragma unroll
      for (int cf = 0; cf < 4; ++cf)
        bfv[cf] = *(const bf16x8*)&pb[(wn * 64 + cf * 16 + rsel) * 64 + kl];
#pragma unroll
      for (int rf = 0; rf < 8; ++rf) {
        const bf16x8 af = *(const bf16x8*)&pa[(wm * 128 + rf * 16 + rsel) * 64 + kl];
#pragma unroll
        for (int cf = 0; cf < 4; ++cf)
          acc[rf][cf] = __builtin_amdgcn_mfma_f32_16x16x32_bf16(af, bfv[cf], acc[rf][cf], 0, 0, 0);
      }
    }
    __syncthreads();
  }
#undef STG256

#pragma unroll
  for (int rf = 0; rf < 8; ++rf) {
    const int row0 = bm + wm * 128 + rf * 16 + (lane >> 4) * 4;
#pragma unroll
    for (int cf = 0; cf < 4; ++cf) {
      const int col = bn + wn * 64 + cf * 16 + rsel;
#pragma unroll
      for (int j = 0; j < 4; ++j)
        C[(size_t)(row0 + j) * 8192 + col] = f2bf(acc[rf][cf][j]);
    }
  }
}

// ---------------- bf16 MFMA GEMM, C = A(M,K) * B(N,K)^T, 128x128 tile ----------------
struct GArg { const unsigned short* A; const unsigned short* B; void* C; const float* bias; };

template<int EPI, int OUT, int ATOMIC, int NDIR>
__global__ __launch_bounds__(256)
void gemm_bt(GArg g0, GArg g1, int M, int N, int K, int lda, int ldb, int ldc, int koff)
{
  __shared__ __align__(16) unsigned short As[2][128 * 32];
  __shared__ __align__(16) unsigned short Bs[2][128 * 32];
  const GArg ga = (NDIR == 2 && (blockIdx.z & 1)) ? g1 : g0;
  const int kc = (NDIR == 2) ? ((int)blockIdx.z >> 1) : (int)blockIdx.z;
  const unsigned short* Ap = ga.A + (size_t)kc * koff;
  const unsigned short* Bp = ga.B + (size_t)kc * koff;

  const int tid  = threadIdx.x;
  const int wave = tid >> 6;
  const int lane = tid & 63;
  const int bm = blockIdx.y * 128;
  const int bn = blockIdx.x * 128;
  const int wr = wave >> 1, wc = wave & 1;

  f32x4 acc[4][4];
#pragma unroll
  for (int m = 0; m < 4; ++m)
#pragma unroll
    for (int n = 0; n < 4; ++n) acc[m][n] = (f32x4){0.f, 0.f, 0.f, 0.f};

  const int rsel = lane & 15;
  const int ksel = (lane >> 4) * 8;
  const int NT = K >> 5;

  const int chunk0 = wave * 2;
  const int flat0  = chunk0 * 512 + lane * 8;
  const int row0s  = flat0 >> 5, col0s = flat0 & 31;
  const int flat1  = (chunk0 + 1) * 512 + lane * 8;
  const int row1s  = flat1 >> 5, col1s = flat1 & 31;
  int grA0 = bm + row0s; if (grA0 > M - 1) grA0 = M - 1;
  int grA1 = bm + row1s; if (grA1 > M - 1) grA1 = M - 1;
  int gcB0 = bn + row0s; if (gcB0 > N - 1) gcB0 = N - 1;
  int gcB1 = bn + row1s; if (gcB1 > N - 1) gcB1 = N - 1;

#define STAGE(buf, kt)                                                                       \
  do {                                                                                       \
    const int k0_ = (kt) << 5;                                                               \
    __builtin_amdgcn_global_load_lds(                                                        \
        (const __attribute__((address_space(1))) void*)(Ap + (size_t)grA0 * lda + k0_ + col0s), \
        (__attribute__((address_space(3))) void*)(&As[buf][chunk0 * 512]), 16, 0, 0);        \
    __builtin_amdgcn_global_load_lds(                                                        \
        (const __attribute__((address_space(1))) void*)(Ap + (size_t)grA1 * lda + k0_ + col1s), \
        (__attribute__((address_space(3))) void*)(&As[buf][(chunk0 + 1) * 512]), 16, 0, 0);  \
    __builtin_amdgcn_global_load_lds(                                                        \
        (const __attribute__((address_space(1))) void*)(Bp + (size_t)gcB0 * ldb + k0_ + col0s), \
        (__attribute__((address_space(3))) void*)(&Bs[buf][chunk0 * 512]), 16, 0, 0);        \
    __builtin_amdgcn_global_load_lds(                                                        \
        (const __attribute__((address_space(1))) void*)(Bp + (size_t)gcB1 * ldb + k0_ + col1s), \
        (__attribute__((address_space(3))) void*)(&Bs[buf][(chunk0 + 1) * 512]), 16, 0, 0);  \
  } while (0)

  STAGE(0, 0);
  __syncthreads();
  int cur = 0;
  for (int kt = 0; kt < NT; ++kt) {
    if (kt + 1 < NT) STAGE(cur ^ 1, kt + 1);
    bf16x8 af[4], bfv[4];
#pragma unroll
    for (int m = 0; m < 4; ++m)
      af[m] = *(const bf16x8*)&As[cur][(wr * 64 + m * 16 + rsel) * 32 + ksel];
#pragma unroll
    for (int n = 0; n < 4; ++n)
      bfv[n] = *(const bf16x8*)&Bs[cur][(wc * 64 + n * 16 + rsel) * 32 + ksel];
#pragma unroll
    for (int m = 0; m < 4; ++m)
#pragma unroll
      for (int n = 0; n < 4; ++n)
        acc[m][n] = __builtin_amdgcn_mfma_f32_16x16x32_bf16(af[m], bfv[n], acc[m][n], 0, 0, 0);
    if (kt + 1 < NT) {
      __syncthreads();
      cur ^= 1;
    }
  }
#undef STAGE

#pragma unroll
  for (int m = 0; m < 4; ++m) {
    const int rowb = bm + wr * 64 + m * 16 + (lane >> 4) * 4;
#pragma unroll
    for (int n = 0; n < 4; ++n) {
      const int col = bn + wc * 64 + n * 16 + rsel;
      if (col < N) {
#pragma unroll
        for (int r = 0; r < 4; ++r) {
          const int rr = rowb + r;
          if (rr < M) {
            float v = acc[m][n][r];
            if constexpr (EPI == 1) {
              v += ga.bias[col];
              v = (v > 15.f) ? v : log1pf(__expf(v));   // softplus
            }
            if constexpr (ATOMIC) {
              atomicAdd((float*)ga.C + (size_t)rr * ldc + col, v);
            } else if constexpr (OUT == 1) {
              ((unsigned short*)ga.C)[(size_t)rr * ldc + col] = f2bf(v);
            } else {
              ((float*)ga.C)[(size_t)rr * ldc + col] = v;
            }
          }
        }
      }
    }
  }
}

// ---------------- depthwise causal conv(4) + silu -> bf16 (x8 d-vectorized) -----------
// 8 rows/thread, 512 blocks
__global__ __launch_bounds__(256)
void conv_silu_k(const unsigned short* __restrict__ xz,
                 const float* __restrict__ cw_f, const float* __restrict__ cb_f,
                 const float* __restrict__ cw_r, const float* __restrict__ cb_r,
                 unsigned short* __restrict__ ub)
{
  const int tid = threadIdx.x;
  const int d0  = tid * 8;
  const int l0  = blockIdx.x * 8;
  const int dir = blockIdx.y >> 1, b = blockIdx.y & 1;
  const float* cw = dir ? cw_r : cw_f;
  const float* cb = dir ? cb_r : cb_f;
  float w0[8], w1[8], w2[8], w3[8], bs[8];
#pragma unroll
  for (int j = 0; j < 8; ++j) {
    const float4 wv = *(const float4*)&cw[(d0 + j) * 4];
    w0[j] = wv.x; w1[j] = wv.y; w2[j] = wv.z; w3[j] = wv.w;
    bs[j] = cb[d0 + j];
  }
  const unsigned short* uin = xz + (size_t)dir * 4096 + d0;
  unsigned short* uo = ub + (size_t)dir * ((size_t)MR * DI) + d0;
  const size_t rbase = (size_t)b * LL;
  float xa[8], xbv[8], xc[8];
#pragma unroll
  for (int j = 0; j < 8; ++j) { xa[j] = 0.f; xbv[j] = 0.f; xc[j] = 0.f; }
  if (l0 >= 3) { const short8v v = *(const short8v*)&uin[(rbase + l0 - 3) * 8192];
#pragma unroll
    for (int j = 0; j < 8; ++j) xa[j] = bf2f((unsigned short)v[j]); }
  if (l0 >= 2) { const short8v v = *(const short8v*)&uin[(rbase + l0 - 2) * 8192];
#pragma unroll
    for (int j = 0; j < 8; ++j) xbv[j] = bf2f((unsigned short)v[j]); }
  if (l0 >= 1) { const short8v v = *(const short8v*)&uin[(rbase + l0 - 1) * 8192];
#pragma unroll
    for (int j = 0; j < 8; ++j) xc[j] = bf2f((unsigned short)v[j]); }
  for (int l = l0; l < l0 + 8; ++l) {
    const short8v v = *(const short8v*)&uin[(rbase + l) * 8192];
    short8v ov;
#pragma unroll
    for (int j = 0; j < 8; ++j) {
      const float x3 = bf2f((unsigned short)v[j]);
      float o = w0[j] * xa[j] + w1[j] * xbv[j] + w2[j] * xc[j] + w3[j] * x3 + bs[j];
      ov[j] = (short)f2bf(fsilu(o));
      xa[j] = xbv[j]; xbv[j] = xc[j]; xc[j] = x3;
    }
    *(short8v*)&uo[(rbase + l) * DI] = ov;
  }
}

// ---------------- chunked selective scan (bf16 delta/state, f32 sumdl) ----------------
__global__ __launch_bounds__(256)
void scanA(const unsigned short* __restrict__ dlt, const unsigned short* __restrict__ ub,
           const float* __restrict__ xdbl, const float* __restrict__ A2,
           float* __restrict__ sdl, unsigned short* __restrict__ hb)
{
  const int tid = threadIdx.x;
  const int d = blockIdx.x * 256 + tid;
  const int c = blockIdx.y;
  const int dir = blockIdx.z >> 1, b = blockIdx.z & 1;
  __shared__ float sB[LC * DS];
  const float* xd = xdbl + (size_t)dir * (MR * 96);
  for (int i = tid; i < LC * DS; i += 256) {
    int t = i >> 4, s = i & 15;
    sB[i] = xd[(size_t)(b * LL + c * LC + t) * 96 + 64 + s];
  }
  __syncthreads();
  const unsigned short* dl_p = dlt + (size_t)dir * ((size_t)MR * DI) + d;
  const unsigned short* uu = ub + (size_t)dir * ((size_t)MR * DI) + d;
  float a2[DS];
#pragma unroll
  for (int s = 0; s < DS; ++s) a2[s] = A2[((size_t)dir * DI + d) * DS + s];
  float h[DS];
#pragma unroll
  for (int s = 0; s < DS; ++s) h[s] = 0.f;
  float sumdl = 0.f;
  for (int t = 0; t < LC; ++t) {
    size_t r = (size_t)b * LL + c * LC + t;
    float dl = bf2f(dl_p[r * DI]);
    float du = dl * bf2f(uu[r * DI]);
    sumdl += dl;
#pragma unroll
    for (int s = 0; s < DS; ++s) {
      float e = __expf(dl * a2[s]);
      h[s] = e * h[s] + du * sB[t * DS + s];
    }
  }
  const size_t base = ((((size_t)(dir * 2 + b)) * NCH + c) * DI + d) * DS;
#pragma unroll
  for (int s = 0; s < DS; ++s) hb[base + s] = f2bf(h[s]);
  sdl[(((size_t)(dir * 2 + b)) * NCH + c) * DI + d] = sumdl;
}

__global__ __launch_bounds__(256)
void scanB(const float* __restrict__ sdl, const float* __restrict__ A2,
           unsigned short* __restrict__ hb)
{
  const int i = blockIdx.x * 256 + threadIdx.x;
  const int db = i >> 15;
  const int ds_ = i & 32767;
  const int d = ds_ >> 4, s = i & 15;
  const int dir = db >> 1;
  const float a2 = A2[((size_t)dir * DI + d) * DS + s];
  float hrun = 0.f;
  for (int c = 0; c < NCH; ++c) {
    const size_t off = (((size_t)db * NCH + c) << 15) + ds_;
    const float h0 = bf2f(hb[off]);
    const float pa = __expf(a2 * sdl[((size_t)db * NCH + c) * DI + d]);
    hb[off] = f2bf(hrun);
    hrun = pa * hrun + h0;
  }
}

__global__ __launch_bounds__(256)
void scanC_f(const unsigned short* __restrict__ xz, const unsigned short* __restrict__ ub,
             const unsigned short* __restrict__ dlt, const float* __restrict__ xdbl,
             const float* __restrict__ A2, const float* __restrict__ Dv_f,
             const float* __restrict__ Dv_r, const unsigned short* __restrict__ hb,
             unsigned short* __restrict__ ygb)
{
  const int tid = threadIdx.x;
  const int d = blockIdx.x * 256 + tid;
  const int c = blockIdx.y;
  const int b = blockIdx.z;
  __shared__ float sB[2][LC * DS], sC[2][LC * DS];
  for (int i = tid; i < LC * DS; i += 256) {
    int t = i >> 4, s = i & 15;
    size_t ro = (size_t)(b * LL + c * LC + t) * 96;
    sB[0][i] = xdbl[ro + 64 + s];
    sC[0][i] = xdbl[ro + 80 + s];
    sB[1][i] = xdbl[(size_t)MR * 96 + ro + 64 + s];
    sC[1][i] = xdbl[(size_t)MR * 96 + ro + 80 + s];
  }
  __syncthreads();
  float a2f[DS], a2r[DS], hf[DS], hr[DS];
  const size_t basef = ((((size_t)b) * NCH + c) * DI + d) * DS;
  const size_t baser = ((((size_t)(2 + b)) * NCH + c) * DI + d) * DS;
#pragma unroll
  for (int s = 0; s < DS; ++s) {
    a2f[s] = A2[(size_t)d * DS + s];
    a2r[s] = A2[((size_t)DI + d) * DS + s];
    hf[s] = bf2f(hb[basef + s]);
    hr[s] = bf2f(hb[baser + s]);
  }
  const float Df = Dv_f[d], Dr = Dv_r[d];
  for (int t = 0; t < LC; ++t) {
    size_t r = (size_t)b * LL + c * LC + t;
    float dlf = bf2f(dlt[r * DI + d]);
    float dlr = bf2f(dlt[(size_t)MR * DI + r * DI + d]);
    float uf = bf2f(ub[r * DI + d]);
    float ur = bf2f(ub[(size_t)MR * DI + r * DI + d]);
    float duf = dlf * uf, dur = dlr * ur;
    float yf = 0.f, yr = 0.f;
#pragma unroll
    for (int s = 0; s < DS; ++s) {
      float ef = __expf(dlf * a2f[s]);
      hf[s] = ef * hf[s] + duf * sB[0][t * DS + s];
      yf += hf[s] * sC[0][t * DS + s];
      float er = __expf(dlr * a2r[s]);
      hr[s] = er * hr[s] + dur * sB[1][t * DS + s];
      yr += hr[s] * sC[1][t * DS + s];
    }
    yf += Df * uf;
    yr += Dr * ur;
    float zf = bf2f(xz[r * 8192 + 2048 + d]);
    float zr = bf2f(xz[r * 8192 + 6144 + d]);
    float yg = yf * fsilu(zf) + yr * fsilu(zr);
    ygb[r * DI + d] = f2bf(yg);
  }
}

// ---------------- host launch ----------------

extern "C" void kernel_launch(void* const* d_in, const int* in_sizes, int n_in,
                              void* d_out, int out_size, void* d_ws, size_t ws_size,
                              hipStream_t stream)
{
  (void)in_sizes; (void)n_in; (void)out_size; (void)ws_size;
  const float* x      = (const float*)d_in[0];
  const float* mask   = (const float*)d_in[1];
  const float* inpw   = (const float*)d_in[2];
  const float* outpw  = (const float*)d_in[3];
  const float* cw_f   = (const float*)d_in[4];
  const float* cb_f   = (const float*)d_in[5];
  const float* xpw_f  = (const float*)d_in[6];
  const float* dtw_f  = (const float*)d_in[7];
  const float* dtbias_f = (const float*)d_in[8];
  const float* alog_f = (const float*)d_in[9];
  const float* Dv_f   = (const float*)d_in[10];
  const float* cw_r   = (const float*)d_in[11];
  const float* cb_r   = (const float*)d_in[12];
  const float* xpw_r  = (const float*)d_in[13];
  const float* dtw_r  = (const float*)d_in[14];
  const float* dtbias_r = (const float*)d_in[15];
  const float* alog_r = (const float*)d_in[16];
  const float* Dv_r   = (const float*)d_in[17];
  float* out = (float*)d_out;

  char* p = (char*)d_ws;
  auto carve = [&](size_t bytes) -> char* {
    char* q = p; p += (bytes + 255) & ~(size_t)255; return q;
  };
  unsigned short* xb   = (unsigned short*)carve((size_t)MR * DM * 2);
  unsigned short* Wcat = (unsigned short*)carve((size_t)8192 * 1024 * 2);
  unsigned short* xpb  = (unsigned short*)carve((size_t)2 * 96 * DI * 2);
  unsigned short* dtwb = (unsigned short*)carve((size_t)2 * DI * RK * 2);
  unsigned short* opb  = (unsigned short*)carve((size_t)DM * DI * 2);
  float*          A2   = (float*)carve((size_t)2 * DI * DS * 4);
  unsigned short* xz   = (unsigned short*)carve((size_t)MR * 8192 * 2);
  unsigned short* dlt  = (unsigned short*)carve((size_t)2 * MR * DI * 2);
  unsigned short* ub   = (unsigned short*)carve((size_t)2 * MR * DI * 2);
  float*          xdbl = (float*)carve((size_t)2 * MR * 96 * 4);
  unsigned short* dtb  = (unsigned short*)carve((size_t)2 * MR * RK * 2);
  float*          sdl  = (float*)carve((size_t)4 * NCH * DI * 4);
  unsigned short* hb   = (unsigned short*)carve((size_t)4 * NCH * DI * DS * 2);
  unsigned short* ygb  = (unsigned short*)carve((size_t)MR * DI * 2);

  // fused prep (+ zero-init of atomic targets xdbl/out)
  prep_all<<<(N_PREP / 4 + 255) / 256, 256, 0, stream>>>(
      x, mask, inpw, xpw_f, xpw_r, dtw_f, dtw_r, outpw, alog_f, alog_r,
      xb, Wcat, xpb, dtwb, opb, A2, xdbl, out);

  // G1: xz(2048 x 8192, bf16) = xb @ Wcat^T — 256^2 swizzled kernel
  gemm256<<<dim3(32, 8, 1), 512, 0, stream>>>(xb, Wcat, xz);

  // conv + silu -> ub
  conv_silu_k<<<dim3(128, 4, 1), 256, 0, stream>>>(xz, cw_f, cb_f, cw_r, cb_r, ub);
  // G2: x_dbl = ub @ x_proj^T, split-K=8, atomic accumulate
  {
    GArg g0{ub, xpb, xdbl, nullptr};
    GArg g1{ub + (size_t)MR * DI, xpb + 96 * DI, xdbl + (size_t)MR * 96, nullptr};
    gemm_bt<0, 0, 1, 2><<<dim3(1, 16, 16), 256, 0, stream>>>(
        g0, g1, MR, 96, 256, DI, DI, 96, 256);
  }
  cvt_dtb<<<(2 * MR * RK / 4 + 255) / 256, 256, 0, stream>>>(xdbl, dtb);
  // G3: delta = softplus(dt @ dt_w^T + dt_b) -> dlt (bf16, ldc=DI)
  {
    GArg g0{dtb, dtwb, dlt, dtbias_f};
    GArg g1{dtb + (size_t)MR * RK, dtwb + DI * RK, dlt + (size_t)MR * DI, dtbias_r};
    gemm_bt<1, 1, 0, 2><<<dim3(16, 16, 2), 256, 0, stream>>>(
        g0, g1, MR, DI, 64, RK, RK, DI, 0);
  }
  scanA<<<dim3(8, NCH, 4), 256, 0, stream>>>(dlt, ub, xdbl, A2, sdl, hb);
  scanB<<<dim3(512, 1, 1), 256, 0, stream>>>(sdl, A2, hb);
  scanC_f<<<dim3(8, NCH, 2), 256, 0, stream>>>(xz, ub, dlt, xdbl, A2, Dv_f, Dv_r, hb, ygb);
  // G4: out = ygb @ out_proj^T, split-K=4, atomic accumulate
  {
    GArg g0{ygb, opb, out, nullptr};
    gemm_bt<0, 0, 1, 1><<<dim3(8, 16, 4), 256, 0, stream>>>(
        g0, g0, MR, DM, 512, DI, DI, DM, 512);
  }
}

// Round 9
// 212.592 us; speedup vs baseline: 1.6650x; 1.1254x over previous
//
#include <hip/hip_runtime.h>

#define DM   1024
#define DI   2048
#define DS   16
#define RK   64
#define NBAT 2
#define LL   1024
#define MR   (NBAT*LL)   // 2048 rows (B*L)
#define NCH  128         // scan chunks
#define LC   (LL/NCH)    // 8 steps per chunk

typedef short  bf16x8 __attribute__((ext_vector_type(8)));
typedef short  short8v __attribute__((ext_vector_type(8)));
typedef float  f32x4  __attribute__((ext_vector_type(4)));

__device__ __forceinline__ float bf2f(unsigned short u) {
  union { unsigned int i; float f; } v; v.i = ((unsigned int)u) << 16; return v.f;
}
__device__ __forceinline__ unsigned short f2bf(float f) {
  union { float f; unsigned int i; } v; v.f = f;
  return (unsigned short)((v.i + 0x7FFFu + ((v.i >> 16) & 1u)) >> 16);  // RNE
}
__device__ __forceinline__ float fsilu(float z) {
  return z * __builtin_amdgcn_rcpf(1.f + __expf(-z));   // v_rcp_f32, ~1e-5 rel
}
// branch-free, stable softplus: max(x,0) + log(1+exp(-|x|)); HW exp/log only
__device__ __forceinline__ float fsoftplus(float x) {
  return fmaxf(x, 0.f) + __logf(1.f + __expf(-fabsf(x)));
}

// ---------------- fused prep / convert / zero-init (one launch, x4 vectorized) --------
#define N_XB    (MR*DM)
#define N_WH    (4096*1024)       // half of Wcat (source W elements)
#define N_XPB   (96*DI)
#define N_DTWB  (DI*RK)
#define N_OPB   (DM*DI)
#define N_A2    (DI*DS)
#define N_ZXD   (2*MR*96)
#define N_ZOUT  (MR*DM)
#define N_PREP  (N_XB + N_WH + 2*N_XPB + 2*N_DTWB + N_OPB + 2*N_A2 + N_ZXD + N_ZOUT)

__device__ __forceinline__ void cvt4(const float* src, unsigned short* dst) {
  const float4 v = *(const float4*)src;
  ushort4 o; o.x = f2bf(v.x); o.y = f2bf(v.y); o.z = f2bf(v.z); o.w = f2bf(v.w);
  *(ushort4*)dst = o;
}

__global__ void prep_all(const float* __restrict__ x, const float* __restrict__ mask,
                         const float* __restrict__ W,
                         const float* __restrict__ xpw_f, const float* __restrict__ xpw_r,
                         const float* __restrict__ dtw_f, const float* __restrict__ dtw_r,
                         const float* __restrict__ outpw,
                         const float* __restrict__ Af, const float* __restrict__ Ar,
                         unsigned short* __restrict__ xb, unsigned short* __restrict__ Wcat,
                         unsigned short* __restrict__ xpb, unsigned short* __restrict__ dtwb,
                         unsigned short* __restrict__ opb, float* __restrict__ A2,
                         float* __restrict__ xdbl_z, float* __restrict__ out_z)
{
  int i = (blockIdx.x * 256 + threadIdx.x) * 4;
  if (i < N_XB) {
    const float4 v = *(const float4*)&x[i];
    const float m = mask[i >> 10];
    ushort4 o; o.x = f2bf(v.x * m); o.y = f2bf(v.y * m); o.z = f2bf(v.z * m); o.w = f2bf(v.w * m);
    *(ushort4*)&xb[i] = o; return;
  }
  i -= N_XB;
  if (i < N_WH) {
    const int nrow = i >> 10, k = i & 1023;
    const float4 v = *(const float4*)&W[i];
    ushort4 o; o.x = f2bf(v.x); o.y = f2bf(v.y); o.z = f2bf(v.z); o.w = f2bf(v.w);
    *(ushort4*)&Wcat[i] = o;
    ushort4 rr; rr.x = f2bf(v.w); rr.y = f2bf(v.z); rr.z = f2bf(v.y); rr.w = f2bf(v.x);
    *(ushort4*)&Wcat[(size_t)(4096 + nrow) * 1024 + (1020 - k)] = rr;
    return;
  }
  i -= N_WH;
  if (i < N_XPB) { cvt4(&xpw_f[i], &xpb[i]); return; }
  i -= N_XPB;
  if (i < N_XPB) { cvt4(&xpw_r[i], &xpb[N_XPB + i]); return; }
  i -= N_XPB;
  if (i < N_DTWB) { cvt4(&dtw_f[i], &dtwb[i]); return; }
  i -= N_DTWB;
  if (i < N_DTWB) { cvt4(&dtw_r[i], &dtwb[N_DTWB + i]); return; }
  i -= N_DTWB;
  if (i < N_OPB) { cvt4(&outpw[i], &opb[i]); return; }
  i -= N_OPB;
  if (i < N_A2) {
    const float4 v = *(const float4*)&Af[i];
    float4 o; o.x = -__expf(v.x); o.y = -__expf(v.y); o.z = -__expf(v.z); o.w = -__expf(v.w);
    *(float4*)&A2[i] = o; return;
  }
  i -= N_A2;
  if (i < N_A2) {
    const float4 v = *(const float4*)&Ar[i];
    float4 o; o.x = -__expf(v.x); o.y = -__expf(v.y); o.z = -__expf(v.z); o.w = -__expf(v.w);
    *(float4*)&A2[N_A2 + i] = o; return;
  }
  i -= N_A2;
  if (i < N_ZXD) { *(float4*)&xdbl_z[i] = (float4){0.f, 0.f, 0.f, 0.f}; return; }
  i -= N_ZXD;
  if (i < N_ZOUT) { *(float4*)&out_z[i] = (float4){0.f, 0.f, 0.f, 0.f}; return; }
}

__global__ void cvt_dtb(const float* __restrict__ xdbl, unsigned short* __restrict__ dtb) {
  int i = (blockIdx.x * 256 + threadIdx.x) * 4;
  if (i < 2 * MR * RK) {
    const int dir = i / (MR * RK);
    const int j = i % (MR * RK);
    const int r = j >> 6, k = j & 63;
    cvt4(&xdbl[(size_t)dir * (MR * 96) + (size_t)r * 96 + k], &dtb[i]);
  }
}

// ---------------- G1: 256x256 tile, BK=64, swizzled-LDS bf16 MFMA GEMM ----------------
__global__ __launch_bounds__(512)
void gemm256(const unsigned short* __restrict__ A, const unsigned short* __restrict__ B,
             unsigned short* __restrict__ C)
{
  __shared__ __align__(16) unsigned short As[2][16384];   // 2 x 256x64
  __shared__ __align__(16) unsigned short Bs[2][16384];   // 2 x 256x64
  const int tid = threadIdx.x;
  const int wid = tid >> 6, lane = tid & 63;
  const int bm = blockIdx.y * 256;
  const int bn = blockIdx.x * 256;
  const int wm = wid >> 2, wn = wid & 3;
  const bool isA = wid < 4;
  const int cw = isA ? wid : wid - 4;

  const unsigned short* sp[8];
#pragma unroll
  for (int l = 0; l < 8; ++l) {
    const int row = cw * 64 + l * 8 + (lane >> 3);
    const int col = ((lane & 7) * 8) ^ (((row >> 1) & 7) << 3);    // pre-swizzled source
    sp[l] = (isA ? A + (size_t)(bm + row) * 1024
                 : B + (size_t)(bn + row) * 1024) + col;
  }
  const int dbase = cw * 4096 + lane * 8;

  f32x4 acc[8][4];
#pragma unroll
  for (int rf = 0; rf < 8; ++rf)
#pragma unroll
    for (int cf = 0; cf < 4; ++cf) acc[rf][cf] = (f32x4){0.f, 0.f, 0.f, 0.f};

#define STG256(b, kt)                                                                  \
  do {                                                                                 \
    unsigned short* dst = (isA ? &As[b][0] : &Bs[b][0]) + dbase;                       \
    const int kk = (kt) * 64;                                                          \
    _Pragma("unroll")                                                                  \
    for (int l = 0; l < 8; ++l)                                                        \
      __builtin_amdgcn_global_load_lds(                                                \
          (const __attribute__((address_space(1))) void*)(sp[l] + kk),                 \
          (__attribute__((address_space(3))) void*)(dst + l * 512), 16, 0, 0);         \
  } while (0)

  const int rsel = lane & 15;
  const int ko = (lane >> 4) * 8;
  const int swzl = ((rsel >> 1) & 7) << 3;

  STG256(0, 0);
  __syncthreads();
  for (int t = 0; t < 16; ++t) {
    const int buf = t & 1;
    if (t < 15) STG256(buf ^ 1, t + 1);
    const unsigned short* pa = &As[buf][0];
    const unsigned short* pb = &Bs[buf][0];
#pragma unroll
    for (int ks = 0; ks < 2; ++ks) {
      const int kl = (ks * 32 + ko) ^ swzl;
      bf16x8 bfv[4];
#pragma unroll
      for (int cf = 0; cf < 4; ++cf)
        bfv[cf] = *(const bf16x8*)&pb[(wn * 64 + cf * 16 + rsel) * 64 + kl];
#pragma unroll
      for (int rf = 0; rf < 8; ++rf) {
        const bf16x8 af = *(const bf16x8*)&pa[(wm * 128 + rf * 16 + rsel) * 64 + kl];
#pragma unroll
        for (int cf = 0; cf < 4; ++cf)
          acc[rf][cf] = __builtin_amdgcn_mfma_f32_16x16x32_bf16(af, bfv[cf], acc[rf][cf], 0, 0, 0);
      }
    }
    __syncthreads();
  }
#undef STG256

#pragma unroll
  for (int rf = 0; rf < 8; ++rf) {
    const int row0 = bm + wm * 128 + rf * 16 + (lane >> 4) * 4;
#pragma unroll
    for (int cf = 0; cf < 4; ++cf) {
      const int col = bn + wn * 64 + cf * 16 + rsel;
#pragma unroll
      for (int j = 0; j < 4; ++j)
        C[(size_t)(row0 + j) * 8192 + col] = f2bf(acc[rf][cf][j]);
    }
  }
}

// ---------------- bf16 MFMA GEMM, C = A(M,K) * B(N,K)^T, 128x128 tile ----------------
struct GArg { const unsigned short* A; const unsigned short* B; void* C; const float* bias; };

template<int EPI, int OUT, int ATOMIC, int NDIR>
__global__ __launch_bounds__(256)
void gemm_bt(GArg g0, GArg g1, int M, int N, int K, int lda, int ldb, int ldc, int koff)
{
  __shared__ __align__(16) unsigned short As[2][128 * 32];
  __shared__ __align__(16) unsigned short Bs[2][128 * 32];
  const GArg ga = (NDIR == 2 && (blockIdx.z & 1)) ? g1 : g0;
  const int kc = (NDIR == 2) ? ((int)blockIdx.z >> 1) : (int)blockIdx.z;
  const unsigned short* Ap = ga.A + (size_t)kc * koff;
  const unsigned short* Bp = ga.B + (size_t)kc * koff;

  const int tid  = threadIdx.x;
  const int wave = tid >> 6;
  const int lane = tid & 63;
  const int bm = blockIdx.y * 128;
  const int bn = blockIdx.x * 128;
  const int wr = wave >> 1, wc = wave & 1;

  f32x4 acc[4][4];
#pragma unroll
  for (int m = 0; m < 4; ++m)
#pragma unroll
    for (int n = 0; n < 4; ++n) acc[m][n] = (f32x4){0.f, 0.f, 0.f, 0.f};

  const int rsel = lane & 15;
  const int ksel = (lane >> 4) * 8;
  const int NT = K >> 5;

  const int chunk0 = wave * 2;
  const int flat0  = chunk0 * 512 + lane * 8;
  const int row0s  = flat0 >> 5, col0s = flat0 & 31;
  const int flat1  = (chunk0 + 1) * 512 + lane * 8;
  const int row1s  = flat1 >> 5, col1s = flat1 & 31;
  int grA0 = bm + row0s; if (grA0 > M - 1) grA0 = M - 1;
  int grA1 = bm + row1s; if (grA1 > M - 1) grA1 = M - 1;
  int gcB0 = bn + row0s; if (gcB0 > N - 1) gcB0 = N - 1;
  int gcB1 = bn + row1s; if (gcB1 > N - 1) gcB1 = N - 1;

#define STAGE(buf, kt)                                                                       \
  do {                                                                                       \
    const int k0_ = (kt) << 5;                                                               \
    __builtin_amdgcn_global_load_lds(                                                        \
        (const __attribute__((address_space(1))) void*)(Ap + (size_t)grA0 * lda + k0_ + col0s), \
        (__attribute__((address_space(3))) void*)(&As[buf][chunk0 * 512]), 16, 0, 0);        \
    __builtin_amdgcn_global_load_lds(                                                        \
        (const __attribute__((address_space(1))) void*)(Ap + (size_t)grA1 * lda + k0_ + col1s), \
        (__attribute__((address_space(3))) void*)(&As[buf][(chunk0 + 1) * 512]), 16, 0, 0);  \
    __builtin_amdgcn_global_load_lds(                                                        \
        (const __attribute__((address_space(1))) void*)(Bp + (size_t)gcB0 * ldb + k0_ + col0s), \
        (__attribute__((address_space(3))) void*)(&Bs[buf][chunk0 * 512]), 16, 0, 0);        \
    __builtin_amdgcn_global_load_lds(                                                        \
        (const __attribute__((address_space(1))) void*)(Bp + (size_t)gcB1 * ldb + k0_ + col1s), \
        (__attribute__((address_space(3))) void*)(&Bs[buf][(chunk0 + 1) * 512]), 16, 0, 0);  \
  } while (0)

  STAGE(0, 0);
  __syncthreads();
  int cur = 0;
  for (int kt = 0; kt < NT; ++kt) {
    if (kt + 1 < NT) STAGE(cur ^ 1, kt + 1);
    bf16x8 af[4], bfv[4];
#pragma unroll
    for (int m = 0; m < 4; ++m)
      af[m] = *(const bf16x8*)&As[cur][(wr * 64 + m * 16 + rsel) * 32 + ksel];
#pragma unroll
    for (int n = 0; n < 4; ++n)
      bfv[n] = *(const bf16x8*)&Bs[cur][(wc * 64 + n * 16 + rsel) * 32 + ksel];
#pragma unroll
    for (int m = 0; m < 4; ++m)
#pragma unroll
      for (int n = 0; n < 4; ++n)
        acc[m][n] = __builtin_amdgcn_mfma_f32_16x16x32_bf16(af[m], bfv[n], acc[m][n], 0, 0, 0);
    if (kt + 1 < NT) {
      __syncthreads();
      cur ^= 1;
    }
  }
#undef STAGE

#pragma unroll
  for (int m = 0; m < 4; ++m) {
    const int rowb = bm + wr * 64 + m * 16 + (lane >> 4) * 4;
#pragma unroll
    for (int n = 0; n < 4; ++n) {
      const int col = bn + wc * 64 + n * 16 + rsel;
      if (col < N) {
#pragma unroll
        for (int r = 0; r < 4; ++r) {
          const int rr = rowb + r;
          if (rr < M) {
            float v = acc[m][n][r];
            if constexpr (EPI == 1) {
              v = fsoftplus(v + ga.bias[col]);   // branch-free HW softplus
            }
            if constexpr (ATOMIC) {
              atomicAdd((float*)ga.C + (size_t)rr * ldc + col, v);
            } else if constexpr (OUT == 1) {
              ((unsigned short*)ga.C)[(size_t)rr * ldc + col] = f2bf(v);
            } else {
              ((float*)ga.C)[(size_t)rr * ldc + col] = v;
            }
          }
        }
      }
    }
  }
}

// ---------------- depthwise causal conv(4) + silu -> bf16 (x8 d-vectorized) -----------
__global__ __launch_bounds__(256)
void conv_silu_k(const unsigned short* __restrict__ xz,
                 const float* __restrict__ cw_f, const float* __restrict__ cb_f,
                 const float* __restrict__ cw_r, const float* __restrict__ cb_r,
                 unsigned short* __restrict__ ub)
{
  const int tid = threadIdx.x;
  const int d0  = tid * 8;
  const int l0  = blockIdx.x * 8;
  const int dir = blockIdx.y >> 1, b = blockIdx.y & 1;
  const float* cw = dir ? cw_r : cw_f;
  const float* cb = dir ? cb_r : cb_f;
  float w0[8], w1[8], w2[8], w3[8], bs[8];
#pragma unroll
  for (int j = 0; j < 8; ++j) {
    const float4 wv = *(const float4*)&cw[(d0 + j) * 4];
    w0[j] = wv.x; w1[j] = wv.y; w2[j] = wv.z; w3[j] = wv.w;
    bs[j] = cb[d0 + j];
  }
  const unsigned short* uin = xz + (size_t)dir * 4096 + d0;
  unsigned short* uo = ub + (size_t)dir * ((size_t)MR * DI) + d0;
  const size_t rbase = (size_t)b * LL;
  float xa[8], xbv[8], xc[8];
#pragma unroll
  for (int j = 0; j < 8; ++j) { xa[j] = 0.f; xbv[j] = 0.f; xc[j] = 0.f; }
  if (l0 >= 3) { const short8v v = *(const short8v*)&uin[(rbase + l0 - 3) * 8192];
#pragma unroll
    for (int j = 0; j < 8; ++j) xa[j] = bf2f((unsigned short)v[j]); }
  if (l0 >= 2) { const short8v v = *(const short8v*)&uin[(rbase + l0 - 2) * 8192];
#pragma unroll
    for (int j = 0; j < 8; ++j) xbv[j] = bf2f((unsigned short)v[j]); }
  if (l0 >= 1) { const short8v v = *(const short8v*)&uin[(rbase + l0 - 1) * 8192];
#pragma unroll
    for (int j = 0; j < 8; ++j) xc[j] = bf2f((unsigned short)v[j]); }
  for (int l = l0; l < l0 + 8; ++l) {
    const short8v v = *(const short8v*)&uin[(rbase + l) * 8192];
    short8v ov;
#pragma unroll
    for (int j = 0; j < 8; ++j) {
      const float x3 = bf2f((unsigned short)v[j]);
      float o = w0[j] * xa[j] + w1[j] * xbv[j] + w2[j] * xc[j] + w3[j] * x3 + bs[j];
      ov[j] = (short)f2bf(fsilu(o));
      xa[j] = xbv[j]; xbv[j] = xc[j]; xc[j] = x3;
    }
    *(short8v*)&uo[(rbase + l) * DI] = ov;
  }
}

// ---------------- chunked selective scan (bf16 delta/state, f32 sumdl) ----------------
__global__ __launch_bounds__(256)
void scanA(const unsigned short* __restrict__ dlt, const unsigned short* __restrict__ ub,
           const float* __restrict__ xdbl, const float* __restrict__ A2,
           float* __restrict__ sdl, unsigned short* __restrict__ hb)
{
  const int tid = threadIdx.x;
  const int d = blockIdx.x * 256 + tid;
  const int c = blockIdx.y;
  const int dir = blockIdx.z >> 1, b = blockIdx.z & 1;
  __shared__ float sB[LC * DS];
  const float* xd = xdbl + (size_t)dir * (MR * 96);
  for (int i = tid; i < LC * DS; i += 256) {
    int t = i >> 4, s = i & 15;
    sB[i] = xd[(size_t)(b * LL + c * LC + t) * 96 + 64 + s];
  }
  __syncthreads();
  const unsigned short* dl_p = dlt + (size_t)dir * ((size_t)MR * DI) + d;
  const unsigned short* uu = ub + (size_t)dir * ((size_t)MR * DI) + d;
  float a2[DS];
#pragma unroll
  for (int s = 0; s < DS; ++s) a2[s] = A2[((size_t)dir * DI + d) * DS + s];
  float h[DS];
#pragma unroll
  for (int s = 0; s < DS; ++s) h[s] = 0.f;
  float sumdl = 0.f;
  for (int t = 0; t < LC; ++t) {
    size_t r = (size_t)b * LL + c * LC + t;
    float dl = bf2f(dl_p[r * DI]);
    float du = dl * bf2f(uu[r * DI]);
    sumdl += dl;
#pragma unroll
    for (int s = 0; s < DS; ++s) {
      float e = __expf(dl * a2[s]);
      h[s] = e * h[s] + du * sB[t * DS + s];
    }
  }
  const size_t base = ((((size_t)(dir * 2 + b)) * NCH + c) * DI + d) * DS;
#pragma unroll
  for (int s = 0; s < DS; ++s) hb[base + s] = f2bf(h[s]);
  sdl[(((size_t)(dir * 2 + b)) * NCH + c) * DI + d] = sumdl;
}

__global__ __launch_bounds__(256)
void scanB(const float* __restrict__ sdl, const float* __restrict__ A2,
           unsigned short* __restrict__ hb)
{
  const int i = blockIdx.x * 256 + threadIdx.x;
  const int db = i >> 15;
  const int ds_ = i & 32767;
  const int d = ds_ >> 4, s = i & 15;
  const int dir = db >> 1;
  const float a2 = A2[((size_t)dir * DI + d) * DS + s];
  float hrun = 0.f;
  for (int c = 0; c < NCH; ++c) {
    const size_t off = (((size_t)db * NCH + c) << 15) + ds_;
    const float h0 = bf2f(hb[off]);
    const float pa = __expf(a2 * sdl[((size_t)db * NCH + c) * DI + d]);
    hb[off] = f2bf(hrun);
    hrun = pa * hrun + h0;
  }
}

// phase C: dirs split across wave halves of a 512-thread block.
// tid<256 -> fwd, tid>=256 -> rev for the same (c,b,d). Rev stashes its 8 gated
// partials in LDS; one barrier; fwd adds + stores bf16.
__global__ __launch_bounds__(512)
void scanC_f(const unsigned short* __restrict__ xz, const unsigned short* __restrict__ ub,
             const unsigned short* __restrict__ dlt, const float* __restrict__ xdbl,
             const float* __restrict__ A2, const float* __restrict__ Dv_f,
             const float* __restrict__ Dv_r, const unsigned short* __restrict__ hb,
             unsigned short* __restrict__ ygb)
{
  const int tid = threadIdx.x;
  const int dir = tid >> 8;          // 0 fwd, 1 rev
  const int td  = tid & 255;
  const int d = blockIdx.x * 256 + td;
  const int c = blockIdx.y;
  const int b = blockIdx.z;
  __shared__ float sB[2][LC * DS], sC[2][LC * DS];
  __shared__ float sY[LC][256];
  for (int i = tid; i < 2 * LC * DS; i += 512) {
    const int di = i >> 7;           // dir of this element
    const int j = i & 127;
    const int t = j >> 4, s = j & 15;
    const size_t ro = (size_t)di * (MR * 96) + (size_t)(b * LL + c * LC + t) * 96;
    sB[di][j] = xdbl[ro + 64 + s];
    sC[di][j] = xdbl[ro + 80 + s];
  }
  __syncthreads();
  float a2[DS], h[DS];
  const size_t base = ((((size_t)(dir * 2 + b)) * NCH + c) * DI + d) * DS;
#pragma unroll
  for (int s = 0; s < DS; ++s) {
    a2[s] = A2[((size_t)dir * DI + d) * DS + s];
    h[s] = bf2f(hb[base + s]);
  }
  const float Dd = dir ? Dv_r[d] : Dv_f[d];
  const unsigned short* dl_p = dlt + (size_t)dir * ((size_t)MR * DI) + d;
  const unsigned short* uu  = ub + (size_t)dir * ((size_t)MR * DI) + d;
  float yg[LC];
#pragma unroll
  for (int t = 0; t < LC; ++t) {
    const size_t r = (size_t)b * LL + c * LC + t;
    const float dl = bf2f(dl_p[r * DI]);
    const float uf = bf2f(uu[r * DI]);
    const float du = dl * uf;
    float y = 0.f;
#pragma unroll
    for (int s = 0; s < DS; ++s) {
      const float e = __expf(dl * a2[s]);
      h[s] = e * h[s] + du * sB[dir][t * DS + s];
      y += h[s] * sC[dir][t * DS + s];
    }
    y += Dd * uf;
    const float z = bf2f(xz[r * 8192 + 2048 + dir * 4096 + d]);
    yg[t] = y * fsilu(z);
  }
  if (dir == 1) {
#pragma unroll
    for (int t = 0; t < LC; ++t) sY[t][td] = yg[t];
  }
  __syncthreads();
  if (dir == 0) {
#pragma unroll
    for (int t = 0; t < LC; ++t) {
      const size_t r = (size_t)b * LL + c * LC + t;
      ygb[r * DI + d] = f2bf(yg[t] + sY[t][td]);
    }
  }
}

// ---------------- host launch ----------------

extern "C" void kernel_launch(void* const* d_in, const int* in_sizes, int n_in,
                              void* d_out, int out_size, void* d_ws, size_t ws_size,
                              hipStream_t stream)
{
  (void)in_sizes; (void)n_in; (void)out_size; (void)ws_size;
  const float* x      = (const float*)d_in[0];
  const float* mask   = (const float*)d_in[1];
  const float* inpw   = (const float*)d_in[2];
  const float* outpw  = (const float*)d_in[3];
  const float* cw_f   = (const float*)d_in[4];
  const float* cb_f   = (const float*)d_in[5];
  const float* xpw_f  = (const float*)d_in[6];
  const float* dtw_f  = (const float*)d_in[7];
  const float* dtbias_f = (const float*)d_in[8];
  const float* alog_f = (const float*)d_in[9];
  const float* Dv_f   = (const float*)d_in[10];
  const float* cw_r   = (const float*)d_in[11];
  const float* cb_r   = (const float*)d_in[12];
  const float* xpw_r  = (const float*)d_in[13];
  const float* dtw_r  = (const float*)d_in[14];
  const float* dtbias_r = (const float*)d_in[15];
  const float* alog_r = (const float*)d_in[16];
  const float* Dv_r   = (const float*)d_in[17];
  float* out = (float*)d_out;

  char* p = (char*)d_ws;
  auto carve = [&](size_t bytes) -> char* {
    char* q = p; p += (bytes + 255) & ~(size_t)255; return q;
  };
  unsigned short* xb   = (unsigned short*)carve((size_t)MR * DM * 2);
  unsigned short* Wcat = (unsigned short*)carve((size_t)8192 * 1024 * 2);
  unsigned short* xpb  = (unsigned short*)carve((size_t)2 * 96 * DI * 2);
  unsigned short* dtwb = (unsigned short*)carve((size_t)2 * DI * RK * 2);
  unsigned short* opb  = (unsigned short*)carve((size_t)DM * DI * 2);
  float*          A2   = (float*)carve((size_t)2 * DI * DS * 4);
  unsigned short* xz   = (unsigned short*)carve((size_t)MR * 8192 * 2);
  unsigned short* dlt  = (unsigned short*)carve((size_t)2 * MR * DI * 2);
  unsigned short* ub   = (unsigned short*)carve((size_t)2 * MR * DI * 2);
  float*          xdbl = (float*)carve((size_t)2 * MR * 96 * 4);
  unsigned short* dtb  = (unsigned short*)carve((size_t)2 * MR * RK * 2);
  float*          sdl  = (float*)carve((size_t)4 * NCH * DI * 4);
  unsigned short* hb   = (unsigned short*)carve((size_t)4 * NCH * DI * DS * 2);
  unsigned short* ygb  = (unsigned short*)carve((size_t)MR * DI * 2);

  // fused prep (+ zero-init of atomic targets xdbl/out)
  prep_all<<<(N_PREP / 4 + 255) / 256, 256, 0, stream>>>(
      x, mask, inpw, xpw_f, xpw_r, dtw_f, dtw_r, outpw, alog_f, alog_r,
      xb, Wcat, xpb, dtwb, opb, A2, xdbl, out);

  // G1: xz(2048 x 8192, bf16) = xb @ Wcat^T — 256^2 swizzled kernel
  gemm256<<<dim3(32, 8, 1), 512, 0, stream>>>(xb, Wcat, xz);

  // conv + silu -> ub
  conv_silu_k<<<dim3(128, 4, 1), 256, 0, stream>>>(xz, cw_f, cb_f, cw_r, cb_r, ub);
  // G2: x_dbl = ub @ x_proj^T, split-K=8, atomic accumulate
  {
    GArg g0{ub, xpb, xdbl, nullptr};
    GArg g1{ub + (size_t)MR * DI, xpb + 96 * DI, xdbl + (size_t)MR * 96, nullptr};
    gemm_bt<0, 0, 1, 2><<<dim3(1, 16, 16), 256, 0, stream>>>(
        g0, g1, MR, 96, 256, DI, DI, 96, 256);
  }
  cvt_dtb<<<(2 * MR * RK / 4 + 255) / 256, 256, 0, stream>>>(xdbl, dtb);
  // G3: delta = softplus(dt @ dt_w^T + dt_b) -> dlt (bf16, ldc=DI)
  {
    GArg g0{dtb, dtwb, dlt, dtbias_f};
    GArg g1{dtb + (size_t)MR * RK, dtwb + DI * RK, dlt + (size_t)MR * DI, dtbias_r};
    gemm_bt<1, 1, 0, 2><<<dim3(16, 16, 2), 256, 0, stream>>>(
        g0, g1, MR, DI, 64, RK, RK, DI, 0);
  }
  scanA<<<dim3(8, NCH, 4), 256, 0, stream>>>(dlt, ub, xdbl, A2, sdl, hb);
  scanB<<<dim3(512, 1, 1), 256, 0, stream>>>(sdl, A2, hb);
  scanC_f<<<dim3(8, NCH, 2), 512, 0, stream>>>(xz, ub, dlt, xdbl, A2, Dv_f, Dv_r, hb, ygb);
  // G4: out = ygb @ out_proj^T, split-K=4, atomic accumulate
  {
    GArg g0{ygb, opb, out, nullptr};
    gemm_bt<0, 0, 1, 1><<<dim3(8, 16, 4), 256, 0, stream>>>(
        g0, g0, MR, DM, 512, DI, DI, DM, 512);
  }
}

// Round 10
// 199.179 us; speedup vs baseline: 1.7772x; 1.0673x over previous
//
#include <hip/hip_runtime.h>

#define DM   1024
#define DI   2048
#define DS   16
#define RK   64
#define NBAT 2
#define LL   1024
#define MR   (NBAT*LL)   // 2048 rows (B*L)
#define NCH  128         // scan chunks
#define LC   (LL/NCH)    // 8 steps per chunk

typedef short  bf16x8 __attribute__((ext_vector_type(8)));
typedef short  short8v __attribute__((ext_vector_type(8)));
typedef float  f32x4  __attribute__((ext_vector_type(4)));

__device__ __forceinline__ float bf2f(unsigned short u) {
  union { unsigned int i; float f; } v; v.i = ((unsigned int)u) << 16; return v.f;
}
__device__ __forceinline__ unsigned short f2bf(float f) {
  union { float f; unsigned int i; } v; v.f = f;
  return (unsigned short)((v.i + 0x7FFFu + ((v.i >> 16) & 1u)) >> 16);  // RNE
}
__device__ __forceinline__ float fsilu(float z) {
  return z * __builtin_amdgcn_rcpf(1.f + __expf(-z));   // v_rcp_f32, ~1e-5 rel
}
// branch-free, stable softplus: max(x,0) + log(1+exp(-|x|)); HW exp/log only
__device__ __forceinline__ float fsoftplus(float x) {
  return fmaxf(x, 0.f) + __logf(1.f + __expf(-fabsf(x)));
}

// ---------------- fused prep / convert (one launch, x4 vectorized) --------
#define N_XB    (MR*DM)
#define N_WH    (4096*1024)       // half of Wcat (source W elements)
#define N_XPB   (96*DI)
#define N_DTWB  (DI*RK)
#define N_OPB   (DM*DI)
#define N_A2    (DI*DS)
#define N_PREP  (N_XB + N_WH + 2*N_XPB + 2*N_DTWB + N_OPB + 2*N_A2)

__device__ __forceinline__ void cvt4(const float* src, unsigned short* dst) {
  const float4 v = *(const float4*)src;
  ushort4 o; o.x = f2bf(v.x); o.y = f2bf(v.y); o.z = f2bf(v.z); o.w = f2bf(v.w);
  *(ushort4*)dst = o;
}

__global__ void prep_all(const float* __restrict__ x, const float* __restrict__ mask,
                         const float* __restrict__ W,
                         const float* __restrict__ xpw_f, const float* __restrict__ xpw_r,
                         const float* __restrict__ dtw_f, const float* __restrict__ dtw_r,
                         const float* __restrict__ outpw,
                         const float* __restrict__ Af, const float* __restrict__ Ar,
                         unsigned short* __restrict__ xb, unsigned short* __restrict__ Wcat,
                         unsigned short* __restrict__ xpb, unsigned short* __restrict__ dtwb,
                         unsigned short* __restrict__ opb, float* __restrict__ A2)
{
  int i = (blockIdx.x * 256 + threadIdx.x) * 4;
  if (i < N_XB) {
    const float4 v = *(const float4*)&x[i];
    const float m = mask[i >> 10];
    ushort4 o; o.x = f2bf(v.x * m); o.y = f2bf(v.y * m); o.z = f2bf(v.z * m); o.w = f2bf(v.w * m);
    *(ushort4*)&xb[i] = o; return;
  }
  i -= N_XB;
  if (i < N_WH) {
    const int nrow = i >> 10, k = i & 1023;
    const float4 v = *(const float4*)&W[i];
    ushort4 o; o.x = f2bf(v.x); o.y = f2bf(v.y); o.z = f2bf(v.z); o.w = f2bf(v.w);
    *(ushort4*)&Wcat[i] = o;
    ushort4 rr; rr.x = f2bf(v.w); rr.y = f2bf(v.z); rr.z = f2bf(v.y); rr.w = f2bf(v.x);
    *(ushort4*)&Wcat[(size_t)(4096 + nrow) * 1024 + (1020 - k)] = rr;
    return;
  }
  i -= N_WH;
  if (i < N_XPB) { cvt4(&xpw_f[i], &xpb[i]); return; }
  i -= N_XPB;
  if (i < N_XPB) { cvt4(&xpw_r[i], &xpb[N_XPB + i]); return; }
  i -= N_XPB;
  if (i < N_DTWB) { cvt4(&dtw_f[i], &dtwb[i]); return; }
  i -= N_DTWB;
  if (i < N_DTWB) { cvt4(&dtw_r[i], &dtwb[N_DTWB + i]); return; }
  i -= N_DTWB;
  if (i < N_OPB) { cvt4(&outpw[i], &opb[i]); return; }
  i -= N_OPB;
  if (i < N_A2) {
    const float4 v = *(const float4*)&Af[i];
    float4 o; o.x = -__expf(v.x); o.y = -__expf(v.y); o.z = -__expf(v.z); o.w = -__expf(v.w);
    *(float4*)&A2[i] = o; return;
  }
  i -= N_A2;
  if (i < N_A2) {
    const float4 v = *(const float4*)&Ar[i];
    float4 o; o.x = -__expf(v.x); o.y = -__expf(v.y); o.z = -__expf(v.z); o.w = -__expf(v.w);
    *(float4*)&A2[N_A2 + i] = o; return;
  }
}

// ---------------- G1: 256x256 tile, BK=64, swizzled-LDS bf16 MFMA GEMM ----------------
__global__ __launch_bounds__(512)
void gemm256(const unsigned short* __restrict__ A, const unsigned short* __restrict__ B,
             unsigned short* __restrict__ C)
{
  __shared__ __align__(16) unsigned short As[2][16384];   // 2 x 256x64
  __shared__ __align__(16) unsigned short Bs[2][16384];   // 2 x 256x64
  const int tid = threadIdx.x;
  const int wid = tid >> 6, lane = tid & 63;
  const int bm = blockIdx.y * 256;
  const int bn = blockIdx.x * 256;
  const int wm = wid >> 2, wn = wid & 3;
  const bool isA = wid < 4;
  const int cw = isA ? wid : wid - 4;

  const unsigned short* sp[8];
#pragma unroll
  for (int l = 0; l < 8; ++l) {
    const int row = cw * 64 + l * 8 + (lane >> 3);
    const int col = ((lane & 7) * 8) ^ (((row >> 1) & 7) << 3);    // pre-swizzled source
    sp[l] = (isA ? A + (size_t)(bm + row) * 1024
                 : B + (size_t)(bn + row) * 1024) + col;
  }
  const int dbase = cw * 4096 + lane * 8;

  f32x4 acc[8][4];
#pragma unroll
  for (int rf = 0; rf < 8; ++rf)
#pragma unroll
    for (int cf = 0; cf < 4; ++cf) acc[rf][cf] = (f32x4){0.f, 0.f, 0.f, 0.f};

#define STG256(b, kt)                                                                  \
  do {                                                                                 \
    unsigned short* dst = (isA ? &As[b][0] : &Bs[b][0]) + dbase;                       \
    const int kk = (kt) * 64;                                                          \
    _Pragma("unroll")                                                                  \
    for (int l = 0; l < 8; ++l)                                                        \
      __builtin_amdgcn_global_load_lds(                                                \
          (const __attribute__((address_space(1))) void*)(sp[l] + kk),                 \
          (__attribute__((address_space(3))) void*)(dst + l * 512), 16, 0, 0);         \
  } while (0)

  const int rsel = lane & 15;
  const int ko = (lane >> 4) * 8;
  const int swzl = ((rsel >> 1) & 7) << 3;

  STG256(0, 0);
  __syncthreads();
  for (int t = 0; t < 16; ++t) {
    const int buf = t & 1;
    if (t < 15) STG256(buf ^ 1, t + 1);
    const unsigned short* pa = &As[buf][0];
    const unsigned short* pb = &Bs[buf][0];
#pragma unroll
    for (int ks = 0; ks < 2; ++ks) {
      const int kl = (ks * 32 + ko) ^ swzl;
      bf16x8 bfv[4];
#pragma unroll
      for (int cf = 0; cf < 4; ++cf)
        bfv[cf] = *(const bf16x8*)&pb[(wn * 64 + cf * 16 + rsel) * 64 + kl];
#pragma unroll
      for (int rf = 0; rf < 8; ++rf) {
        const bf16x8 af = *(const bf16x8*)&pa[(wm * 128 + rf * 16 + rsel) * 64 + kl];
#pragma unroll
        for (int cf = 0; cf < 4; ++cf)
          acc[rf][cf] = __builtin_amdgcn_mfma_f32_16x16x32_bf16(af, bfv[cf], acc[rf][cf], 0, 0, 0);
      }
    }
    __syncthreads();
  }
#undef STG256

#pragma unroll
  for (int rf = 0; rf < 8; ++rf) {
    const int row0 = bm + wm * 128 + rf * 16 + (lane >> 4) * 4;
#pragma unroll
    for (int cf = 0; cf < 4; ++cf) {
      const int col = bn + wn * 64 + cf * 16 + rsel;
#pragma unroll
      for (int j = 0; j < 4; ++j)
        C[(size_t)(row0 + j) * 8192 + col] = f2bf(acc[rf][cf][j]);
    }
  }
}

// ---------------- bf16 MFMA GEMM, C = A(M,K) * B(N,K)^T, 128x128 tile ----------------
// split-K writes NON-ATOMIC per-split partials: C element index = kc*coff + rr*ldc + col
struct GArg { const unsigned short* A; const unsigned short* B; void* C; const float* bias; };

template<int EPI, int OUT, int NDIR>
__global__ __launch_bounds__(256)
void gemm_bt(GArg g0, GArg g1, int M, int N, int K, int lda, int ldb, int ldc,
             int koff, int coff)
{
  __shared__ __align__(16) unsigned short As[2][128 * 32];
  __shared__ __align__(16) unsigned short Bs[2][128 * 32];
  const GArg ga = (NDIR == 2 && (blockIdx.z & 1)) ? g1 : g0;
  const int kc = (NDIR == 2) ? ((int)blockIdx.z >> 1) : (int)blockIdx.z;
  const unsigned short* Ap = ga.A + (size_t)kc * koff;
  const unsigned short* Bp = ga.B + (size_t)kc * koff;
  const size_t cbase = (size_t)kc * coff;

  const int tid  = threadIdx.x;
  const int wave = tid >> 6;
  const int lane = tid & 63;
  const int bm = blockIdx.y * 128;
  const int bn = blockIdx.x * 128;
  const int wr = wave >> 1, wc = wave & 1;

  f32x4 acc[4][4];
#pragma unroll
  for (int m = 0; m < 4; ++m)
#pragma unroll
    for (int n = 0; n < 4; ++n) acc[m][n] = (f32x4){0.f, 0.f, 0.f, 0.f};

  const int rsel = lane & 15;
  const int ksel = (lane >> 4) * 8;
  const int NT = K >> 5;

  const int chunk0 = wave * 2;
  const int flat0  = chunk0 * 512 + lane * 8;
  const int row0s  = flat0 >> 5, col0s = flat0 & 31;
  const int flat1  = (chunk0 + 1) * 512 + lane * 8;
  const int row1s  = flat1 >> 5, col1s = flat1 & 31;
  int grA0 = bm + row0s; if (grA0 > M - 1) grA0 = M - 1;
  int grA1 = bm + row1s; if (grA1 > M - 1) grA1 = M - 1;
  int gcB0 = bn + row0s; if (gcB0 > N - 1) gcB0 = N - 1;
  int gcB1 = bn + row1s; if (gcB1 > N - 1) gcB1 = N - 1;

#define STAGE(buf, kt)                                                                       \
  do {                                                                                       \
    const int k0_ = (kt) << 5;                                                               \
    __builtin_amdgcn_global_load_lds(                                                        \
        (const __attribute__((address_space(1))) void*)(Ap + (size_t)grA0 * lda + k0_ + col0s), \
        (__attribute__((address_space(3))) void*)(&As[buf][chunk0 * 512]), 16, 0, 0);        \
    __builtin_amdgcn_global_load_lds(                                                        \
        (const __attribute__((address_space(1))) void*)(Ap + (size_t)grA1 * lda + k0_ + col1s), \
        (__attribute__((address_space(3))) void*)(&As[buf][(chunk0 + 1) * 512]), 16, 0, 0);  \
    __builtin_amdgcn_global_load_lds(                                                        \
        (const __attribute__((address_space(1))) void*)(Bp + (size_t)gcB0 * ldb + k0_ + col0s), \
        (__attribute__((address_space(3))) void*)(&Bs[buf][chunk0 * 512]), 16, 0, 0);        \
    __builtin_amdgcn_global_load_lds(                                                        \
        (const __attribute__((address_space(1))) void*)(Bp + (size_t)gcB1 * ldb + k0_ + col1s), \
        (__attribute__((address_space(3))) void*)(&Bs[buf][(chunk0 + 1) * 512]), 16, 0, 0);  \
  } while (0)

  STAGE(0, 0);
  __syncthreads();
  int cur = 0;
  for (int kt = 0; kt < NT; ++kt) {
    if (kt + 1 < NT) STAGE(cur ^ 1, kt + 1);
    bf16x8 af[4], bfv[4];
#pragma unroll
    for (int m = 0; m < 4; ++m)
      af[m] = *(const bf16x8*)&As[cur][(wr * 64 + m * 16 + rsel) * 32 + ksel];
#pragma unroll
    for (int n = 0; n < 4; ++n)
      bfv[n] = *(const bf16x8*)&Bs[cur][(wc * 64 + n * 16 + rsel) * 32 + ksel];
#pragma unroll
    for (int m = 0; m < 4; ++m)
#pragma unroll
      for (int n = 0; n < 4; ++n)
        acc[m][n] = __builtin_amdgcn_mfma_f32_16x16x32_bf16(af[m], bfv[n], acc[m][n], 0, 0, 0);
    if (kt + 1 < NT) {
      __syncthreads();
      cur ^= 1;
    }
  }
#undef STAGE

#pragma unroll
  for (int m = 0; m < 4; ++m) {
    const int rowb = bm + wr * 64 + m * 16 + (lane >> 4) * 4;
#pragma unroll
    for (int n = 0; n < 4; ++n) {
      const int col = bn + wc * 64 + n * 16 + rsel;
      if (col < N) {
#pragma unroll
        for (int r = 0; r < 4; ++r) {
          const int rr = rowb + r;
          if (rr < M) {
            float v = acc[m][n][r];
            if constexpr (EPI == 1) {
              v = fsoftplus(v + ga.bias[col]);   // branch-free HW softplus
            }
            if constexpr (OUT == 1) {
              ((unsigned short*)ga.C)[cbase + (size_t)rr * ldc + col] = f2bf(v);
            } else {
              ((float*)ga.C)[cbase + (size_t)rr * ldc + col] = v;
            }
          }
        }
      }
    }
  }
}

// reduce 8 G2 partials -> xdbl f32, and emit dtb bf16 (cols<64) in the same pass
__global__ void reduce_xdbl(const float* __restrict__ pxd, float* __restrict__ xdbl,
                            unsigned short* __restrict__ dtb)
{
  const int i = blockIdx.x * 256 + threadIdx.x;   // 0..2*MR*96-1
  if (i >= 2 * MR * 96) return;
  float s = 0.f;
#pragma unroll
  for (int k = 0; k < 8; ++k) s += pxd[(size_t)k * (2 * MR * 96) + i];
  xdbl[i] = s;
  const int k = i % 96;
  if (k < 64) {
    const int dr = i / 96;        // = dir*MR + r
    dtb[(size_t)dr * 64 + k] = f2bf(s);
  }
}

// reduce 2 G4 partials -> out f32 (float4)
__global__ void reduce_out(const float* __restrict__ pout, float* __restrict__ out)
{
  const int i = (blockIdx.x * 256 + threadIdx.x) * 4;
  if (i < MR * DM) {
    const float4 a = *(const float4*)&pout[i];
    const float4 b = *(const float4*)&pout[(size_t)MR * DM + i];
    float4 o; o.x = a.x + b.x; o.y = a.y + b.y; o.z = a.z + b.z; o.w = a.w + b.w;
    *(float4*)&out[i] = o;
  }
}

// ---------------- depthwise causal conv(4) + silu -> bf16 (x8 d-vectorized) -----------
__global__ __launch_bounds__(256)
void conv_silu_k(const unsigned short* __restrict__ xz,
                 const float* __restrict__ cw_f, const float* __restrict__ cb_f,
                 const float* __restrict__ cw_r, const float* __restrict__ cb_r,
                 unsigned short* __restrict__ ub)
{
  const int tid = threadIdx.x;
  const int d0  = tid * 8;
  const int l0  = blockIdx.x * 8;
  const int dir = blockIdx.y >> 1, b = blockIdx.y & 1;
  const float* cw = dir ? cw_r : cw_f;
  const float* cb = dir ? cb_r : cb_f;
  float w0[8], w1[8], w2[8], w3[8], bs[8];
#pragma unroll
  for (int j = 0; j < 8; ++j) {
    const float4 wv = *(const float4*)&cw[(d0 + j) * 4];
    w0[j] = wv.x; w1[j] = wv.y; w2[j] = wv.z; w3[j] = wv.w;
    bs[j] = cb[d0 + j];
  }
  const unsigned short* uin = xz + (size_t)dir * 4096 + d0;
  unsigned short* uo = ub + (size_t)dir * ((size_t)MR * DI) + d0;
  const size_t rbase = (size_t)b * LL;
  float xa[8], xbv[8], xc[8];
#pragma unroll
  for (int j = 0; j < 8; ++j) { xa[j] = 0.f; xbv[j] = 0.f; xc[j] = 0.f; }
  if (l0 >= 3) { const short8v v = *(const short8v*)&uin[(rbase + l0 - 3) * 8192];
#pragma unroll
    for (int j = 0; j < 8; ++j) xa[j] = bf2f((unsigned short)v[j]); }
  if (l0 >= 2) { const short8v v = *(const short8v*)&uin[(rbase + l0 - 2) * 8192];
#pragma unroll
    for (int j = 0; j < 8; ++j) xbv[j] = bf2f((unsigned short)v[j]); }
  if (l0 >= 1) { const short8v v = *(const short8v*)&uin[(rbase + l0 - 1) * 8192];
#pragma unroll
    for (int j = 0; j < 8; ++j) xc[j] = bf2f((unsigned short)v[j]); }
  for (int l = l0; l < l0 + 8; ++l) {
    const short8v v = *(const short8v*)&uin[(rbase + l) * 8192];
    short8v ov;
#pragma unroll
    for (int j = 0; j < 8; ++j) {
      const float x3 = bf2f((unsigned short)v[j]);
      float o = w0[j] * xa[j] + w1[j] * xbv[j] + w2[j] * xc[j] + w3[j] * x3 + bs[j];
      ov[j] = (short)f2bf(fsilu(o));
      xa[j] = xbv[j]; xbv[j] = xc[j]; xc[j] = x3;
    }
    *(short8v*)&uo[(rbase + l) * DI] = ov;
  }
}

// ---------------- chunked selective scan (bf16 delta/state, f32 sumdl) ----------------
__global__ __launch_bounds__(256)
void scanA(const unsigned short* __restrict__ dlt, const unsigned short* __restrict__ ub,
           const float* __restrict__ xdbl, const float* __restrict__ A2,
           float* __restrict__ sdl, unsigned short* __restrict__ hb)
{
  const int tid = threadIdx.x;
  const int d = blockIdx.x * 256 + tid;
  const int c = blockIdx.y;
  const int dir = blockIdx.z >> 1, b = blockIdx.z & 1;
  __shared__ float sB[LC * DS];
  const float* xd = xdbl + (size_t)dir * (MR * 96);
  for (int i = tid; i < LC * DS; i += 256) {
    int t = i >> 4, s = i & 15;
    sB[i] = xd[(size_t)(b * LL + c * LC + t) * 96 + 64 + s];
  }
  __syncthreads();
  const unsigned short* dl_p = dlt + (size_t)dir * ((size_t)MR * DI) + d;
  const unsigned short* uu = ub + (size_t)dir * ((size_t)MR * DI) + d;
  float a2[DS];
#pragma unroll
  for (int s = 0; s < DS; ++s) a2[s] = A2[((size_t)dir * DI + d) * DS + s];
  float h[DS];
#pragma unroll
  for (int s = 0; s < DS; ++s) h[s] = 0.f;
  float sumdl = 0.f;
  for (int t = 0; t < LC; ++t) {
    size_t r = (size_t)b * LL + c * LC + t;
    float dl = bf2f(dl_p[r * DI]);
    float du = dl * bf2f(uu[r * DI]);
    sumdl += dl;
#pragma unroll
    for (int s = 0; s < DS; ++s) {
      float e = __expf(dl * a2[s]);
      h[s] = e * h[s] + du * sB[t * DS + s];
    }
  }
  const size_t base = ((((size_t)(dir * 2 + b)) * NCH + c) * DI + d) * DS;
#pragma unroll
  for (int s = 0; s < DS; ++s) hb[base + s] = f2bf(h[s]);
  sdl[(((size_t)(dir * 2 + b)) * NCH + c) * DI + d] = sumdl;
}

__global__ __launch_bounds__(256)
void scanB(const float* __restrict__ sdl, const float* __restrict__ A2,
           unsigned short* __restrict__ hb)
{
  const int i = blockIdx.x * 256 + threadIdx.x;
  const int db = i >> 15;
  const int ds_ = i & 32767;
  const int d = ds_ >> 4, s = i & 15;
  const int dir = db >> 1;
  const float a2 = A2[((size_t)dir * DI + d) * DS + s];
  float hrun = 0.f;
  for (int c = 0; c < NCH; ++c) {
    const size_t off = (((size_t)db * NCH + c) << 15) + ds_;
    const float h0 = bf2f(hb[off]);
    const float pa = __expf(a2 * sdl[((size_t)db * NCH + c) * DI + d]);
    hb[off] = f2bf(hrun);
    hrun = pa * hrun + h0;
  }
}

// phase C: dirs split across wave halves of a 512-thread block.
__global__ __launch_bounds__(512)
void scanC_f(const unsigned short* __restrict__ xz, const unsigned short* __restrict__ ub,
             const unsigned short* __restrict__ dlt, const float* __restrict__ xdbl,
             const float* __restrict__ A2, const float* __restrict__ Dv_f,
             const float* __restrict__ Dv_r, const unsigned short* __restrict__ hb,
             unsigned short* __restrict__ ygb)
{
  const int tid = threadIdx.x;
  const int dir = tid >> 8;          // 0 fwd, 1 rev
  const int td  = tid & 255;
  const int d = blockIdx.x * 256 + td;
  const int c = blockIdx.y;
  const int b = blockIdx.z;
  __shared__ float sB[2][LC * DS], sC[2][LC * DS];
  __shared__ float sY[LC][256];
  for (int i = tid; i < 2 * LC * DS; i += 512) {
    const int di = i >> 7;
    const int j = i & 127;
    const int t = j >> 4, s = j & 15;
    const size_t ro = (size_t)di * (MR * 96) + (size_t)(b * LL + c * LC + t) * 96;
    sB[di][j] = xdbl[ro + 64 + s];
    sC[di][j] = xdbl[ro + 80 + s];
  }
  __syncthreads();
  float a2[DS], h[DS];
  const size_t base = ((((size_t)(dir * 2 + b)) * NCH + c) * DI + d) * DS;
#pragma unroll
  for (int s = 0; s < DS; ++s) {
    a2[s] = A2[((size_t)dir * DI + d) * DS + s];
    h[s] = bf2f(hb[base + s]);
  }
  const float Dd = dir ? Dv_r[d] : Dv_f[d];
  const unsigned short* dl_p = dlt + (size_t)dir * ((size_t)MR * DI) + d;
  const unsigned short* uu  = ub + (size_t)dir * ((size_t)MR * DI) + d;
  float yg[LC];
#pragma unroll
  for (int t = 0; t < LC; ++t) {
    const size_t r = (size_t)b * LL + c * LC + t;
    const float dl = bf2f(dl_p[r * DI]);
    const float uf = bf2f(uu[r * DI]);
    const float du = dl * uf;
    float y = 0.f;
#pragma unroll
    for (int s = 0; s < DS; ++s) {
      const float e = __expf(dl * a2[s]);
      h[s] = e * h[s] + du * sB[dir][t * DS + s];
      y += h[s] * sC[dir][t * DS + s];
    }
    y += Dd * uf;
    const float z = bf2f(xz[r * 8192 + 2048 + dir * 4096 + d]);
    yg[t] = y * fsilu(z);
  }
  if (dir == 1) {
#pragma unroll
    for (int t = 0; t < LC; ++t) sY[t][td] = yg[t];
  }
  __syncthreads();
  if (dir == 0) {
#pragma unroll
    for (int t = 0; t < LC; ++t) {
      const size_t r = (size_t)b * LL + c * LC + t;
      ygb[r * DI + d] = f2bf(yg[t] + sY[t][td]);
    }
  }
}

// ---------------- host launch ----------------

extern "C" void kernel_launch(void* const* d_in, const int* in_sizes, int n_in,
                              void* d_out, int out_size, void* d_ws, size_t ws_size,
                              hipStream_t stream)
{
  (void)in_sizes; (void)n_in; (void)out_size; (void)ws_size;
  const float* x      = (const float*)d_in[0];
  const float* mask   = (const float*)d_in[1];
  const float* inpw   = (const float*)d_in[2];
  const float* outpw  = (const float*)d_in[3];
  const float* cw_f   = (const float*)d_in[4];
  const float* cb_f   = (const float*)d_in[5];
  const float* xpw_f  = (const float*)d_in[6];
  const float* dtw_f  = (const float*)d_in[7];
  const float* dtbias_f = (const float*)d_in[8];
  const float* alog_f = (const float*)d_in[9];
  const float* Dv_f   = (const float*)d_in[10];
  const float* cw_r   = (const float*)d_in[11];
  const float* cb_r   = (const float*)d_in[12];
  const float* xpw_r  = (const float*)d_in[13];
  const float* dtw_r  = (const float*)d_in[14];
  const float* dtbias_r = (const float*)d_in[15];
  const float* alog_r = (const float*)d_in[16];
  const float* Dv_r   = (const float*)d_in[17];
  float* out = (float*)d_out;

  char* p = (char*)d_ws;
  auto carve = [&](size_t bytes) -> char* {
    char* q = p; p += (bytes + 255) & ~(size_t)255; return q;
  };
  unsigned short* xb   = (unsigned short*)carve((size_t)MR * DM * 2);
  unsigned short* Wcat = (unsigned short*)carve((size_t)8192 * 1024 * 2);
  unsigned short* xpb  = (unsigned short*)carve((size_t)2 * 96 * DI * 2);
  unsigned short* dtwb = (unsigned short*)carve((size_t)2 * DI * RK * 2);
  unsigned short* opb  = (unsigned short*)carve((size_t)DM * DI * 2);
  float*          A2   = (float*)carve((size_t)2 * DI * DS * 4);
  unsigned short* xz   = (unsigned short*)carve((size_t)MR * 8192 * 2);
  unsigned short* dlt  = (unsigned short*)carve((size_t)2 * MR * DI * 2);
  unsigned short* ub   = (unsigned short*)carve((size_t)2 * MR * DI * 2);
  float*          xdbl = (float*)carve((size_t)2 * MR * 96 * 4);
  unsigned short* dtb  = (unsigned short*)carve((size_t)2 * MR * RK * 2);
  float*          sdl  = (float*)carve((size_t)4 * NCH * DI * 4);
  unsigned short* hb   = (unsigned short*)carve((size_t)4 * NCH * DI * DS * 2);
  unsigned short* ygb  = (unsigned short*)carve((size_t)MR * DI * 2);
  float*          pxd  = (float*)carve((size_t)8 * 2 * MR * 96 * 4);   // G2 partials
  // G4 partials alias Wcat (dead after G1; 2 * MR*DM*4 == N_WCAT*2 bytes exactly)
  float*          pout = (float*)Wcat;

  // fused prep
  prep_all<<<(N_PREP / 4 + 255) / 256, 256, 0, stream>>>(
      x, mask, inpw, xpw_f, xpw_r, dtw_f, dtw_r, outpw, alog_f, alog_r,
      xb, Wcat, xpb, dtwb, opb, A2);

  // G1: xz(2048 x 8192, bf16) = xb @ Wcat^T — 256^2 swizzled kernel
  gemm256<<<dim3(32, 8, 1), 512, 0, stream>>>(xb, Wcat, xz);

  // conv + silu -> ub
  conv_silu_k<<<dim3(128, 4, 1), 256, 0, stream>>>(xz, cw_f, cb_f, cw_r, cb_r, ub);
  // G2: x_dbl partials = ub @ x_proj^T, split-K=8, non-atomic per-split slabs
  {
    GArg g0{ub, xpb, pxd, nullptr};
    GArg g1{ub + (size_t)MR * DI, xpb + 96 * DI, pxd + (size_t)MR * 96, nullptr};
    gemm_bt<0, 0, 2><<<dim3(1, 16, 16), 256, 0, stream>>>(
        g0, g1, MR, 96, 256, DI, DI, 96, 256, 2 * MR * 96);
  }
  // reduce partials -> xdbl f32 + dtb bf16
  reduce_xdbl<<<(2 * MR * 96 + 255) / 256, 256, 0, stream>>>(pxd, xdbl, dtb);
  // G3: delta = softplus(dt @ dt_w^T + dt_b) -> dlt (bf16, ldc=DI)
  {
    GArg g0{dtb, dtwb, dlt, dtbias_f};
    GArg g1{dtb + (size_t)MR * RK, dtwb + DI * RK, dlt + (size_t)MR * DI, dtbias_r};
    gemm_bt<1, 1, 2><<<dim3(16, 16, 2), 256, 0, stream>>>(
        g0, g1, MR, DI, 64, RK, RK, DI, 0, 0);
  }
  scanA<<<dim3(8, NCH, 4), 256, 0, stream>>>(dlt, ub, xdbl, A2, sdl, hb);
  scanB<<<dim3(512, 1, 1), 256, 0, stream>>>(sdl, A2, hb);
  scanC_f<<<dim3(8, NCH, 2), 512, 0, stream>>>(xz, ub, dlt, xdbl, A2, Dv_f, Dv_r, hb, ygb);
  // G4: out partials = ygb @ out_proj^T, split-K=2, non-atomic
  {
    GArg g0{ygb, opb, pout, nullptr};
    gemm_bt<0, 0, 1><<<dim3(8, 16, 2), 256, 0, stream>>>(
        g0, g0, MR, DM, 1024, DI, DI, DM, 1024, MR * DM);
  }
  reduce_out<<<(MR * DM / 4 + 255) / 256, 256, 0, stream>>>(pout, out);
}